// Round 5
// baseline (563.010 us; speedup 1.0000x reference)
//
#include <hip/hip_runtime.h>

// Problem constants (from reference)
#define N_NODES 100000
#define N_EDGES 1600000
#define N_REL   5
#define M_BUCKETS (N_NODES * N_REL)          // 500000 (dst,rel) buckets
#define SCAN_NB  ((M_BUCKETS + 1023) / 1024) // 489 scan blocks
#define NCOARSE  196                         // ceil(N_NODES / 512) coarse buckets
#define CHUNK   25000                        // nodes per processing chunk
#define NCHUNK  4

using bf16x8 = __attribute__((ext_vector_type(8))) short;
using f32x4  = __attribute__((ext_vector_type(4))) float;

__device__ __forceinline__ unsigned short f2bf(float f) {
    unsigned int u = __float_as_uint(f);
    u += 0x7fffu + ((u >> 16) & 1u);          // RNE
    return (unsigned short)(u >> 16);
}
__device__ __forceinline__ float bflo(unsigned int p) { return __uint_as_float(p << 16); }
__device__ __forceinline__ float bfhi(unsigned int p) { return __uint_as_float(p & 0xffff0000u); }

// ---------------------------------------------------------------------------
// Fine histogram (feeds the 500K-bucket scan; degs also used for mean fold)
// ---------------------------------------------------------------------------
__global__ void count_edges(const int* __restrict__ dst, const int* __restrict__ et,
                            int* __restrict__ counts) {
    int e = blockIdx.x * blockDim.x + threadIdx.x;
    if (e >= N_EDGES) return;
    atomicAdd(&counts[dst[e] * N_REL + et[e]], 1);
}

__global__ __launch_bounds__(256) void scan1(const int* __restrict__ counts,
                                             int* __restrict__ offs, int* __restrict__ tops) {
    __shared__ int lds[256];
    int tid = threadIdx.x;
    int base = blockIdx.x * 1024 + tid * 4;
    int v0 = (base + 0 < M_BUCKETS) ? counts[base + 0] : 0;
    int v1 = (base + 1 < M_BUCKETS) ? counts[base + 1] : 0;
    int v2 = (base + 2 < M_BUCKETS) ? counts[base + 2] : 0;
    int v3 = (base + 3 < M_BUCKETS) ? counts[base + 3] : 0;
    int s = v0 + v1 + v2 + v3;
    lds[tid] = s;
    __syncthreads();
    for (int d = 1; d < 256; d <<= 1) {
        int t = (tid >= d) ? lds[tid - d] : 0;
        __syncthreads();
        lds[tid] += t;
        __syncthreads();
    }
    int excl = lds[tid] - s;
    if (base + 0 < M_BUCKETS) offs[base + 0] = excl;
    excl += v0;
    if (base + 1 < M_BUCKETS) offs[base + 1] = excl;
    excl += v1;
    if (base + 2 < M_BUCKETS) offs[base + 2] = excl;
    excl += v2;
    if (base + 3 < M_BUCKETS) offs[base + 3] = excl;
    if (tid == 255) tops[blockIdx.x] = lds[255];
}

__global__ __launch_bounds__(512) void scan2(int* __restrict__ tops) {
    __shared__ int lds[512];
    int tid = threadIdx.x;
    int v = (tid < SCAN_NB) ? tops[tid] : 0;
    lds[tid] = v;
    __syncthreads();
    for (int d = 1; d < 512; d <<= 1) {
        int t = (tid >= d) ? lds[tid - d] : 0;
        __syncthreads();
        lds[tid] += t;
        __syncthreads();
    }
    if (tid < SCAN_NB) tops[tid] = lds[tid] - v;  // exclusive
}

__global__ void scan3(int* __restrict__ offs, const int* __restrict__ tops) {
    int i = blockIdx.x * blockDim.x + threadIdx.x;
    if (i >= M_BUCKETS) return;
    offs[i] += tops[i >> 10];
}

// ---------------------------------------------------------------------------
// Coarse (dst>>9) partition pipeline: hist -> 1-block scan -> partition ->
// fine scatter. Avoids 1.6M random-line writes of the one-shot scatter.
// ---------------------------------------------------------------------------
__global__ __launch_bounds__(1024) void coarse_hist(const int* __restrict__ dst,
                                                    int* __restrict__ chist) {
    __shared__ int lh[256];
    int tid = threadIdx.x;
    if (tid < 256) lh[tid] = 0;
    __syncthreads();
    int base = blockIdx.x * 4096;
    #pragma unroll
    for (int i = 0; i < 4; ++i) {
        int e = base + i * 1024 + tid;
        if (e < N_EDGES) atomicAdd(&lh[dst[e] >> 9], 1);
    }
    __syncthreads();
    if (tid < 256 && lh[tid]) atomicAdd(&chist[tid], lh[tid]);
}

// single block: exclusive scan of 256 coarse counts; also offs[M]=E sentinel
__global__ __launch_bounds__(256) void cscan(const int* __restrict__ chist,
                                             int* __restrict__ cstart, int* __restrict__ ccur,
                                             int* __restrict__ offs) {
    __shared__ int lds[256];
    int tid = threadIdx.x;
    int v = chist[tid];
    lds[tid] = v;
    __syncthreads();
    for (int d = 1; d < 256; d <<= 1) {
        int t = (tid >= d) ? lds[tid - d] : 0;
        __syncthreads();
        lds[tid] += t;
        __syncthreads();
    }
    int excl = lds[tid] - v;
    cstart[tid] = excl;
    ccur[tid] = excl;
    if (tid == 0) offs[M_BUCKETS] = N_EDGES;
}

// partition into coarse-bucket order; record = (src | rel<<17 | dlow9<<20, ew)
__global__ __launch_bounds__(1024) void partition(
    const int* __restrict__ src, const int* __restrict__ dstv,
    const float* __restrict__ ew, const int* __restrict__ et,
    int* __restrict__ ccur, int2* __restrict__ pe) {
    __shared__ int lh[256];
    __shared__ int lb[256];
    int tid = threadIdx.x;
    if (tid < 256) lh[tid] = 0;
    __syncthreads();
    int base = blockIdx.x * 4096;
    int key[4], rank[4], meta[4];
    float w[4];
    #pragma unroll
    for (int i = 0; i < 4; ++i) {
        int e = base + i * 1024 + tid;
        key[i] = -1;
        if (e < N_EDGES) {
            int d = dstv[e];
            key[i] = d >> 9;
            meta[i] = src[e] | (et[e] << 17) | ((d & 511) << 20);
            w[i] = ew[e];
            rank[i] = atomicAdd(&lh[key[i]], 1);
        }
    }
    __syncthreads();
    if (tid < 256) {
        int c = lh[tid];
        lb[tid] = c ? atomicAdd(&ccur[tid], c) : 0;
    }
    __syncthreads();
    #pragma unroll
    for (int i = 0; i < 4; ++i)
        if (key[i] >= 0)
            pe[lb[key[i]] + rank[i]] = make_int2(meta[i], __float_as_int(w[i]));
}

__global__ void node_cur_init(const int* __restrict__ offs, int* __restrict__ nodeCur) {
    int n = blockIdx.x * blockDim.x + threadIdx.x;
    if (n < N_NODES) nodeCur[n] = offs[n * N_REL];
}

// fine scatter: node-granular position; writes confined to 64KB coarse regions
__global__ void fine_scatter(const int2* __restrict__ pe, const int* __restrict__ cstart,
                             int* __restrict__ nodeCur, int2* __restrict__ edges) {
    int e = blockIdx.x * blockDim.x + threadIdx.x;
    if (e >= N_EDGES) return;
    int2 r = pe[e];
    int lo = 0, hi = NCOARSE - 1;
    while (lo < hi) {                       // find coarse bucket of position e
        int mid = (lo + hi + 1) >> 1;
        if (cstart[mid] <= e) lo = mid; else hi = mid - 1;
    }
    int d = (lo << 9) | ((r.x >> 20) & 511);
    int pos = atomicAdd(&nodeCur[d], 1);
    edges[pos] = make_int2(r.x & 0xFFFFF, r.y);   // keep src|rel<<17
}

// ---------------------------------------------------------------------------
// Precision conversions (once per launch)
// ---------------------------------------------------------------------------
__global__ void cvt_feat(const float* __restrict__ x, ushort* __restrict__ xh) {
    int i = blockIdx.x * blockDim.x + threadIdx.x;   // float4 index
    if (i >= (N_NODES * 128) / 4) return;
    float4 v = reinterpret_cast<const float4*>(x)[i];
    ushort4 o;
    o.x = f2bf(v.x); o.y = f2bf(v.y); o.z = f2bf(v.z); o.w = f2bf(v.w);
    reinterpret_cast<ushort4*>(xh)[i] = o;
}

// Stack [root; W_0..W_4] transposed: Wt[o][seg*128+k], seg0=root, seg r+1=W_r.
__global__ void cvt_wstack(const float* __restrict__ W, const float* __restrict__ root,
                           ushort* __restrict__ Wt, int NN) {
    int t = blockIdx.x * blockDim.x + threadIdx.x;   // 0..767
    int o = blockIdx.y;
    int seg = t >> 7, k = t & 127;
    float v = (seg == 0) ? root[k * NN + o] : W[(size_t)(seg - 1) * 128 * NN + k * NN + o];
    Wt[(size_t)o * 768 + t] = f2bf(v);
}

// ---------------------------------------------------------------------------
// Gather-aggregate, one wave per node, all relations in one pass.
// A[n-node0][768] bf16 = [own(128) | mean_r0(128) | ... | mean_r4(128)].
// Mean folded POST-accumulation: inv_r from offs diffs (no per-edge cost).
// 16-deep unrolled feature gathers for ILP.
// ---------------------------------------------------------------------------
__global__ __launch_bounds__(256) void gather_all(
    const ushort* __restrict__ feat,   // bf16 [N][128]
    const int2* __restrict__ edges,
    const int* __restrict__ offs,      // exclusive starts, offs[M]=E
    ushort* __restrict__ A,            // [>=CHUNK][768] bf16
    int node0) {
    int n = __builtin_amdgcn_readfirstlane(node0 + blockIdx.x * 4 + (threadIdx.x >> 6));
    int lane = threadIdx.x & 63;
    int b0 = n * N_REL;
    int o0 = offs[b0], o1 = offs[b0 + 1], o2 = offs[b0 + 2];
    int o3 = offs[b0 + 3], o4 = offs[b0 + 4], o5 = offs[b0 + 5];
    const unsigned int* fp = reinterpret_cast<const unsigned int*>(feat);

    unsigned int own = fp[(size_t)n * 64 + lane];
    float a0x = 0.f, a0y = 0.f, a1x = 0.f, a1y = 0.f, a2x = 0.f, a2y = 0.f;
    float a3x = 0.f, a3y = 0.f, a4x = 0.f, a4y = 0.f;

    for (int base = o0; base < o5; base += 64) {
        int idx = base + lane;
        int2 er = (idx < o5) ? edges[idx] : make_int2(0, 0);  // pad: w=0, rel=0, src=0
        int cnt = o5 - base; if (cnt > 64) cnt = 64;
        int cnt16 = (cnt + 15) & ~15;
        for (int e = 0; e < cnt16; e += 16) {
            #pragma unroll
            for (int j = 0; j < 16; ++j) {
                int meta = __builtin_amdgcn_readlane(er.x, e + j);
                float w = __uint_as_float(__builtin_amdgcn_readlane(er.y, e + j));
                int s = meta & 0x1FFFF;
                int rel = (meta >> 17) & 7;
                unsigned int p = fp[(size_t)s * 64 + lane];
                float lo = bflo(p), hi = bfhi(p);
                float w0 = (rel == 0) ? w : 0.f;
                float w1 = (rel == 1) ? w : 0.f;
                float w2 = (rel == 2) ? w : 0.f;
                float w3 = (rel == 3) ? w : 0.f;
                float w4 = (rel == 4) ? w : 0.f;
                a0x = fmaf(w0, lo, a0x); a0y = fmaf(w0, hi, a0y);
                a1x = fmaf(w1, lo, a1x); a1y = fmaf(w1, hi, a1y);
                a2x = fmaf(w2, lo, a2x); a2y = fmaf(w2, hi, a2y);
                a3x = fmaf(w3, lo, a3x); a3y = fmaf(w3, hi, a3y);
                a4x = fmaf(w4, lo, a4x); a4y = fmaf(w4, hi, a4y);
            }
        }
    }

    float i0 = (o1 > o0) ? 1.f / (float)(o1 - o0) : 0.f;
    float i1 = (o2 > o1) ? 1.f / (float)(o2 - o1) : 0.f;
    float i2 = (o3 > o2) ? 1.f / (float)(o3 - o2) : 0.f;
    float i3 = (o4 > o3) ? 1.f / (float)(o4 - o3) : 0.f;
    float i4 = (o5 > o4) ? 1.f / (float)(o5 - o4) : 0.f;

    unsigned int* Ap = reinterpret_cast<unsigned int*>(A) + (size_t)(n - node0) * 384;
    Ap[lane] = own;
    Ap[64 * 1 + lane] = (unsigned int)f2bf(a0x * i0) | ((unsigned int)f2bf(a0y * i0) << 16);
    Ap[64 * 2 + lane] = (unsigned int)f2bf(a1x * i1) | ((unsigned int)f2bf(a1y * i1) << 16);
    Ap[64 * 3 + lane] = (unsigned int)f2bf(a2x * i2) | ((unsigned int)f2bf(a2y * i2) << 16);
    Ap[64 * 4 + lane] = (unsigned int)f2bf(a3x * i3) | ((unsigned int)f2bf(a3y * i3) << 16);
    Ap[64 * 5 + lane] = (unsigned int)f2bf(a4x * i4) | ((unsigned int)f2bf(a4y * i4) << 16);
}

// ---------------------------------------------------------------------------
// GEMM: out[row][BN] = A[row][768] @ Wt[BN][768]^T + bias (+relu)
// ---------------------------------------------------------------------------
template<int BN, bool RELU, bool F32OUT>
__global__ __launch_bounds__(256) void gemm768(
    const ushort* __restrict__ A,    // chunk-local [rows][768] bf16
    const ushort* __restrict__ Wt,   // [BN][768] bf16
    const float* __restrict__ bias,  // [BN]
    void* __restrict__ outp,         // bf16 [N][BN] or f32 [N][BN]
    int row0, int nrows) {
    __shared__ ushort As[128 * 64];          // 16 KB
    __shared__ ushort Bs[BN * 64];           // 16 KB | 2 KB
    const int tid = threadIdx.x, lane = tid & 63, wave = tid >> 6;
    const int m0 = blockIdx.x * 128;         // chunk-local row base

    constexpr int MF = (BN == 128) ? 4 : 2;
    constexpr int NF = (BN == 128) ? 4 : 1;
    const int wr0 = (BN == 128) ? (wave >> 1) * 64 : wave * 32;
    const int wc0 = (BN == 128) ? (wave & 1) * 64 : 0;

    f32x4 acc[MF][NF] = {};

    for (int ks = 0; ks < 12; ++ks) {
        #pragma unroll
        for (int u = 0; u < 4; ++u) {
            int idx = tid + u * 256;
            int row = idx >> 3, slot = idx & 7;
            float4 v = *reinterpret_cast<const float4*>(
                A + (size_t)(m0 + row) * 768 + ks * 64 + slot * 8);
            int byte = row * 128 + ((slot ^ (row & 7)) << 4);
            *reinterpret_cast<float4*>(reinterpret_cast<char*>(As) + byte) = v;
        }
        constexpr int BCH = BN * 8;
        #pragma unroll
        for (int u = 0; u < (BCH + 255) / 256; ++u) {
            int idx = tid + u * 256;
            if ((BCH % 256) && idx >= BCH) break;
            int row = idx >> 3, slot = idx & 7;
            float4 v = *reinterpret_cast<const float4*>(
                Wt + (size_t)row * 768 + ks * 64 + slot * 8);
            int byte = row * 128 + ((slot ^ (row & 7)) << 4);
            *reinterpret_cast<float4*>(reinterpret_cast<char*>(Bs) + byte) = v;
        }
        __syncthreads();

        #pragma unroll
        for (int kh = 0; kh < 2; ++kh) {
            bf16x8 af[MF], bfr[NF];
            #pragma unroll
            for (int m = 0; m < MF; ++m) {
                int row = wr0 + m * 16 + (lane & 15);
                int slot = kh * 4 + (lane >> 4);
                int byte = row * 128 + ((slot ^ (row & 7)) << 4);
                af[m] = *reinterpret_cast<const bf16x8*>(
                    reinterpret_cast<const char*>(As) + byte);
            }
            #pragma unroll
            for (int nn = 0; nn < NF; ++nn) {
                int row = wc0 + nn * 16 + (lane & 15);
                int slot = kh * 4 + (lane >> 4);
                int byte = row * 128 + ((slot ^ (row & 7)) << 4);
                bfr[nn] = *reinterpret_cast<const bf16x8*>(
                    reinterpret_cast<const char*>(Bs) + byte);
            }
            #pragma unroll
            for (int m = 0; m < MF; ++m)
                #pragma unroll
                for (int nn = 0; nn < NF; ++nn)
                    acc[m][nn] = __builtin_amdgcn_mfma_f32_16x16x32_bf16(
                        af[m], bfr[nn], acc[m][nn], 0, 0, 0);
        }
        __syncthreads();
    }

    #pragma unroll
    for (int m = 0; m < MF; ++m) {
        int rloc = wr0 + m * 16 + (lane >> 4) * 4;
        #pragma unroll
        for (int nn = 0; nn < NF; ++nn) {
            int c = wc0 + nn * 16 + (lane & 15);
            float bv = bias[c];
            #pragma unroll
            for (int q = 0; q < 4; ++q) {
                int lrow = m0 + rloc + q;
                if (lrow < nrows) {
                    int grow = row0 + lrow;
                    float v = acc[m][nn][q] + bv;
                    if (RELU) v = fmaxf(v, 0.f);
                    if (F32OUT)
                        reinterpret_cast<float*>(outp)[(size_t)grow * BN + c] = v;
                    else
                        reinterpret_cast<ushort*>(outp)[(size_t)grow * BN + c] = f2bf(v);
                }
            }
        }
    }
}

// ---------------------------------------------------------------------------
// In-place log_softmax over rows of 16.
// ---------------------------------------------------------------------------
__global__ void log_softmax16(float* __restrict__ out) {
    int n = blockIdx.x * blockDim.x + threadIdx.x;
    if (n >= N_NODES) return;
    float4* p = reinterpret_cast<float4*>(out + (size_t)n * 16);
    float4 a = p[0], b = p[1], c = p[2], d = p[3];
    float m = a.x;
    m = fmaxf(m, a.y); m = fmaxf(m, a.z); m = fmaxf(m, a.w);
    m = fmaxf(m, b.x); m = fmaxf(m, b.y); m = fmaxf(m, b.z); m = fmaxf(m, b.w);
    m = fmaxf(m, c.x); m = fmaxf(m, c.y); m = fmaxf(m, c.z); m = fmaxf(m, c.w);
    m = fmaxf(m, d.x); m = fmaxf(m, d.y); m = fmaxf(m, d.z); m = fmaxf(m, d.w);
    float s = 0.f;
    s += expf(a.x - m) + expf(a.y - m) + expf(a.z - m) + expf(a.w - m);
    s += expf(b.x - m) + expf(b.y - m) + expf(b.z - m) + expf(b.w - m);
    s += expf(c.x - m) + expf(c.y - m) + expf(c.z - m) + expf(c.w - m);
    s += expf(d.x - m) + expf(d.y - m) + expf(d.z - m) + expf(d.w - m);
    float lse = m + logf(s);
    a.x -= lse; a.y -= lse; a.z -= lse; a.w -= lse;
    b.x -= lse; b.y -= lse; b.z -= lse; b.w -= lse;
    c.x -= lse; c.y -= lse; c.z -= lse; c.w -= lse;
    d.x -= lse; d.y -= lse; d.z -= lse; d.w -= lse;
    p[0] = a; p[1] = b; p[2] = c; p[3] = d;
}

// ---------------------------------------------------------------------------
extern "C" void kernel_launch(void* const* d_in, const int* in_sizes, int n_in,
                              void* d_out, int out_size, void* d_ws, size_t ws_size,
                              hipStream_t stream) {
    const float* x     = (const float*)d_in[0];
    const int*   ei    = (const int*)d_in[1];
    const int*   src   = ei;
    const int*   dst   = ei + N_EDGES;
    const float* ew    = (const float*)d_in[2];
    const int*   et    = (const int*)d_in[3];
    const float* W1    = (const float*)d_in[4];
    const float* root1 = (const float*)d_in[5];
    const float* b1    = (const float*)d_in[6];
    const float* W2    = (const float*)d_in[7];
    const float* root2 = (const float*)d_in[8];
    const float* b2    = (const float*)d_in[9];
    float* out = (float*)d_out;

    // workspace layout (~102.2 MiB)
    char* ws = (char*)d_ws;
    int*    counts  = (int*)ws;                        //  2,000,000 B
    int*    offs    = (int*)(ws + 2000000);            //  2,000,004 B (M+1)
    int*    tops    = (int*)(ws + 4000016);            //      4,096 B
    int*    chist   = (int*)(ws + 4004112);            //      1,024 B
    int*    cstart  = (int*)(ws + 4005136);            //      1,024 B
    int*    ccur    = (int*)(ws + 4006160);            //      1,024 B
    int*    nodeCur = (int*)(ws + 4007184);            //    400,000 B
    int2*   edges   = (int2*)(ws + 4407296);           // 12,800,000 B
    ushort* xh      = (ushort*)(ws + 17207296);        // 25,600,000 B
    ushort* h       = (ushort*)(ws + 42807296);        // 25,600,000 B
    ushort* Wt1     = (ushort*)(ws + 68407296);        //    196,608 B
    ushort* Wt2     = (ushort*)(ws + 68603904);        //     24,576 B
    // union region: pe (12.8 MB, CSR build) then Achunk (38.5 MB, layers)
    int2*   pe      = (int2*)(ws + 68628480);
    ushort* Achunk  = (ushort*)(ws + 68628480);        // 25088*1536 B

    // --- precision conversions ---
    cvt_feat<<<((N_NODES * 128 / 4) + 255) / 256, 256, 0, stream>>>(x, xh);
    cvt_wstack<<<dim3(3, 128), 256, 0, stream>>>(W1, root1, Wt1, 128);
    cvt_wstack<<<dim3(3, 16), 256, 0, stream>>>(W2, root2, Wt2, 16);

    // --- build (dst,rel)-bucketed CSR via coarse partition ---
    hipMemsetAsync(counts, 0, (size_t)M_BUCKETS * sizeof(int), stream);
    hipMemsetAsync(chist, 0, 1024, stream);
    count_edges<<<(N_EDGES + 255) / 256, 256, 0, stream>>>(dst, et, counts);
    coarse_hist<<<(N_EDGES + 4095) / 4096, 1024, 0, stream>>>(dst, chist);
    scan1<<<SCAN_NB, 256, 0, stream>>>(counts, offs, tops);
    scan2<<<1, 512, 0, stream>>>(tops);
    scan3<<<(M_BUCKETS + 255) / 256, 256, 0, stream>>>(offs, tops);
    cscan<<<1, 256, 0, stream>>>(chist, cstart, ccur, offs);
    partition<<<(N_EDGES + 4095) / 4096, 1024, 0, stream>>>(src, dst, ew, et, ccur, pe);
    node_cur_init<<<(N_NODES + 255) / 256, 256, 0, stream>>>(offs, nodeCur);
    fine_scatter<<<(N_EDGES + 255) / 256, 256, 0, stream>>>(pe, cstart, nodeCur, edges);

    const int ggrid = (CHUNK + 4 - 1) / 4;        // 6250 gather blocks / chunk
    const int mgrid = (CHUNK + 127) / 128;        // 196 gemm blocks / chunk

    // --- layer 1: h = bf16(relu(A1 @ Wt1^T + b1)), A1 = [x | agg_r(x)] ---
    for (int c = 0; c < NCHUNK; ++c) {
        gather_all<<<ggrid, 256, 0, stream>>>(xh, edges, offs, Achunk, c * CHUNK);
        gemm768<128, true, false><<<mgrid, 256, 0, stream>>>(
            Achunk, Wt1, b1, h, c * CHUNK, CHUNK);
    }

    // --- layer 2: out = A2 @ Wt2^T + b2, A2 = [h | agg_r(h)] ---
    for (int c = 0; c < NCHUNK; ++c) {
        gather_all<<<ggrid, 256, 0, stream>>>(h, edges, offs, Achunk, c * CHUNK);
        gemm768<16, false, true><<<mgrid, 256, 0, stream>>>(
            Achunk, Wt2, b2, out, c * CHUNK, CHUNK);
    }

    log_softmax16<<<(N_NODES + 255) / 256, 256, 0, stream>>>(out);
}

// Round 6
// 447.857 us; speedup vs baseline: 1.2571x; 1.2571x over previous
//
#include <hip/hip_runtime.h>

// Problem constants (from reference)
#define N_NODES 100000
#define N_EDGES 1600000
#define N_REL   5
#define M_BUCKETS (N_NODES * N_REL)          // 500000 (dst,rel) buckets
#define NCOARSE  196                         // ceil(N_NODES / 512) coarse buckets
#define CAP      16384                       // pe capacity per coarse bucket (avg 8163)
#define CHUNK   25000                        // nodes per processing chunk
#define NCHUNK  4

using bf16x8 = __attribute__((ext_vector_type(8))) short;
using f32x4  = __attribute__((ext_vector_type(4))) float;

__device__ __forceinline__ unsigned short f2bf(float f) {
    unsigned int u = __float_as_uint(f);
    u += 0x7fffu + ((u >> 16) & 1u);          // RNE
    return (unsigned short)(u >> 16);
}
__device__ __forceinline__ float bflo(unsigned int p) { return __uint_as_float(p << 16); }
__device__ __forceinline__ float bfhi(unsigned int p) { return __uint_as_float(p & 0xffff0000u); }

// ---------------------------------------------------------------------------
// Pass 1: append edges into coarse (dst>>9) regions of pe.
// Block-local LDS histogram -> one global atomicAdd per (block, bucket).
// Record = (src | rel<<17 | dlow9<<20, ew).
// ---------------------------------------------------------------------------
__global__ __launch_bounds__(1024) void partition_append(
    const int* __restrict__ src, const int* __restrict__ dstv,
    const float* __restrict__ ew, const int* __restrict__ et,
    int* __restrict__ ccur, int2* __restrict__ pe) {
    __shared__ int lh[256];
    __shared__ int lb[256];
    int tid = threadIdx.x;
    if (tid < 256) lh[tid] = 0;
    __syncthreads();
    int base = blockIdx.x * 4096;
    int key[4], rank[4], meta[4];
    float w[4];
    #pragma unroll
    for (int i = 0; i < 4; ++i) {
        int e = base + i * 1024 + tid;
        key[i] = -1;
        if (e < N_EDGES) {
            int d = dstv[e];
            key[i] = d >> 9;
            meta[i] = src[e] | (et[e] << 17) | ((d & 511) << 20);
            w[i] = ew[e];
            rank[i] = atomicAdd(&lh[key[i]], 1);
        }
    }
    __syncthreads();
    if (tid < 256) {
        int c = lh[tid];
        lb[tid] = c ? atomicAdd(&ccur[tid], c) : 0;
    }
    __syncthreads();
    #pragma unroll
    for (int i = 0; i < 4; ++i)
        if (key[i] >= 0) {
            int pos = lb[key[i]] + rank[i];
            if (pos < CAP)   // never triggers for this input (max ~8.5K/bucket)
                pe[((size_t)key[i] << 14) + pos] = make_int2(meta[i], __float_as_int(w[i]));
        }
}

// Pass 2 (tiny): exclusive scan of 256 coarse counts -> global bases; sentinel.
__global__ __launch_bounds__(256) void cscan(const int* __restrict__ ccur,
                                             int* __restrict__ cstart,
                                             int* __restrict__ offs) {
    __shared__ int lds[256];
    int tid = threadIdx.x;
    int v = ccur[tid];
    lds[tid] = v;
    __syncthreads();
    for (int d = 1; d < 256; d <<= 1) {
        int t = (tid >= d) ? lds[tid - d] : 0;
        __syncthreads();
        lds[tid] += t;
        __syncthreads();
    }
    cstart[tid] = lds[tid] - v;
    if (tid == 0) offs[M_BUCKETS] = N_EDGES;
}

// ---------------------------------------------------------------------------
// Pass 3: one block per coarse bucket. LDS fine-histogram (512 nodes x 5 rel),
// LDS scan -> writes offs slice (coalesced) + scatters records to final dense
// order (writes within a 64KB span, L2-local). Replaces the 500K-bucket
// global histogram + 3 scan kernels + node_cur_init + fine_scatter.
// ---------------------------------------------------------------------------
__global__ __launch_bounds__(1024) void bucket_sort(
    const int* __restrict__ ccnt, const int* __restrict__ cstart,
    const int2* __restrict__ pe, int2* __restrict__ edges, int* __restrict__ offs) {
    int cb = blockIdx.x;
    int node0 = cb << 9;
    if (node0 >= N_NODES) return;
    int nNodes = N_NODES - node0; if (nNodes > 512) nNodes = 512;
    int nf = nNodes * N_REL;                 // fine buckets in this block (<=2560)
    __shared__ int hist[2560];
    __shared__ int cur[2560];
    __shared__ int sums[1024];
    int tid = threadIdx.x;
    int cnt = ccnt[cb]; if (cnt > CAP) cnt = CAP;
    int gbase = cstart[cb];
    const int2* my = pe + ((size_t)cb << 14);

    for (int i = tid; i < nf; i += 1024) hist[i] = 0;
    __syncthreads();
    for (int i = tid; i < cnt; i += 1024) {
        int m = my[i].x;
        int fb = ((m >> 20) & 511) * N_REL + ((m >> 17) & 7);
        atomicAdd(&hist[fb], 1);
    }
    __syncthreads();

    // block exclusive scan over hist[0..nf): 3 elems/thread + 1024-wide scan
    int t0 = tid * 3;
    int a0 = (t0 + 0 < nf) ? hist[t0 + 0] : 0;
    int a1 = (t0 + 1 < nf) ? hist[t0 + 1] : 0;
    int a2 = (t0 + 2 < nf) ? hist[t0 + 2] : 0;
    int s = a0 + a1 + a2;
    sums[tid] = s;
    __syncthreads();
    for (int d = 1; d < 1024; d <<= 1) {
        int t = (tid >= d) ? sums[tid - d] : 0;
        __syncthreads();
        sums[tid] += t;
        __syncthreads();
    }
    int excl = sums[tid] - s;
    int gb0 = node0 * N_REL;
    if (t0 + 0 < nf) { offs[gb0 + t0 + 0] = gbase + excl; cur[t0 + 0] = excl; }
    excl += a0;
    if (t0 + 1 < nf) { offs[gb0 + t0 + 1] = gbase + excl; cur[t0 + 1] = excl; }
    excl += a1;
    if (t0 + 2 < nf) { offs[gb0 + t0 + 2] = gbase + excl; cur[t0 + 2] = excl; }
    __syncthreads();

    for (int i = tid; i < cnt; i += 1024) {
        int2 r = my[i];
        int fb = ((r.x >> 20) & 511) * N_REL + ((r.x >> 17) & 7);
        int pos = gbase + atomicAdd(&cur[fb], 1);
        edges[pos] = make_int2(r.x & 0xFFFFF, r.y);   // keep src | rel<<17
    }
}

// ---------------------------------------------------------------------------
// Precision conversions (once per launch)
// ---------------------------------------------------------------------------
__global__ void cvt_feat(const float* __restrict__ x, ushort* __restrict__ xh) {
    int i = blockIdx.x * blockDim.x + threadIdx.x;   // float4 index
    if (i >= (N_NODES * 128) / 4) return;
    float4 v = reinterpret_cast<const float4*>(x)[i];
    ushort4 o;
    o.x = f2bf(v.x); o.y = f2bf(v.y); o.z = f2bf(v.z); o.w = f2bf(v.w);
    reinterpret_cast<ushort4*>(xh)[i] = o;
}

// Stack [root; W_0..W_4] transposed: Wt[o][seg*128+k], seg0=root, seg r+1=W_r.
__global__ void cvt_wstack(const float* __restrict__ W, const float* __restrict__ root,
                           ushort* __restrict__ Wt, int NN) {
    int t = blockIdx.x * blockDim.x + threadIdx.x;   // 0..767
    int o = blockIdx.y;
    int seg = t >> 7, k = t & 127;
    float v = (seg == 0) ? root[k * NN + o] : W[(size_t)(seg - 1) * 128 * NN + k * NN + o];
    Wt[(size_t)o * 768 + t] = f2bf(v);
}

// ---------------------------------------------------------------------------
// Gather-aggregate, one wave per node, all relations in one pass.
// A[n-node0][768] bf16 = [own(128) | mean_r0(128) | ... | mean_r4(128)].
// Mean folded POST-accumulation: inv_r from offs diffs.
// ---------------------------------------------------------------------------
__global__ __launch_bounds__(256) void gather_all(
    const ushort* __restrict__ feat,   // bf16 [N][128]
    const int2* __restrict__ edges,
    const int* __restrict__ offs,      // exclusive starts, offs[M]=E
    ushort* __restrict__ A,            // [>=CHUNK][768] bf16
    int node0) {
    int n = __builtin_amdgcn_readfirstlane(node0 + blockIdx.x * 4 + (threadIdx.x >> 6));
    int lane = threadIdx.x & 63;
    int b0 = n * N_REL;
    int o0 = offs[b0], o1 = offs[b0 + 1], o2 = offs[b0 + 2];
    int o3 = offs[b0 + 3], o4 = offs[b0 + 4], o5 = offs[b0 + 5];
    const unsigned int* fp = reinterpret_cast<const unsigned int*>(feat);

    unsigned int own = fp[(size_t)n * 64 + lane];
    float a0x = 0.f, a0y = 0.f, a1x = 0.f, a1y = 0.f, a2x = 0.f, a2y = 0.f;
    float a3x = 0.f, a3y = 0.f, a4x = 0.f, a4y = 0.f;

    for (int base = o0; base < o5; base += 64) {
        int idx = base + lane;
        int2 er = (idx < o5) ? edges[idx] : make_int2(0, 0);  // pad: w=0, rel=0, src=0
        int cnt = o5 - base; if (cnt > 64) cnt = 64;
        int cnt16 = (cnt + 15) & ~15;
        for (int e = 0; e < cnt16; e += 16) {
            #pragma unroll
            for (int j = 0; j < 16; ++j) {
                int meta = __builtin_amdgcn_readlane(er.x, e + j);
                float w = __uint_as_float(__builtin_amdgcn_readlane(er.y, e + j));
                int s = meta & 0x1FFFF;
                int rel = (meta >> 17) & 7;
                unsigned int p = fp[(size_t)s * 64 + lane];
                float lo = bflo(p), hi = bfhi(p);
                float w0 = (rel == 0) ? w : 0.f;
                float w1 = (rel == 1) ? w : 0.f;
                float w2 = (rel == 2) ? w : 0.f;
                float w3 = (rel == 3) ? w : 0.f;
                float w4 = (rel == 4) ? w : 0.f;
                a0x = fmaf(w0, lo, a0x); a0y = fmaf(w0, hi, a0y);
                a1x = fmaf(w1, lo, a1x); a1y = fmaf(w1, hi, a1y);
                a2x = fmaf(w2, lo, a2x); a2y = fmaf(w2, hi, a2y);
                a3x = fmaf(w3, lo, a3x); a3y = fmaf(w3, hi, a3y);
                a4x = fmaf(w4, lo, a4x); a4y = fmaf(w4, hi, a4y);
            }
        }
    }

    float i0 = (o1 > o0) ? 1.f / (float)(o1 - o0) : 0.f;
    float i1 = (o2 > o1) ? 1.f / (float)(o2 - o1) : 0.f;
    float i2 = (o3 > o2) ? 1.f / (float)(o3 - o2) : 0.f;
    float i3 = (o4 > o3) ? 1.f / (float)(o4 - o3) : 0.f;
    float i4 = (o5 > o4) ? 1.f / (float)(o5 - o4) : 0.f;

    unsigned int* Ap = reinterpret_cast<unsigned int*>(A) + (size_t)(n - node0) * 384;
    Ap[lane] = own;
    Ap[64 * 1 + lane] = (unsigned int)f2bf(a0x * i0) | ((unsigned int)f2bf(a0y * i0) << 16);
    Ap[64 * 2 + lane] = (unsigned int)f2bf(a1x * i1) | ((unsigned int)f2bf(a1y * i1) << 16);
    Ap[64 * 3 + lane] = (unsigned int)f2bf(a2x * i2) | ((unsigned int)f2bf(a2y * i2) << 16);
    Ap[64 * 4 + lane] = (unsigned int)f2bf(a3x * i3) | ((unsigned int)f2bf(a3y * i3) << 16);
    Ap[64 * 5 + lane] = (unsigned int)f2bf(a4x * i4) | ((unsigned int)f2bf(a4y * i4) << 16);
}

// ---------------------------------------------------------------------------
// GEMM: out[row][BN] = A[row][768] @ Wt[BN][768]^T + bias (+relu)
// ---------------------------------------------------------------------------
template<int BN, bool RELU, bool F32OUT>
__global__ __launch_bounds__(256) void gemm768(
    const ushort* __restrict__ A,    // chunk-local [rows][768] bf16
    const ushort* __restrict__ Wt,   // [BN][768] bf16
    const float* __restrict__ bias,  // [BN]
    void* __restrict__ outp,         // bf16 [N][BN] or f32 [N][BN]
    int row0, int nrows) {
    __shared__ ushort As[128 * 64];          // 16 KB
    __shared__ ushort Bs[BN * 64];           // 16 KB | 2 KB
    const int tid = threadIdx.x, lane = tid & 63, wave = tid >> 6;
    const int m0 = blockIdx.x * 128;         // chunk-local row base

    constexpr int MF = (BN == 128) ? 4 : 2;
    constexpr int NF = (BN == 128) ? 4 : 1;
    const int wr0 = (BN == 128) ? (wave >> 1) * 64 : wave * 32;
    const int wc0 = (BN == 128) ? (wave & 1) * 64 : 0;

    f32x4 acc[MF][NF] = {};

    for (int ks = 0; ks < 12; ++ks) {
        #pragma unroll
        for (int u = 0; u < 4; ++u) {
            int idx = tid + u * 256;
            int row = idx >> 3, slot = idx & 7;
            float4 v = *reinterpret_cast<const float4*>(
                A + (size_t)(m0 + row) * 768 + ks * 64 + slot * 8);
            int byte = row * 128 + ((slot ^ (row & 7)) << 4);
            *reinterpret_cast<float4*>(reinterpret_cast<char*>(As) + byte) = v;
        }
        constexpr int BCH = BN * 8;
        #pragma unroll
        for (int u = 0; u < (BCH + 255) / 256; ++u) {
            int idx = tid + u * 256;
            if ((BCH % 256) && idx >= BCH) break;
            int row = idx >> 3, slot = idx & 7;
            float4 v = *reinterpret_cast<const float4*>(
                Wt + (size_t)row * 768 + ks * 64 + slot * 8);
            int byte = row * 128 + ((slot ^ (row & 7)) << 4);
            *reinterpret_cast<float4*>(reinterpret_cast<char*>(Bs) + byte) = v;
        }
        __syncthreads();

        #pragma unroll
        for (int kh = 0; kh < 2; ++kh) {
            bf16x8 af[MF], bfr[NF];
            #pragma unroll
            for (int m = 0; m < MF; ++m) {
                int row = wr0 + m * 16 + (lane & 15);
                int slot = kh * 4 + (lane >> 4);
                int byte = row * 128 + ((slot ^ (row & 7)) << 4);
                af[m] = *reinterpret_cast<const bf16x8*>(
                    reinterpret_cast<const char*>(As) + byte);
            }
            #pragma unroll
            for (int nn = 0; nn < NF; ++nn) {
                int row = wc0 + nn * 16 + (lane & 15);
                int slot = kh * 4 + (lane >> 4);
                int byte = row * 128 + ((slot ^ (row & 7)) << 4);
                bfr[nn] = *reinterpret_cast<const bf16x8*>(
                    reinterpret_cast<const char*>(Bs) + byte);
            }
            #pragma unroll
            for (int m = 0; m < MF; ++m)
                #pragma unroll
                for (int nn = 0; nn < NF; ++nn)
                    acc[m][nn] = __builtin_amdgcn_mfma_f32_16x16x32_bf16(
                        af[m], bfr[nn], acc[m][nn], 0, 0, 0);
        }
        __syncthreads();
    }

    #pragma unroll
    for (int m = 0; m < MF; ++m) {
        int rloc = wr0 + m * 16 + (lane >> 4) * 4;
        #pragma unroll
        for (int nn = 0; nn < NF; ++nn) {
            int c = wc0 + nn * 16 + (lane & 15);
            float bv = bias[c];
            #pragma unroll
            for (int q = 0; q < 4; ++q) {
                int lrow = m0 + rloc + q;
                if (lrow < nrows) {
                    int grow = row0 + lrow;
                    float v = acc[m][nn][q] + bv;
                    if (RELU) v = fmaxf(v, 0.f);
                    if (F32OUT)
                        reinterpret_cast<float*>(outp)[(size_t)grow * BN + c] = v;
                    else
                        reinterpret_cast<ushort*>(outp)[(size_t)grow * BN + c] = f2bf(v);
                }
            }
        }
    }
}

// ---------------------------------------------------------------------------
// In-place log_softmax over rows of 16.
// ---------------------------------------------------------------------------
__global__ void log_softmax16(float* __restrict__ out) {
    int n = blockIdx.x * blockDim.x + threadIdx.x;
    if (n >= N_NODES) return;
    float4* p = reinterpret_cast<float4*>(out + (size_t)n * 16);
    float4 a = p[0], b = p[1], c = p[2], d = p[3];
    float m = a.x;
    m = fmaxf(m, a.y); m = fmaxf(m, a.z); m = fmaxf(m, a.w);
    m = fmaxf(m, b.x); m = fmaxf(m, b.y); m = fmaxf(m, b.z); m = fmaxf(m, b.w);
    m = fmaxf(m, c.x); m = fmaxf(m, c.y); m = fmaxf(m, c.z); m = fmaxf(m, c.w);
    m = fmaxf(m, d.x); m = fmaxf(m, d.y); m = fmaxf(m, d.z); m = fmaxf(m, d.w);
    float s = 0.f;
    s += expf(a.x - m) + expf(a.y - m) + expf(a.z - m) + expf(a.w - m);
    s += expf(b.x - m) + expf(b.y - m) + expf(b.z - m) + expf(b.w - m);
    s += expf(c.x - m) + expf(c.y - m) + expf(c.z - m) + expf(c.w - m);
    s += expf(d.x - m) + expf(d.y - m) + expf(d.z - m) + expf(d.w - m);
    float lse = m + logf(s);
    a.x -= lse; a.y -= lse; a.z -= lse; a.w -= lse;
    b.x -= lse; b.y -= lse; b.z -= lse; b.w -= lse;
    c.x -= lse; c.y -= lse; c.z -= lse; c.w -= lse;
    d.x -= lse; d.y -= lse; d.z -= lse; d.w -= lse;
    p[0] = a; p[1] = b; p[2] = c; p[3] = d;
}

// ---------------------------------------------------------------------------
extern "C" void kernel_launch(void* const* d_in, const int* in_sizes, int n_in,
                              void* d_out, int out_size, void* d_ws, size_t ws_size,
                              hipStream_t stream) {
    const float* x     = (const float*)d_in[0];
    const int*   ei    = (const int*)d_in[1];
    const int*   src   = ei;
    const int*   dst   = ei + N_EDGES;
    const float* ew    = (const float*)d_in[2];
    const int*   et    = (const int*)d_in[3];
    const float* W1    = (const float*)d_in[4];
    const float* root1 = (const float*)d_in[5];
    const float* b1    = (const float*)d_in[6];
    const float* W2    = (const float*)d_in[7];
    const float* root2 = (const float*)d_in[8];
    const float* b2    = (const float*)d_in[9];
    float* out = (float*)d_out;

    // workspace layout (~100 MiB)
    char* ws = (char*)d_ws;
    int*    offs    = (int*)ws;                        //  2,000,004 B (M+1), pad to 2,000,896
    int*    ccur    = (int*)(ws + 2000896);            //      1,024 B
    int*    cstart  = (int*)(ws + 2001920);            //      2,176 B pad
    int2*   edges   = (int2*)(ws + 2004096);           // 12,800,000 B
    ushort* xh      = (ushort*)(ws + 14804096);        // 25,600,000 B
    ushort* h       = (ushort*)(ws + 40404096);        // 25,600,000 B
    ushort* Wt1     = (ushort*)(ws + 66004096);        //    196,608 B
    ushort* Wt2     = (ushort*)(ws + 66200704);        //     24,576 B
    // union region: pe (33.6 MB, CSR build only) then Achunk (38.5 MB, layers)
    int2*   pe      = (int2*)(ws + 66225280);
    ushort* Achunk  = (ushort*)(ws + 66225280);        // 25088*1536 B

    // --- precision conversions ---
    cvt_feat<<<((N_NODES * 128 / 4) + 255) / 256, 256, 0, stream>>>(x, xh);
    cvt_wstack<<<dim3(3, 128), 256, 0, stream>>>(W1, root1, Wt1, 128);
    cvt_wstack<<<dim3(3, 16), 256, 0, stream>>>(W2, root2, Wt2, 16);

    // --- build (dst,rel)-bucketed CSR: 3 passes, no random global atomics ---
    hipMemsetAsync(ccur, 0, 1024, stream);
    partition_append<<<(N_EDGES + 4095) / 4096, 1024, 0, stream>>>(src, dst, ew, et, ccur, pe);
    cscan<<<1, 256, 0, stream>>>(ccur, cstart, offs);
    bucket_sort<<<NCOARSE, 1024, 0, stream>>>(ccur, cstart, pe, edges, offs);

    const int ggrid = (CHUNK + 4 - 1) / 4;        // 6250 gather blocks / chunk
    const int mgrid = (CHUNK + 127) / 128;        // 196 gemm blocks / chunk

    // --- layer 1: h = bf16(relu(A1 @ Wt1^T + b1)), A1 = [x | agg_r(x)] ---
    for (int c = 0; c < NCHUNK; ++c) {
        gather_all<<<ggrid, 256, 0, stream>>>(xh, edges, offs, Achunk, c * CHUNK);
        gemm768<128, true, false><<<mgrid, 256, 0, stream>>>(
            Achunk, Wt1, b1, h, c * CHUNK, CHUNK);
    }

    // --- layer 2: out = A2 @ Wt2^T + b2, A2 = [h | agg_r(h)] ---
    for (int c = 0; c < NCHUNK; ++c) {
        gather_all<<<ggrid, 256, 0, stream>>>(h, edges, offs, Achunk, c * CHUNK);
        gemm768<16, false, true><<<mgrid, 256, 0, stream>>>(
            Achunk, Wt2, b2, out, c * CHUNK, CHUNK);
    }

    log_softmax16<<<(N_NODES + 255) / 256, 256, 0, stream>>>(out);
}

// Round 7
// 345.593 us; speedup vs baseline: 1.6291x; 1.2959x over previous
//
#include <hip/hip_runtime.h>

// Problem constants (from reference)
#define N_NODES 100000
#define N_EDGES 1600000
#define N_REL   5
#define M_BUCKETS (N_NODES * N_REL)          // 500000 (dst,rel) buckets
#define NCOARSE  196                         // ceil(N_NODES / 512) coarse buckets
#define CAP      16384                       // pe capacity per coarse bucket (avg 8163)

using bf16x8 = __attribute__((ext_vector_type(8))) short;
using f32x4  = __attribute__((ext_vector_type(4))) float;

__device__ __forceinline__ unsigned short f2bf(float f) {
    unsigned int u = __float_as_uint(f);
    u += 0x7fffu + ((u >> 16) & 1u);          // RNE
    return (unsigned short)(u >> 16);
}
__device__ __forceinline__ float bflo(unsigned int p) { return __uint_as_float(p << 16); }
__device__ __forceinline__ float bfhi(unsigned int p) { return __uint_as_float(p & 0xffff0000u); }

// ---------------------------------------------------------------------------
// Pass 1: append edges into coarse (dst>>9) regions of pe.
// Record = (src | rel<<17 | dlow9<<20, ew).
// ---------------------------------------------------------------------------
__global__ __launch_bounds__(1024) void partition_append(
    const int* __restrict__ src, const int* __restrict__ dstv,
    const float* __restrict__ ew, const int* __restrict__ et,
    int* __restrict__ ccur, int2* __restrict__ pe) {
    __shared__ int lh[256];
    __shared__ int lb[256];
    int tid = threadIdx.x;
    if (tid < 256) lh[tid] = 0;
    __syncthreads();
    int base = blockIdx.x * 4096;
    int key[4], rank[4], meta[4];
    float w[4];
    #pragma unroll
    for (int i = 0; i < 4; ++i) {
        int e = base + i * 1024 + tid;
        key[i] = -1;
        if (e < N_EDGES) {
            int d = dstv[e];
            key[i] = d >> 9;
            meta[i] = src[e] | (et[e] << 17) | ((d & 511) << 20);
            w[i] = ew[e];
            rank[i] = atomicAdd(&lh[key[i]], 1);
        }
    }
    __syncthreads();
    if (tid < 256) {
        int c = lh[tid];
        lb[tid] = c ? atomicAdd(&ccur[tid], c) : 0;
    }
    __syncthreads();
    #pragma unroll
    for (int i = 0; i < 4; ++i)
        if (key[i] >= 0) {
            int pos = lb[key[i]] + rank[i];
            if (pos < CAP)
                pe[((size_t)key[i] << 14) + pos] = make_int2(meta[i], __float_as_int(w[i]));
        }
}

// Pass 2 (tiny): exclusive scan of 256 coarse counts -> global bases; sentinel.
__global__ __launch_bounds__(256) void cscan(const int* __restrict__ ccur,
                                             int* __restrict__ cstart,
                                             int* __restrict__ offs) {
    __shared__ int lds[256];
    int tid = threadIdx.x;
    int v = ccur[tid];
    lds[tid] = v;
    __syncthreads();
    for (int d = 1; d < 256; d <<= 1) {
        int t = (tid >= d) ? lds[tid - d] : 0;
        __syncthreads();
        lds[tid] += t;
        __syncthreads();
    }
    cstart[tid] = lds[tid] - v;
    if (tid == 0) offs[M_BUCKETS] = N_EDGES;
}

// ---------------------------------------------------------------------------
// Pass 3: one block per coarse bucket: LDS fine-histogram + scan -> offs slice
// (coalesced) + scatter records to final dense order (64KB span, L2-local).
// Within each node, edges end up grouped by relation (ascending).
// ---------------------------------------------------------------------------
__global__ __launch_bounds__(1024) void bucket_sort(
    const int* __restrict__ ccnt, const int* __restrict__ cstart,
    const int2* __restrict__ pe, int2* __restrict__ edges, int* __restrict__ offs) {
    int cb = blockIdx.x;
    int node0 = cb << 9;
    if (node0 >= N_NODES) return;
    int nNodes = N_NODES - node0; if (nNodes > 512) nNodes = 512;
    int nf = nNodes * N_REL;                 // fine buckets in this block (<=2560)
    __shared__ int hist[2560];
    __shared__ int cur[2560];
    __shared__ int sums[1024];
    int tid = threadIdx.x;
    int cnt = ccnt[cb]; if (cnt > CAP) cnt = CAP;
    int gbase = cstart[cb];
    const int2* my = pe + ((size_t)cb << 14);

    for (int i = tid; i < nf; i += 1024) hist[i] = 0;
    __syncthreads();
    for (int i = tid; i < cnt; i += 1024) {
        int m = my[i].x;
        int fb = ((m >> 20) & 511) * N_REL + ((m >> 17) & 7);
        atomicAdd(&hist[fb], 1);
    }
    __syncthreads();

    int t0 = tid * 3;
    int a0 = (t0 + 0 < nf) ? hist[t0 + 0] : 0;
    int a1 = (t0 + 1 < nf) ? hist[t0 + 1] : 0;
    int a2 = (t0 + 2 < nf) ? hist[t0 + 2] : 0;
    int s = a0 + a1 + a2;
    sums[tid] = s;
    __syncthreads();
    for (int d = 1; d < 1024; d <<= 1) {
        int t = (tid >= d) ? sums[tid - d] : 0;
        __syncthreads();
        sums[tid] += t;
        __syncthreads();
    }
    int excl = sums[tid] - s;
    int gb0 = node0 * N_REL;
    if (t0 + 0 < nf) { offs[gb0 + t0 + 0] = gbase + excl; cur[t0 + 0] = excl; }
    excl += a0;
    if (t0 + 1 < nf) { offs[gb0 + t0 + 1] = gbase + excl; cur[t0 + 1] = excl; }
    excl += a1;
    if (t0 + 2 < nf) { offs[gb0 + t0 + 2] = gbase + excl; cur[t0 + 2] = excl; }
    __syncthreads();

    for (int i = tid; i < cnt; i += 1024) {
        int2 r = my[i];
        int fb = ((r.x >> 20) & 511) * N_REL + ((r.x >> 17) & 7);
        int pos = gbase + atomicAdd(&cur[fb], 1);
        edges[pos] = make_int2(r.x & 0x1FFFF, r.y);   // keep src only (17 bits)
    }
}

// ---------------------------------------------------------------------------
// Precision conversions (once per launch)
// ---------------------------------------------------------------------------
__global__ void cvt_feat(const float* __restrict__ x, ushort* __restrict__ xh) {
    int i = blockIdx.x * blockDim.x + threadIdx.x;   // float4 index
    if (i >= (N_NODES * 128) / 4) return;
    float4 v = reinterpret_cast<const float4*>(x)[i];
    ushort4 o;
    o.x = f2bf(v.x); o.y = f2bf(v.y); o.z = f2bf(v.z); o.w = f2bf(v.w);
    reinterpret_cast<ushort4*>(xh)[i] = o;
}

// Stack [root; W_0..W_4] transposed: Wt[o][seg*128+k], seg0=root, seg r+1=W_r.
__global__ void cvt_wstack(const float* __restrict__ W, const float* __restrict__ root,
                           ushort* __restrict__ Wt, int NN) {
    int t = blockIdx.x * blockDim.x + threadIdx.x;   // 0..767
    int o = blockIdx.y;
    int seg = t >> 7, k = t & 127;
    float v = (seg == 0) ? root[k * NN + o] : W[(size_t)(seg - 1) * 128 * NN + k * NN + o];
    Wt[(size_t)o * 768 + t] = f2bf(v);
}

// ---------------------------------------------------------------------------
// Gather-aggregate, one wave per node. Edges are relation-sorted within the
// node, so each relation is a contiguous sub-range: process with 2 live
// accumulators, no relation-select. ~8 VALU/edge. Pad to x4 for load ILP;
// padded lanes have (src=0, w=0) from the guarded batch load -> contribute 0.
// A[n-node0][768] = [own(128) | mean_r0..mean_r4].
// ---------------------------------------------------------------------------
__global__ __launch_bounds__(256) void gather_all(
    const ushort* __restrict__ feat,   // bf16 [N][128]
    const int2* __restrict__ edges,    // (src, w) relation-sorted per node
    const int* __restrict__ offs,      // exclusive starts, offs[M]=E
    ushort* __restrict__ A,            // [>=rows][768] bf16
    int node0) {
    int n = __builtin_amdgcn_readfirstlane(node0 + blockIdx.x * 4 + (threadIdx.x >> 6));
    int lane = threadIdx.x & 63;
    int b0 = n * N_REL;
    int o[6];
    #pragma unroll
    for (int r = 0; r < 6; ++r) o[r] = offs[b0 + r];
    const unsigned int* fp = reinterpret_cast<const unsigned int*>(feat);

    unsigned int* Ap = reinterpret_cast<unsigned int*>(A) + (size_t)(n - node0) * 384;
    Ap[lane] = fp[(size_t)n * 64 + lane];     // own features (root segment)

    #pragma unroll
    for (int r = 0; r < 5; ++r) {
        int s0 = o[r], e1 = o[r + 1];
        float ax = 0.f, ay = 0.f;
        for (int base = s0; base < e1; base += 64) {
            int idx = base + lane;
            int2 er = (idx < e1) ? edges[idx] : make_int2(0, 0);
            int m = e1 - base; if (m > 64) m = 64;
            int m4 = (m + 3) & ~3;
            for (int j = 0; j < m4; j += 4) {
                #pragma unroll
                for (int u = 0; u < 4; ++u) {
                    int sidx = __builtin_amdgcn_readlane(er.x, j + u);
                    float w = __uint_as_float(__builtin_amdgcn_readlane(er.y, j + u));
                    unsigned int p = fp[((size_t)sidx << 6) + lane];
                    ax = fmaf(w, bflo(p), ax);
                    ay = fmaf(w, bfhi(p), ay);
                }
            }
        }
        float inv = (e1 > s0) ? 1.f / (float)(e1 - s0) : 0.f;
        Ap[64 * (r + 1) + lane] =
            (unsigned int)f2bf(ax * inv) | ((unsigned int)f2bf(ay * inv) << 16);
    }
}

// ---------------------------------------------------------------------------
// GEMM: out[row][BN] = A[row][768] @ Wt[BN][768]^T + bias (+relu)
// ---------------------------------------------------------------------------
template<int BN, bool RELU, bool F32OUT>
__global__ __launch_bounds__(256) void gemm768(
    const ushort* __restrict__ A,    // chunk-local [rows][768] bf16
    const ushort* __restrict__ Wt,   // [BN][768] bf16
    const float* __restrict__ bias,  // [BN]
    void* __restrict__ outp,         // bf16 [N][BN] or f32 [N][BN]
    int row0, int nrows) {
    __shared__ ushort As[128 * 64];          // 16 KB
    __shared__ ushort Bs[BN * 64];           // 16 KB | 2 KB
    const int tid = threadIdx.x, lane = tid & 63, wave = tid >> 6;
    const int m0 = blockIdx.x * 128;         // chunk-local row base

    constexpr int MF = (BN == 128) ? 4 : 2;
    constexpr int NF = (BN == 128) ? 4 : 1;
    const int wr0 = (BN == 128) ? (wave >> 1) * 64 : wave * 32;
    const int wc0 = (BN == 128) ? (wave & 1) * 64 : 0;

    f32x4 acc[MF][NF] = {};

    for (int ks = 0; ks < 12; ++ks) {
        #pragma unroll
        for (int u = 0; u < 4; ++u) {
            int idx = tid + u * 256;
            int row = idx >> 3, slot = idx & 7;
            float4 v = *reinterpret_cast<const float4*>(
                A + (size_t)(m0 + row) * 768 + ks * 64 + slot * 8);
            int byte = row * 128 + ((slot ^ (row & 7)) << 4);
            *reinterpret_cast<float4*>(reinterpret_cast<char*>(As) + byte) = v;
        }
        constexpr int BCH = BN * 8;
        #pragma unroll
        for (int u = 0; u < (BCH + 255) / 256; ++u) {
            int idx = tid + u * 256;
            if ((BCH % 256) && idx >= BCH) break;
            int row = idx >> 3, slot = idx & 7;
            float4 v = *reinterpret_cast<const float4*>(
                Wt + (size_t)row * 768 + ks * 64 + slot * 8);
            int byte = row * 128 + ((slot ^ (row & 7)) << 4);
            *reinterpret_cast<float4*>(reinterpret_cast<char*>(Bs) + byte) = v;
        }
        __syncthreads();

        #pragma unroll
        for (int kh = 0; kh < 2; ++kh) {
            bf16x8 af[MF], bfr[NF];
            #pragma unroll
            for (int m = 0; m < MF; ++m) {
                int row = wr0 + m * 16 + (lane & 15);
                int slot = kh * 4 + (lane >> 4);
                int byte = row * 128 + ((slot ^ (row & 7)) << 4);
                af[m] = *reinterpret_cast<const bf16x8*>(
                    reinterpret_cast<const char*>(As) + byte);
            }
            #pragma unroll
            for (int nn = 0; nn < NF; ++nn) {
                int row = wc0 + nn * 16 + (lane & 15);
                int slot = kh * 4 + (lane >> 4);
                int byte = row * 128 + ((slot ^ (row & 7)) << 4);
                bfr[nn] = *reinterpret_cast<const bf16x8*>(
                    reinterpret_cast<const char*>(Bs) + byte);
            }
            #pragma unroll
            for (int m = 0; m < MF; ++m)
                #pragma unroll
                for (int nn = 0; nn < NF; ++nn)
                    acc[m][nn] = __builtin_amdgcn_mfma_f32_16x16x32_bf16(
                        af[m], bfr[nn], acc[m][nn], 0, 0, 0);
        }
        __syncthreads();
    }

    #pragma unroll
    for (int m = 0; m < MF; ++m) {
        int rloc = wr0 + m * 16 + (lane >> 4) * 4;
        #pragma unroll
        for (int nn = 0; nn < NF; ++nn) {
            int c = wc0 + nn * 16 + (lane & 15);
            float bv = bias[c];
            #pragma unroll
            for (int q = 0; q < 4; ++q) {
                int lrow = m0 + rloc + q;
                if (lrow < nrows) {
                    int grow = row0 + lrow;
                    float v = acc[m][nn][q] + bv;
                    if (RELU) v = fmaxf(v, 0.f);
                    if (F32OUT)
                        reinterpret_cast<float*>(outp)[(size_t)grow * BN + c] = v;
                    else
                        reinterpret_cast<ushort*>(outp)[(size_t)grow * BN + c] = f2bf(v);
                }
            }
        }
    }
}

// ---------------------------------------------------------------------------
// In-place log_softmax over rows of 16.
// ---------------------------------------------------------------------------
__global__ void log_softmax16(float* __restrict__ out) {
    int n = blockIdx.x * blockDim.x + threadIdx.x;
    if (n >= N_NODES) return;
    float4* p = reinterpret_cast<float4*>(out + (size_t)n * 16);
    float4 a = p[0], b = p[1], c = p[2], d = p[3];
    float m = a.x;
    m = fmaxf(m, a.y); m = fmaxf(m, a.z); m = fmaxf(m, a.w);
    m = fmaxf(m, b.x); m = fmaxf(m, b.y); m = fmaxf(m, b.z); m = fmaxf(m, b.w);
    m = fmaxf(m, c.x); m = fmaxf(m, c.y); m = fmaxf(m, c.z); m = fmaxf(m, c.w);
    m = fmaxf(m, d.x); m = fmaxf(m, d.y); m = fmaxf(m, d.z); m = fmaxf(m, d.w);
    float s = 0.f;
    s += expf(a.x - m) + expf(a.y - m) + expf(a.z - m) + expf(a.w - m);
    s += expf(b.x - m) + expf(b.y - m) + expf(b.z - m) + expf(b.w - m);
    s += expf(c.x - m) + expf(c.y - m) + expf(c.z - m) + expf(c.w - m);
    s += expf(d.x - m) + expf(d.y - m) + expf(d.z - m) + expf(d.w - m);
    float lse = m + logf(s);
    a.x -= lse; a.y -= lse; a.z -= lse; a.w -= lse;
    b.x -= lse; b.y -= lse; b.z -= lse; b.w -= lse;
    c.x -= lse; c.y -= lse; c.z -= lse; c.w -= lse;
    d.x -= lse; d.y -= lse; d.z -= lse; d.w -= lse;
    p[0] = a; p[1] = b; p[2] = c; p[3] = d;
}

// ---------------------------------------------------------------------------
extern "C" void kernel_launch(void* const* d_in, const int* in_sizes, int n_in,
                              void* d_out, int out_size, void* d_ws, size_t ws_size,
                              hipStream_t stream) {
    const float* x     = (const float*)d_in[0];
    const int*   ei    = (const int*)d_in[1];
    const int*   src   = ei;
    const int*   dst   = ei + N_EDGES;
    const float* ew    = (const float*)d_in[2];
    const int*   et    = (const int*)d_in[3];
    const float* W1    = (const float*)d_in[4];
    const float* root1 = (const float*)d_in[5];
    const float* b1    = (const float*)d_in[6];
    const float* W2    = (const float*)d_in[7];
    const float* root2 = (const float*)d_in[8];
    const float* b2    = (const float*)d_in[9];
    float* out = (float*)d_out;

    // workspace layout
    char* ws = (char*)d_ws;
    int*    offs    = (int*)ws;                        //  2,000,004 B (M+1), pad to 2,000,896
    int*    ccur    = (int*)(ws + 2000896);            //      1,024 B
    int*    cstart  = (int*)(ws + 2001920);            //      2,176 B pad
    int2*   edges   = (int2*)(ws + 2004096);           // 12,800,000 B
    ushort* xh      = (ushort*)(ws + 14804096);        // 25,600,000 B
    ushort* h       = (ushort*)(ws + 40404096);        // 25,600,000 B
    ushort* Wt1     = (ushort*)(ws + 66004096);        //    196,608 B
    ushort* Wt2     = (ushort*)(ws + 66200704);        //     24,576 B
    // union region @66,225,280: pe (25.7 MB, build only) then A (layers)
    int2*   pe      = (int2*)(ws + 66225280);
    ushort* Abuf    = (ushort*)(ws + 66225280);

    // chunking: single chunk if workspace allows (A = 100096*1536 = 153.7 MB)
    const int chunk = (ws_size >= 220000000ull) ? N_NODES : 25000;
    const int nch   = N_NODES / chunk;

    // --- precision conversions ---
    cvt_feat<<<((N_NODES * 128 / 4) + 255) / 256, 256, 0, stream>>>(x, xh);
    cvt_wstack<<<dim3(3, 128), 256, 0, stream>>>(W1, root1, Wt1, 128);
    cvt_wstack<<<dim3(3, 16), 256, 0, stream>>>(W2, root2, Wt2, 16);

    // --- build (dst,rel)-bucketed CSR: 3 passes, no random global atomics ---
    hipMemsetAsync(ccur, 0, 1024, stream);
    partition_append<<<(N_EDGES + 4095) / 4096, 1024, 0, stream>>>(src, dst, ew, et, ccur, pe);
    cscan<<<1, 256, 0, stream>>>(ccur, cstart, offs);
    bucket_sort<<<NCOARSE, 1024, 0, stream>>>(ccur, cstart, pe, edges, offs);

    const int ggrid = chunk / 4;                  // gather blocks / chunk
    const int mgrid = (chunk + 127) / 128;        // gemm blocks / chunk

    // --- layer 1: h = bf16(relu(A1 @ Wt1^T + b1)), A1 = [x | agg_r(x)] ---
    for (int c = 0; c < nch; ++c) {
        gather_all<<<ggrid, 256, 0, stream>>>(xh, edges, offs, Abuf, c * chunk);
        gemm768<128, true, false><<<mgrid, 256, 0, stream>>>(
            Abuf, Wt1, b1, h, c * chunk, chunk);
    }

    // --- layer 2: out = A2 @ Wt2^T + b2, A2 = [h | agg_r(h)] ---
    for (int c = 0; c < nch; ++c) {
        gather_all<<<ggrid, 256, 0, stream>>>(h, edges, offs, Abuf, c * chunk);
        gemm768<16, false, true><<<mgrid, 256, 0, stream>>>(
            Abuf, Wt2, b2, out, c * chunk, chunk);
    }

    log_softmax16<<<(N_NODES + 255) / 256, 256, 0, stream>>>(out);
}

// Round 8
// 259.361 us; speedup vs baseline: 2.1708x; 1.3325x over previous
//
#include <hip/hip_runtime.h>

// Problem constants (from reference)
#define N_NODES 100000
#define N_EDGES 1600000
#define N_REL   5
#define M_BUCKETS (N_NODES * N_REL)          // 500000 (dst,rel) buckets
#define NCOARSE  196                         // ceil(N_NODES / 512) coarse buckets
#define CAP      16384                       // pe capacity per coarse bucket (avg 8163)

using bf16x8 = __attribute__((ext_vector_type(8))) short;
using f32x4  = __attribute__((ext_vector_type(4))) float;

__device__ __forceinline__ unsigned short f2bf(float f) {
    unsigned int u = __float_as_uint(f);
    u += 0x7fffu + ((u >> 16) & 1u);          // RNE
    return (unsigned short)(u >> 16);
}
__device__ __forceinline__ float bflo(unsigned int p) { return __uint_as_float(p << 16); }
__device__ __forceinline__ float bfhi(unsigned int p) { return __uint_as_float(p & 0xffff0000u); }

// ---------------------------------------------------------------------------
// Pass 1: append edges into coarse (dst>>9) regions of pe.
// Record = (src | rel<<17 | dlow9<<20, ew).
// ---------------------------------------------------------------------------
__global__ __launch_bounds__(1024) void partition_append(
    const int* __restrict__ src, const int* __restrict__ dstv,
    const float* __restrict__ ew, const int* __restrict__ et,
    int* __restrict__ ccur, int2* __restrict__ pe) {
    __shared__ int lh[256];
    __shared__ int lb[256];
    int tid = threadIdx.x;
    if (tid < 256) lh[tid] = 0;
    __syncthreads();
    int base = blockIdx.x * 4096;
    int key[4], rank[4], meta[4];
    float w[4];
    #pragma unroll
    for (int i = 0; i < 4; ++i) {
        int e = base + i * 1024 + tid;
        key[i] = -1;
        if (e < N_EDGES) {
            int d = dstv[e];
            key[i] = d >> 9;
            meta[i] = src[e] | (et[e] << 17) | ((d & 511) << 20);
            w[i] = ew[e];
            rank[i] = atomicAdd(&lh[key[i]], 1);
        }
    }
    __syncthreads();
    if (tid < 256) {
        int c = lh[tid];
        lb[tid] = c ? atomicAdd(&ccur[tid], c) : 0;
    }
    __syncthreads();
    #pragma unroll
    for (int i = 0; i < 4; ++i)
        if (key[i] >= 0) {
            int pos = lb[key[i]] + rank[i];
            if (pos < CAP)
                pe[((size_t)key[i] << 14) + pos] = make_int2(meta[i], __float_as_int(w[i]));
        }
}

// Pass 2 (tiny): exclusive scan of 256 coarse counts -> global bases; sentinel.
__global__ __launch_bounds__(256) void cscan(const int* __restrict__ ccur,
                                             int* __restrict__ cstart,
                                             int* __restrict__ offs) {
    __shared__ int lds[256];
    int tid = threadIdx.x;
    int v = ccur[tid];
    lds[tid] = v;
    __syncthreads();
    for (int d = 1; d < 256; d <<= 1) {
        int t = (tid >= d) ? lds[tid - d] : 0;
        __syncthreads();
        lds[tid] += t;
        __syncthreads();
    }
    cstart[tid] = lds[tid] - v;
    if (tid == 0) offs[M_BUCKETS] = N_EDGES;
}

// ---------------------------------------------------------------------------
// Pass 3: one block per coarse bucket: LDS fine-histogram + scan -> offs slice
// + scatter to final dense order. Keeps rel bits (17-19); folds 1/deg into w
// (mean = sum of w/deg). Within a node, edges grouped by relation ascending.
// ---------------------------------------------------------------------------
__global__ __launch_bounds__(1024) void bucket_sort(
    const int* __restrict__ ccnt, const int* __restrict__ cstart,
    const int2* __restrict__ pe, int2* __restrict__ edges, int* __restrict__ offs) {
    int cb = blockIdx.x;
    int node0 = cb << 9;
    if (node0 >= N_NODES) return;
    int nNodes = N_NODES - node0; if (nNodes > 512) nNodes = 512;
    int nf = nNodes * N_REL;                 // fine buckets in this block (<=2560)
    __shared__ int hist[2560];
    __shared__ int cur[2560];
    __shared__ int sums[1024];
    int tid = threadIdx.x;
    int cnt = ccnt[cb]; if (cnt > CAP) cnt = CAP;
    int gbase = cstart[cb];
    const int2* my = pe + ((size_t)cb << 14);

    for (int i = tid; i < nf; i += 1024) hist[i] = 0;
    __syncthreads();
    for (int i = tid; i < cnt; i += 1024) {
        int m = my[i].x;
        int fb = ((m >> 20) & 511) * N_REL + ((m >> 17) & 7);
        atomicAdd(&hist[fb], 1);
    }
    __syncthreads();

    int t0 = tid * 3;
    int a0 = (t0 + 0 < nf) ? hist[t0 + 0] : 0;
    int a1 = (t0 + 1 < nf) ? hist[t0 + 1] : 0;
    int a2 = (t0 + 2 < nf) ? hist[t0 + 2] : 0;
    int s = a0 + a1 + a2;
    sums[tid] = s;
    __syncthreads();
    for (int d = 1; d < 1024; d <<= 1) {
        int t = (tid >= d) ? sums[tid - d] : 0;
        __syncthreads();
        sums[tid] += t;
        __syncthreads();
    }
    int excl = sums[tid] - s;
    int gb0 = node0 * N_REL;
    if (t0 + 0 < nf) { offs[gb0 + t0 + 0] = gbase + excl; cur[t0 + 0] = excl; }
    excl += a0;
    if (t0 + 1 < nf) { offs[gb0 + t0 + 1] = gbase + excl; cur[t0 + 1] = excl; }
    excl += a1;
    if (t0 + 2 < nf) { offs[gb0 + t0 + 2] = gbase + excl; cur[t0 + 2] = excl; }
    __syncthreads();

    for (int i = tid; i < cnt; i += 1024) {
        int2 r = my[i];
        int fb = ((r.x >> 20) & 511) * N_REL + ((r.x >> 17) & 7);
        int pos = gbase + atomicAdd(&cur[fb], 1);
        float wf = __int_as_float(r.y) / (float)hist[fb];   // fold 1/deg
        edges[pos] = make_int2(r.x & 0xFFFFF, __float_as_int(wf)); // src|rel<<17
    }
}

// ---------------------------------------------------------------------------
// Precision conversions (once per launch)
// ---------------------------------------------------------------------------
__global__ void cvt_feat(const float* __restrict__ x, ushort* __restrict__ xh) {
    int i = blockIdx.x * blockDim.x + threadIdx.x;   // float4 index
    if (i >= (N_NODES * 128) / 4) return;
    float4 v = reinterpret_cast<const float4*>(x)[i];
    ushort4 o;
    o.x = f2bf(v.x); o.y = f2bf(v.y); o.z = f2bf(v.z); o.w = f2bf(v.w);
    reinterpret_cast<ushort4*>(xh)[i] = o;
}

// Stack [root1; W1_0..W1_4] transposed: Wt[o][seg*128+k] (o: 128 outs).
__global__ void cvt_wstack(const float* __restrict__ W, const float* __restrict__ root,
                           ushort* __restrict__ Wt) {
    int t = blockIdx.x * blockDim.x + threadIdx.x;   // 0..767
    int o = blockIdx.y;
    int seg = t >> 7, k = t & 127;
    float v = (seg == 0) ? root[k * 128 + o] : W[(size_t)(seg - 1) * 128 * 128 + k * 128 + o];
    Wt[(size_t)o * 768 + t] = f2bf(v);
}

// Layer-2 stacked weights: Wt2s[o][k], o in 0..95: cols 0-15 root2, 16+r*16+c = W2_r col c.
__global__ void cvt_w2(const float* __restrict__ W2, const float* __restrict__ root2,
                       ushort* __restrict__ Wt2s) {
    int i = blockIdx.x * blockDim.x + threadIdx.x;
    if (i >= 96 * 128) return;
    int o = i >> 7, k = i & 127;
    float v = (o < 16) ? root2[k * 16 + o]
                       : W2[((size_t)((o >> 4) - 1) * 128 + k) * 16 + (o & 15)];
    Wt2s[i] = f2bf(v);
}

// ---------------------------------------------------------------------------
// Layer-1 gather: one wave per node, single edge batch per node (deg<=64 fast
// path; relation sub-ranges walked by scalar readlane — no relation select,
// no per-relation batch overfetch). 1/deg pre-folded. Writes A640 only
// (aggregates; own features staged by the GEMM directly from xh).
// ---------------------------------------------------------------------------
__global__ __launch_bounds__(256) void gather_all(
    const ushort* __restrict__ feat,   // bf16 [N][128]
    const int2* __restrict__ edges,    // (src|rel<<17, w/deg) relation-sorted
    const int* __restrict__ offs,      // exclusive starts, offs[M]=E
    ushort* __restrict__ A,            // [rows][640] bf16
    int node0) {
    int n = __builtin_amdgcn_readfirstlane(node0 + blockIdx.x * 4 + (threadIdx.x >> 6));
    int lane = threadIdx.x & 63;
    int b0 = n * N_REL;
    int o[6];
    #pragma unroll
    for (int r = 0; r < 6; ++r) o[r] = __builtin_amdgcn_readfirstlane(offs[b0 + r]);
    const unsigned int* fp = reinterpret_cast<const unsigned int*>(feat);
    unsigned int* Ap = reinterpret_cast<unsigned int*>(A) + (size_t)(n - node0) * 320;

    int deg = o[5] - o[0];
    if (deg <= 64) {
        int2 er = (o[0] + lane < o[5]) ? edges[o[0] + lane] : make_int2(0, 0);
        #pragma unroll
        for (int r = 0; r < 5; ++r) {
            int jb = o[r] - o[0], je = o[r + 1] - o[0];
            float ax = 0.f, ay = 0.f;
            for (int j = jb; j < je; ++j) {
                int m = __builtin_amdgcn_readlane(er.x, j);
                float w = __uint_as_float(__builtin_amdgcn_readlane(er.y, j));
                unsigned int p = fp[((size_t)(m & 0x1FFFF) << 6) + lane];
                ax = fmaf(w, bflo(p), ax);
                ay = fmaf(w, bfhi(p), ay);
            }
            Ap[64 * r + lane] = (unsigned int)f2bf(ax) | ((unsigned int)f2bf(ay) << 16);
        }
    } else {
        #pragma unroll
        for (int r = 0; r < 5; ++r) {
            int s0 = o[r], e1 = o[r + 1];
            float ax = 0.f, ay = 0.f;
            for (int base = s0; base < e1; base += 64) {
                int idx = base + lane;
                int2 er = (idx < e1) ? edges[idx] : make_int2(0, 0);
                int m = e1 - base; if (m > 64) m = 64;
                for (int j = 0; j < m; ++j) {
                    int mm = __builtin_amdgcn_readlane(er.x, j);
                    float w = __uint_as_float(__builtin_amdgcn_readlane(er.y, j));
                    unsigned int p = fp[((size_t)(mm & 0x1FFFF) << 6) + lane];
                    ax = fmaf(w, bflo(p), ax);
                    ay = fmaf(w, bfhi(p), ay);
                }
            }
            Ap[64 * r + lane] = (unsigned int)f2bf(ax) | ((unsigned int)f2bf(ay) << 16);
        }
    }
}

// ---------------------------------------------------------------------------
// Layer-1 GEMM: h[row][128] = relu([xh_row | A640_row] @ Wt1[128][768]^T + b1)
// K-segment 0-1 staged from xh directly (no own-copy in A).
// ---------------------------------------------------------------------------
__global__ __launch_bounds__(256) void gemmL1(
    const ushort* __restrict__ xh,   // [N][128] bf16
    const ushort* __restrict__ A,    // chunk-local [rows][640] bf16
    const ushort* __restrict__ Wt,   // [128][768] bf16
    const float* __restrict__ bias,  // [128]
    ushort* __restrict__ h,          // [N][128] bf16
    int row0, int nrows) {
    __shared__ ushort As[128 * 64];          // 16 KB
    __shared__ ushort Bs[128 * 64];          // 16 KB
    const int tid = threadIdx.x, lane = tid & 63, wave = tid >> 6;
    const int m0 = blockIdx.x * 128;

    constexpr int MF = 4, NF = 4;
    const int wr0 = (wave >> 1) * 64;
    const int wc0 = (wave & 1) * 64;

    f32x4 acc[MF][NF] = {};

    for (int ks = 0; ks < 12; ++ks) {
        #pragma unroll
        for (int u = 0; u < 4; ++u) {
            int idx = tid + u * 256;
            int row = idx >> 3, slot = idx & 7;
            float4 v;
            if (ks < 2) {
                int gr = row0 + m0 + row; if (gr >= N_NODES) gr = N_NODES - 1;
                v = *reinterpret_cast<const float4*>(xh + (size_t)gr * 128 + ks * 64 + slot * 8);
            } else {
                v = *reinterpret_cast<const float4*>(
                    A + (size_t)(m0 + row) * 640 + (ks - 2) * 64 + slot * 8);
            }
            int byte = row * 128 + ((slot ^ (row & 7)) << 4);
            *reinterpret_cast<float4*>(reinterpret_cast<char*>(As) + byte) = v;
        }
        #pragma unroll
        for (int u = 0; u < 4; ++u) {
            int idx = tid + u * 256;
            int row = idx >> 3, slot = idx & 7;
            float4 v = *reinterpret_cast<const float4*>(
                Wt + (size_t)row * 768 + ks * 64 + slot * 8);
            int byte = row * 128 + ((slot ^ (row & 7)) << 4);
            *reinterpret_cast<float4*>(reinterpret_cast<char*>(Bs) + byte) = v;
        }
        __syncthreads();

        #pragma unroll
        for (int kh = 0; kh < 2; ++kh) {
            bf16x8 af[MF], bfr[NF];
            #pragma unroll
            for (int m = 0; m < MF; ++m) {
                int row = wr0 + m * 16 + (lane & 15);
                int slot = kh * 4 + (lane >> 4);
                int byte = row * 128 + ((slot ^ (row & 7)) << 4);
                af[m] = *reinterpret_cast<const bf16x8*>(
                    reinterpret_cast<const char*>(As) + byte);
            }
            #pragma unroll
            for (int nn = 0; nn < NF; ++nn) {
                int row = wc0 + nn * 16 + (lane & 15);
                int slot = kh * 4 + (lane >> 4);
                int byte = row * 128 + ((slot ^ (row & 7)) << 4);
                bfr[nn] = *reinterpret_cast<const bf16x8*>(
                    reinterpret_cast<const char*>(Bs) + byte);
            }
            #pragma unroll
            for (int m = 0; m < MF; ++m)
                #pragma unroll
                for (int nn = 0; nn < NF; ++nn)
                    acc[m][nn] = __builtin_amdgcn_mfma_f32_16x16x32_bf16(
                        af[m], bfr[nn], acc[m][nn], 0, 0, 0);
        }
        __syncthreads();
    }

    #pragma unroll
    for (int m = 0; m < MF; ++m) {
        int rloc = wr0 + m * 16 + (lane >> 4) * 4;
        #pragma unroll
        for (int nn = 0; nn < NF; ++nn) {
            int c = wc0 + nn * 16 + (lane & 15);
            float bv = bias[c];
            #pragma unroll
            for (int q = 0; q < 4; ++q) {
                int lrow = m0 + rloc + q;
                if (lrow < nrows) {
                    int grow = row0 + lrow;
                    float v = fmaxf(acc[m][nn][q] + bv, 0.f);
                    h[(size_t)grow * 128 + c] = f2bf(v);
                }
            }
        }
    }
}

// ---------------------------------------------------------------------------
// Layer-2 transform: Y[n][96] = h[n][128] @ Wt2s[96][128]^T   (f32 out)
// ---------------------------------------------------------------------------
__global__ __launch_bounds__(256) void gemm96(
    const ushort* __restrict__ h, const ushort* __restrict__ Wt,
    float* __restrict__ Y) {
    __shared__ ushort As[128 * 128];   // 32 KB
    __shared__ ushort Bs[96 * 128];    // 24 KB
    const int tid = threadIdx.x, lane = tid & 63, wave = tid >> 6;
    const int m0 = blockIdx.x * 128;

    // stage As (128 rows x 16 slots of 16B, swizzled by row&15)
    #pragma unroll
    for (int u = 0; u < 8; ++u) {
        int idx = tid + u * 256;
        int row = idx >> 4, slot = idx & 15;
        int gr = m0 + row; if (gr >= N_NODES) gr = N_NODES - 1;
        float4 v = *reinterpret_cast<const float4*>(h + (size_t)gr * 128 + slot * 8);
        int byte = row * 256 + ((slot ^ (row & 15)) << 4);
        *reinterpret_cast<float4*>(reinterpret_cast<char*>(As) + byte) = v;
    }
    #pragma unroll
    for (int u = 0; u < 6; ++u) {
        int idx = tid + u * 256;
        int row = idx >> 4, slot = idx & 15;
        float4 v = *reinterpret_cast<const float4*>(Wt + (size_t)row * 128 + slot * 8);
        int byte = row * 256 + ((slot ^ (row & 15)) << 4);
        *reinterpret_cast<float4*>(reinterpret_cast<char*>(Bs) + byte) = v;
    }
    __syncthreads();

    f32x4 acc[2][6] = {};
    #pragma unroll
    for (int ks = 0; ks < 4; ++ks) {
        bf16x8 af[2], bfr[6];
        #pragma unroll
        for (int m = 0; m < 2; ++m) {
            int row = wave * 32 + m * 16 + (lane & 15);
            int slot = ks * 4 + (lane >> 4);
            int byte = row * 256 + ((slot ^ (row & 15)) << 4);
            af[m] = *reinterpret_cast<const bf16x8*>(reinterpret_cast<const char*>(As) + byte);
        }
        #pragma unroll
        for (int nn = 0; nn < 6; ++nn) {
            int row = nn * 16 + (lane & 15);
            int slot = ks * 4 + (lane >> 4);
            int byte = row * 256 + ((slot ^ (row & 15)) << 4);
            bfr[nn] = *reinterpret_cast<const bf16x8*>(reinterpret_cast<const char*>(Bs) + byte);
        }
        #pragma unroll
        for (int m = 0; m < 2; ++m)
            #pragma unroll
            for (int nn = 0; nn < 6; ++nn)
                acc[m][nn] = __builtin_amdgcn_mfma_f32_16x16x32_bf16(
                    af[m], bfr[nn], acc[m][nn], 0, 0, 0);
    }

    #pragma unroll
    for (int m = 0; m < 2; ++m) {
        int rloc = m0 + wave * 32 + m * 16 + (lane >> 4) * 4;
        #pragma unroll
        for (int nn = 0; nn < 6; ++nn) {
            int c = nn * 16 + (lane & 15);
            #pragma unroll
            for (int q = 0; q < 4; ++q) {
                int row = rloc + q;
                if (row < N_NODES) Y[(size_t)row * 96 + c] = acc[m][nn][q];
            }
        }
    }
}

// ---------------------------------------------------------------------------
// Layer-2 aggregate + bias + log_softmax, fused. 4 nodes/wave, 16 lanes/node.
// out[n][c] = logsoftmax( Y[n][c] + b2[c] + sum_e w_e * Y[src_e][16+rel*16+c] )
// (w pre-divided by deg). Edge walk via per-lane __shfl from 16-record batches.
// ---------------------------------------------------------------------------
__global__ __launch_bounds__(256) void agg2_softmax(
    const float* __restrict__ Y, const int2* __restrict__ edges,
    const int* __restrict__ offs, const float* __restrict__ b2,
    float* __restrict__ out) {
    int wave = threadIdx.x >> 6, lane = threadIdx.x & 63;
    int q = lane >> 4, c = lane & 15;
    int n = (blockIdx.x * 4 + wave) * 4 + q;
    int nn = (n < N_NODES) ? n : N_NODES - 1;
    int o0 = offs[nn * N_REL], o5 = offs[nn * N_REL + 5];
    int deg = o5 - o0;

    float val = Y[(size_t)nn * 96 + c] + b2[c];

    int md = deg;
    md = max(md, __shfl_xor(md, 16));
    md = max(md, __shfl_xor(md, 32));
    md = __builtin_amdgcn_readfirstlane(md);

    for (int b = 0; b < md; b += 16) {
        int idx = o0 + b + c;
        int2 er = (idx < o5) ? edges[idx] : make_int2(0, 0);   // (0,0) pads: w=0
        #pragma unroll
        for (int j = 0; j < 16; ++j) {
            int m = __shfl(er.x, q * 16 + j);
            float w = __uint_as_float(__shfl(er.y, q * 16 + j));
            int s = m & 0x1FFFF;
            int rel = (m >> 17) & 7;
            val = fmaf(w, Y[(size_t)s * 96 + 16 + rel * 16 + c], val);
        }
    }

    // log_softmax over the 16-lane group
    float mx = val;
    #pragma unroll
    for (int i = 1; i < 16; i <<= 1) mx = fmaxf(mx, __shfl_xor(mx, i));
    float ex = expf(val - mx);
    float ssum = ex;
    #pragma unroll
    for (int i = 1; i < 16; i <<= 1) ssum += __shfl_xor(ssum, i);
    float r = val - mx - logf(ssum);
    if (n < N_NODES) out[(size_t)n * 16 + c] = r;
}

// ---------------------------------------------------------------------------
extern "C" void kernel_launch(void* const* d_in, const int* in_sizes, int n_in,
                              void* d_out, int out_size, void* d_ws, size_t ws_size,
                              hipStream_t stream) {
    const float* x     = (const float*)d_in[0];
    const int*   ei    = (const int*)d_in[1];
    const int*   src   = ei;
    const int*   dst   = ei + N_EDGES;
    const float* ew    = (const float*)d_in[2];
    const int*   et    = (const int*)d_in[3];
    const float* W1    = (const float*)d_in[4];
    const float* root1 = (const float*)d_in[5];
    const float* b1    = (const float*)d_in[6];
    const float* W2    = (const float*)d_in[7];
    const float* root2 = (const float*)d_in[8];
    const float* b2    = (const float*)d_in[9];
    float* out = (float*)d_out;

    // workspace layout
    char* ws = (char*)d_ws;
    int*    offs    = (int*)ws;                        //  2,000,004 B -> pad 2,000,896
    int*    ccur    = (int*)(ws + 2000896);            //      1,024 B
    int*    cstart  = (int*)(ws + 2001920);            //      2,176 B pad
    int2*   edges   = (int2*)(ws + 2004096);           // 12,800,000 B
    ushort* xh      = (ushort*)(ws + 14804096);        // 25,600,000 B
    ushort* h       = (ushort*)(ws + 40404096);        // 25,600,000 B
    ushort* Wt1     = (ushort*)(ws + 66004096);        //    196,608 B
    ushort* Wt2s    = (ushort*)(ws + 66200704);        //     24,576 B
    // union region @66,225,280: pe (25.7MB, build) -> A640 (128.1MB, L1) -> Y (38.4MB, L2)
    int2*   pe      = (int2*)(ws + 66225280);
    ushort* Abuf    = (ushort*)(ws + 66225280);
    float*  Y       = (float*)(ws + 66225280);

    const int chunk = (ws_size >= 200000000ull) ? N_NODES : 25000;
    const int nch   = N_NODES / chunk;

    // --- precision conversions ---
    cvt_feat<<<((N_NODES * 128 / 4) + 255) / 256, 256, 0, stream>>>(x, xh);
    cvt_wstack<<<dim3(3, 128), 256, 0, stream>>>(W1, root1, Wt1);
    cvt_w2<<<(96 * 128 + 255) / 256, 256, 0, stream>>>(W2, root2, Wt2s);

    // --- build (dst,rel)-bucketed CSR: 3 passes ---
    hipMemsetAsync(ccur, 0, 1024, stream);
    partition_append<<<(N_EDGES + 4095) / 4096, 1024, 0, stream>>>(src, dst, ew, et, ccur, pe);
    cscan<<<1, 256, 0, stream>>>(ccur, cstart, offs);
    bucket_sort<<<NCOARSE, 1024, 0, stream>>>(ccur, cstart, pe, edges, offs);

    // --- layer 1: gather aggregates (640-wide) + GEMM with xh root segment ---
    for (int cc = 0; cc < nch; ++cc) {
        gather_all<<<chunk / 4, 256, 0, stream>>>(xh, edges, offs, Abuf, cc * chunk);
        gemmL1<<<(chunk + 127) / 128, 256, 0, stream>>>(
            xh, Abuf, Wt1, b1, h, cc * chunk, chunk);
    }

    // --- layer 2: transform-first (Y = h @ Wt2s^T), then 16-wide aggregate ---
    gemm96<<<(N_NODES + 127) / 128, 256, 0, stream>>>(h, Wt2s, Y);
    agg2_softmax<<<(N_NODES + 15) / 16, 256, 0, stream>>>(Y, edges, offs, b2, out);
}

// Round 9
// 234.775 us; speedup vs baseline: 2.3981x; 1.1047x over previous
//
#include <hip/hip_runtime.h>

// Problem constants (from reference)
#define N_NODES 100000
#define N_EDGES 1600000
#define N_REL   5
#define M_BUCKETS (N_NODES * N_REL)          // 500000 (dst,rel) buckets
#define NCOARSE  196                         // ceil(N_NODES / 512) coarse buckets
#define CAP      16384                       // pe capacity per coarse bucket (avg 8163)

using bf16x8 = __attribute__((ext_vector_type(8))) short;
using f32x4  = __attribute__((ext_vector_type(4))) float;

__device__ __forceinline__ unsigned short f2bf(float f) {
    unsigned int u = __float_as_uint(f);
    u += 0x7fffu + ((u >> 16) & 1u);          // RNE
    return (unsigned short)(u >> 16);
}
__device__ __forceinline__ float bflo(unsigned int p) { return __uint_as_float(p << 16); }
__device__ __forceinline__ float bfhi(unsigned int p) { return __uint_as_float(p & 0xffff0000u); }
__device__ __forceinline__ float bfu(unsigned short u) { return __uint_as_float((unsigned int)u << 16); }

// ---------------------------------------------------------------------------
// Pass 1: append edges into coarse (dst>>9) regions of pe.
// Record = (src | rel<<17 | dlow9<<20, ew).
// ---------------------------------------------------------------------------
__global__ __launch_bounds__(1024) void partition_append(
    const int* __restrict__ src, const int* __restrict__ dstv,
    const float* __restrict__ ew, const int* __restrict__ et,
    int* __restrict__ ccur, int2* __restrict__ pe) {
    __shared__ int lh[256];
    __shared__ int lb[256];
    int tid = threadIdx.x;
    if (tid < 256) lh[tid] = 0;
    __syncthreads();
    int base = blockIdx.x * 4096;
    int key[4], rank[4], meta[4];
    float w[4];
    #pragma unroll
    for (int i = 0; i < 4; ++i) {
        int e = base + i * 1024 + tid;
        key[i] = -1;
        if (e < N_EDGES) {
            int d = dstv[e];
            key[i] = d >> 9;
            meta[i] = src[e] | (et[e] << 17) | ((d & 511) << 20);
            w[i] = ew[e];
            rank[i] = atomicAdd(&lh[key[i]], 1);
        }
    }
    __syncthreads();
    if (tid < 256) {
        int c = lh[tid];
        lb[tid] = c ? atomicAdd(&ccur[tid], c) : 0;
    }
    __syncthreads();
    #pragma unroll
    for (int i = 0; i < 4; ++i)
        if (key[i] >= 0) {
            int pos = lb[key[i]] + rank[i];
            if (pos < CAP)
                pe[((size_t)key[i] << 14) + pos] = make_int2(meta[i], __float_as_int(w[i]));
        }
}

// Pass 2 (tiny): exclusive scan of 256 coarse counts -> global bases; sentinel.
__global__ __launch_bounds__(256) void cscan(const int* __restrict__ ccur,
                                             int* __restrict__ cstart,
                                             int* __restrict__ offs) {
    __shared__ int lds[256];
    int tid = threadIdx.x;
    int v = ccur[tid];
    lds[tid] = v;
    __syncthreads();
    for (int d = 1; d < 256; d <<= 1) {
        int t = (tid >= d) ? lds[tid - d] : 0;
        __syncthreads();
        lds[tid] += t;
        __syncthreads();
    }
    cstart[tid] = lds[tid] - v;
    if (tid == 0) offs[M_BUCKETS] = N_EDGES;
}

// ---------------------------------------------------------------------------
// Pass 3: one block per coarse bucket: LDS fine-histogram + scan -> offs slice
// + scatter to final dense order. Folds 1/deg into w; keeps rel bits 17-19.
// Within a node, edges grouped by relation ascending.
// ---------------------------------------------------------------------------
__global__ __launch_bounds__(1024) void bucket_sort(
    const int* __restrict__ ccnt, const int* __restrict__ cstart,
    const int2* __restrict__ pe, int2* __restrict__ edges, int* __restrict__ offs) {
    int cb = blockIdx.x;
    int node0 = cb << 9;
    if (node0 >= N_NODES) return;
    int nNodes = N_NODES - node0; if (nNodes > 512) nNodes = 512;
    int nf = nNodes * N_REL;                 // fine buckets in this block (<=2560)
    __shared__ int hist[2560];
    __shared__ int cur[2560];
    __shared__ int sums[1024];
    int tid = threadIdx.x;
    int cnt = ccnt[cb]; if (cnt > CAP) cnt = CAP;
    int gbase = cstart[cb];
    const int2* my = pe + ((size_t)cb << 14);

    for (int i = tid; i < nf; i += 1024) hist[i] = 0;
    __syncthreads();
    for (int i = tid; i < cnt; i += 1024) {
        int m = my[i].x;
        int fb = ((m >> 20) & 511) * N_REL + ((m >> 17) & 7);
        atomicAdd(&hist[fb], 1);
    }
    __syncthreads();

    int t0 = tid * 3;
    int a0 = (t0 + 0 < nf) ? hist[t0 + 0] : 0;
    int a1 = (t0 + 1 < nf) ? hist[t0 + 1] : 0;
    int a2 = (t0 + 2 < nf) ? hist[t0 + 2] : 0;
    int s = a0 + a1 + a2;
    sums[tid] = s;
    __syncthreads();
    for (int d = 1; d < 1024; d <<= 1) {
        int t = (tid >= d) ? sums[tid - d] : 0;
        __syncthreads();
        sums[tid] += t;
        __syncthreads();
    }
    int excl = sums[tid] - s;
    int gb0 = node0 * N_REL;
    if (t0 + 0 < nf) { offs[gb0 + t0 + 0] = gbase + excl; cur[t0 + 0] = excl; }
    excl += a0;
    if (t0 + 1 < nf) { offs[gb0 + t0 + 1] = gbase + excl; cur[t0 + 1] = excl; }
    excl += a1;
    if (t0 + 2 < nf) { offs[gb0 + t0 + 2] = gbase + excl; cur[t0 + 2] = excl; }
    __syncthreads();

    for (int i = tid; i < cnt; i += 1024) {
        int2 r = my[i];
        int fb = ((r.x >> 20) & 511) * N_REL + ((r.x >> 17) & 7);
        int pos = gbase + atomicAdd(&cur[fb], 1);
        float wf = __int_as_float(r.y) / (float)hist[fb];   // fold 1/deg
        edges[pos] = make_int2(r.x & 0xFFFFF, __float_as_int(wf)); // src|rel<<17
    }
}

// ---------------------------------------------------------------------------
// Precision conversions (once per launch)
// ---------------------------------------------------------------------------
__global__ void cvt_feat(const float* __restrict__ x, ushort* __restrict__ xh) {
    int i = blockIdx.x * blockDim.x + threadIdx.x;   // float4 index
    if (i >= (N_NODES * 128) / 4) return;
    float4 v = reinterpret_cast<const float4*>(x)[i];
    ushort4 o;
    o.x = f2bf(v.x); o.y = f2bf(v.y); o.z = f2bf(v.z); o.w = f2bf(v.w);
    reinterpret_cast<ushort4*>(xh)[i] = o;
}

// Stack [root1; W1_0..W1_4] transposed: Wt[o][seg*128+k] (o: 128 outs).
__global__ void cvt_wstack(const float* __restrict__ W, const float* __restrict__ root,
                           ushort* __restrict__ Wt) {
    int t = blockIdx.x * blockDim.x + threadIdx.x;   // 0..767
    int o = blockIdx.y;
    int seg = t >> 7, k = t & 127;
    float v = (seg == 0) ? root[k * 128 + o] : W[(size_t)(seg - 1) * 128 * 128 + k * 128 + o];
    Wt[(size_t)o * 768 + t] = f2bf(v);
}

// Layer-2 stacked weights: Wt2s[o][k], o in 0..95: cols 0-15 root2, 16+r*16+c = W2_r col c.
__global__ void cvt_w2(const float* __restrict__ W2, const float* __restrict__ root2,
                       ushort* __restrict__ Wt2s) {
    int i = blockIdx.x * blockDim.x + threadIdx.x;
    if (i >= 96 * 128) return;
    int o = i >> 7, k = i & 127;
    float v = (o < 16) ? root2[k * 16 + o]
                       : W2[((size_t)((o >> 4) - 1) * 128 + k) * 16 + (o & 15)];
    Wt2s[i] = f2bf(v);
}

// ---------------------------------------------------------------------------
// Layer-1 gather: one wave per node. Fast path (deg<=64): single edge batch,
// FLAT loop over padded degree in steps of 4 — cluster of 4 independent
// feature loads issued BEFORE the (scalar-branchy) boundary flushes, so ~4
// loads stay in flight per wave. Relation boundaries packed 8-bit in one
// 64-bit scalar; running accumulator snapshot-flushed at each boundary
// (2 FMA/edge, no per-edge selects). 1/deg pre-folded into w.
// ---------------------------------------------------------------------------
__global__ __launch_bounds__(256) void gather_all(
    const ushort* __restrict__ feat,   // bf16 [N][128]
    const int2* __restrict__ edges,    // (src|rel<<17, w/deg) relation-sorted
    const int* __restrict__ offs,      // exclusive starts, offs[M]=E
    ushort* __restrict__ A,            // [rows][640] bf16
    int node0) {
    int n = __builtin_amdgcn_readfirstlane(node0 + blockIdx.x * 4 + (threadIdx.x >> 6));
    int lane = threadIdx.x & 63;
    int b0 = n * N_REL;
    int o0 = __builtin_amdgcn_readfirstlane(offs[b0 + 0]);
    int o1 = __builtin_amdgcn_readfirstlane(offs[b0 + 1]);
    int o2 = __builtin_amdgcn_readfirstlane(offs[b0 + 2]);
    int o3 = __builtin_amdgcn_readfirstlane(offs[b0 + 3]);
    int o4 = __builtin_amdgcn_readfirstlane(offs[b0 + 4]);
    int o5 = __builtin_amdgcn_readfirstlane(offs[b0 + 5]);
    const unsigned int* fp = reinterpret_cast<const unsigned int*>(feat);
    unsigned int* Ap = reinterpret_cast<unsigned int*>(A) + (size_t)(n - node0) * 320;

    int deg = o5 - o0;
    if (deg <= 64) {
        int2 er = (o0 + lane < o5) ? edges[o0 + lane] : make_int2(0, 0);
        // segment boundaries (relative, each <=64) packed 8b into one scalar
        unsigned long long bp =
              (unsigned long long)(unsigned)(o1 - o0)
            | ((unsigned long long)(unsigned)(o2 - o0) << 8)
            | ((unsigned long long)(unsigned)(o3 - o0) << 16)
            | ((unsigned long long)(unsigned)(o4 - o0) << 24)
            | ((unsigned long long)(unsigned)deg << 32);
        float ax = 0.f, ay = 0.f;
        int seg = 0;
        auto flushAt = [&](int jj) {
            while (seg < 5 && jj == (int)((bp >> (seg * 8)) & 0xFFull)) {
                Ap[64 * seg + lane] =
                    (unsigned int)f2bf(ax) | ((unsigned int)f2bf(ay) << 16);
                ax = 0.f; ay = 0.f; ++seg;
            }
        };
        int deg4 = (deg + 3) & ~3;
        for (int j = 0; j < deg4; j += 4) {
            // ---- load cluster: 4 independent gathers issued back-to-back ----
            int m0 = __builtin_amdgcn_readlane(er.x, j + 0);
            int m1 = __builtin_amdgcn_readlane(er.x, j + 1);
            int m2 = __builtin_amdgcn_readlane(er.x, j + 2);
            int m3 = __builtin_amdgcn_readlane(er.x, j + 3);
            unsigned int p0 = fp[((size_t)(m0 & 0x1FFFF) << 6) + lane];
            unsigned int p1 = fp[((size_t)(m1 & 0x1FFFF) << 6) + lane];
            unsigned int p2 = fp[((size_t)(m2 & 0x1FFFF) << 6) + lane];
            unsigned int p3 = fp[((size_t)(m3 & 0x1FFFF) << 6) + lane];
            float w0 = __uint_as_float(__builtin_amdgcn_readlane(er.y, j + 0));
            float w1 = __uint_as_float(__builtin_amdgcn_readlane(er.y, j + 1));
            float w2 = __uint_as_float(__builtin_amdgcn_readlane(er.y, j + 2));
            float w3 = __uint_as_float(__builtin_amdgcn_readlane(er.y, j + 3));
            // ---- consume, flushing segment snapshots at boundaries ----
            flushAt(j + 0);
            ax = fmaf(w0, bflo(p0), ax); ay = fmaf(w0, bfhi(p0), ay);
            flushAt(j + 1);
            ax = fmaf(w1, bflo(p1), ax); ay = fmaf(w1, bfhi(p1), ay);
            flushAt(j + 2);
            ax = fmaf(w2, bflo(p2), ax); ay = fmaf(w2, bfhi(p2), ay);
            flushAt(j + 3);
            ax = fmaf(w3, bflo(p3), ax); ay = fmaf(w3, bfhi(p3), ay);
        }
        while (seg < 5) {   // drain (also handles deg==0 and trailing empties)
            Ap[64 * seg + lane] =
                (unsigned int)f2bf(ax) | ((unsigned int)f2bf(ay) << 16);
            ax = 0.f; ay = 0.f; ++seg;
        }
    } else {
        int o[6] = {o0, o1, o2, o3, o4, o5};
        #pragma unroll
        for (int r = 0; r < 5; ++r) {
            int s0 = o[r], e1 = o[r + 1];
            float ax = 0.f, ay = 0.f;
            for (int base = s0; base < e1; base += 64) {
                int idx = base + lane;
                int2 er = (idx < e1) ? edges[idx] : make_int2(0, 0);
                int m = e1 - base; if (m > 64) m = 64;
                for (int j = 0; j < m; ++j) {
                    int mm = __builtin_amdgcn_readlane(er.x, j);
                    float w = __uint_as_float(__builtin_amdgcn_readlane(er.y, j));
                    unsigned int p = fp[((size_t)(mm & 0x1FFFF) << 6) + lane];
                    ax = fmaf(w, bflo(p), ax);
                    ay = fmaf(w, bfhi(p), ay);
                }
            }
            Ap[64 * r + lane] = (unsigned int)f2bf(ax) | ((unsigned int)f2bf(ay) << 16);
        }
    }
}

// ---------------------------------------------------------------------------
// Layer-1 GEMM: h[row][128] = relu([xh_row | A640_row] @ Wt1[128][768]^T + b1)
// ---------------------------------------------------------------------------
__global__ __launch_bounds__(256) void gemmL1(
    const ushort* __restrict__ xh,   // [N][128] bf16
    const ushort* __restrict__ A,    // chunk-local [rows][640] bf16
    const ushort* __restrict__ Wt,   // [128][768] bf16
    const float* __restrict__ bias,  // [128]
    ushort* __restrict__ h,          // [N][128] bf16
    int row0, int nrows) {
    __shared__ ushort As[128 * 64];          // 16 KB
    __shared__ ushort Bs[128 * 64];          // 16 KB
    const int tid = threadIdx.x, lane = tid & 63, wave = tid >> 6;
    const int m0 = blockIdx.x * 128;

    constexpr int MF = 4, NF = 4;
    const int wr0 = (wave >> 1) * 64;
    const int wc0 = (wave & 1) * 64;

    f32x4 acc[MF][NF] = {};

    for (int ks = 0; ks < 12; ++ks) {
        #pragma unroll
        for (int u = 0; u < 4; ++u) {
            int idx = tid + u * 256;
            int row = idx >> 3, slot = idx & 7;
            float4 v;
            if (ks < 2) {
                int gr = row0 + m0 + row; if (gr >= N_NODES) gr = N_NODES - 1;
                v = *reinterpret_cast<const float4*>(xh + (size_t)gr * 128 + ks * 64 + slot * 8);
            } else {
                v = *reinterpret_cast<const float4*>(
                    A + (size_t)(m0 + row) * 640 + (ks - 2) * 64 + slot * 8);
            }
            int byte = row * 128 + ((slot ^ (row & 7)) << 4);
            *reinterpret_cast<float4*>(reinterpret_cast<char*>(As) + byte) = v;
        }
        #pragma unroll
        for (int u = 0; u < 4; ++u) {
            int idx = tid + u * 256;
            int row = idx >> 3, slot = idx & 7;
            float4 v = *reinterpret_cast<const float4*>(
                Wt + (size_t)row * 768 + ks * 64 + slot * 8);
            int byte = row * 128 + ((slot ^ (row & 7)) << 4);
            *reinterpret_cast<float4*>(reinterpret_cast<char*>(Bs) + byte) = v;
        }
        __syncthreads();

        #pragma unroll
        for (int kh = 0; kh < 2; ++kh) {
            bf16x8 af[MF], bfr[NF];
            #pragma unroll
            for (int m = 0; m < MF; ++m) {
                int row = wr0 + m * 16 + (lane & 15);
                int slot = kh * 4 + (lane >> 4);
                int byte = row * 128 + ((slot ^ (row & 7)) << 4);
                af[m] = *reinterpret_cast<const bf16x8*>(
                    reinterpret_cast<const char*>(As) + byte);
            }
            #pragma unroll
            for (int nn = 0; nn < NF; ++nn) {
                int row = wc0 + nn * 16 + (lane & 15);
                int slot = kh * 4 + (lane >> 4);
                int byte = row * 128 + ((slot ^ (row & 7)) << 4);
                bfr[nn] = *reinterpret_cast<const bf16x8*>(
                    reinterpret_cast<const char*>(Bs) + byte);
            }
            #pragma unroll
            for (int m = 0; m < MF; ++m)
                #pragma unroll
                for (int nn = 0; nn < NF; ++nn)
                    acc[m][nn] = __builtin_amdgcn_mfma_f32_16x16x32_bf16(
                        af[m], bfr[nn], acc[m][nn], 0, 0, 0);
        }
        __syncthreads();
    }

    #pragma unroll
    for (int m = 0; m < MF; ++m) {
        int rloc = wr0 + m * 16 + (lane >> 4) * 4;
        #pragma unroll
        for (int nn = 0; nn < NF; ++nn) {
            int c = wc0 + nn * 16 + (lane & 15);
            float bv = bias[c];
            #pragma unroll
            for (int q = 0; q < 4; ++q) {
                int lrow = m0 + rloc + q;
                if (lrow < nrows) {
                    int grow = row0 + lrow;
                    float v = fmaxf(acc[m][nn][q] + bv, 0.f);
                    h[(size_t)grow * 128 + c] = f2bf(v);
                }
            }
        }
    }
}

// ---------------------------------------------------------------------------
// Layer-2 transform: Yh[n][96] = h[n][128] @ Wt2s[96][128]^T   (bf16 out)
// ---------------------------------------------------------------------------
__global__ __launch_bounds__(256) void gemm96(
    const ushort* __restrict__ h, const ushort* __restrict__ Wt,
    ushort* __restrict__ Yh) {
    __shared__ ushort As[128 * 128];   // 32 KB
    __shared__ ushort Bs[96 * 128];    // 24 KB
    const int tid = threadIdx.x, lane = tid & 63, wave = tid >> 6;
    const int m0 = blockIdx.x * 128;

    #pragma unroll
    for (int u = 0; u < 8; ++u) {
        int idx = tid + u * 256;
        int row = idx >> 4, slot = idx & 15;
        int gr = m0 + row; if (gr >= N_NODES) gr = N_NODES - 1;
        float4 v = *reinterpret_cast<const float4*>(h + (size_t)gr * 128 + slot * 8);
        int byte = row * 256 + ((slot ^ (row & 15)) << 4);
        *reinterpret_cast<float4*>(reinterpret_cast<char*>(As) + byte) = v;
    }
    #pragma unroll
    for (int u = 0; u < 6; ++u) {
        int idx = tid + u * 256;
        int row = idx >> 4, slot = idx & 15;
        float4 v = *reinterpret_cast<const float4*>(Wt + (size_t)row * 128 + slot * 8);
        int byte = row * 256 + ((slot ^ (row & 15)) << 4);
        *reinterpret_cast<float4*>(reinterpret_cast<char*>(Bs) + byte) = v;
    }
    __syncthreads();

    f32x4 acc[2][6] = {};
    #pragma unroll
    for (int ks = 0; ks < 4; ++ks) {
        bf16x8 af[2], bfr[6];
        #pragma unroll
        for (int m = 0; m < 2; ++m) {
            int row = wave * 32 + m * 16 + (lane & 15);
            int slot = ks * 4 + (lane >> 4);
            int byte = row * 256 + ((slot ^ (row & 15)) << 4);
            af[m] = *reinterpret_cast<const bf16x8*>(reinterpret_cast<const char*>(As) + byte);
        }
        #pragma unroll
        for (int nn = 0; nn < 6; ++nn) {
            int row = nn * 16 + (lane & 15);
            int slot = ks * 4 + (lane >> 4);
            int byte = row * 256 + ((slot ^ (row & 15)) << 4);
            bfr[nn] = *reinterpret_cast<const bf16x8*>(reinterpret_cast<const char*>(Bs) + byte);
        }
        #pragma unroll
        for (int m = 0; m < 2; ++m)
            #pragma unroll
            for (int nn = 0; nn < 6; ++nn)
                acc[m][nn] = __builtin_amdgcn_mfma_f32_16x16x32_bf16(
                    af[m], bfr[nn], acc[m][nn], 0, 0, 0);
    }

    #pragma unroll
    for (int m = 0; m < 2; ++m) {
        int rloc = m0 + wave * 32 + m * 16 + (lane >> 4) * 4;
        #pragma unroll
        for (int nn = 0; nn < 6; ++nn) {
            int c = nn * 16 + (lane & 15);
            #pragma unroll
            for (int q = 0; q < 4; ++q) {
                int row = rloc + q;
                if (row < N_NODES) Yh[(size_t)row * 96 + c] = f2bf(acc[m][nn][q]);
            }
        }
    }
}

// ---------------------------------------------------------------------------
// Layer-2 aggregate + bias + log_softmax, fused. 4 nodes/wave, 16 lanes/node.
// out[n][c] = logsoftmax( Yh[n][c] + b2[c] + sum_e w_e * Yh[src_e][16+rel*16+c] )
// Yh is bf16 (halves the random-read bytes vs f32).
// ---------------------------------------------------------------------------
__global__ __launch_bounds__(256) void agg2_softmax(
    const ushort* __restrict__ Yh, const int2* __restrict__ edges,
    const int* __restrict__ offs, const float* __restrict__ b2,
    float* __restrict__ out) {
    int wave = threadIdx.x >> 6, lane = threadIdx.x & 63;
    int q = lane >> 4, c = lane & 15;
    int n = (blockIdx.x * 4 + wave) * 4 + q;
    int nn = (n < N_NODES) ? n : N_NODES - 1;
    int o0 = offs[nn * N_REL], o5 = offs[nn * N_REL + 5];
    int deg = o5 - o0;

    float val = bfu(Yh[(size_t)nn * 96 + c]) + b2[c];

    int md = deg;
    md = max(md, __shfl_xor(md, 16));
    md = max(md, __shfl_xor(md, 32));
    md = __builtin_amdgcn_readfirstlane(md);

    for (int b = 0; b < md; b += 16) {
        int idx = o0 + b + c;
        int2 er = (idx < o5) ? edges[idx] : make_int2(0, 0);   // (0,0) pads: w=0
        #pragma unroll
        for (int j = 0; j < 16; ++j) {
            int m = __shfl(er.x, q * 16 + j);
            float w = __uint_as_float(__shfl(er.y, q * 16 + j));
            int s = m & 0x1FFFF;
            int rel = (m >> 17) & 7;
            val = fmaf(w, bfu(Yh[(size_t)s * 96 + 16 + rel * 16 + c]), val);
        }
    }

    // log_softmax over the 16-lane group
    float mx = val;
    #pragma unroll
    for (int i = 1; i < 16; i <<= 1) mx = fmaxf(mx, __shfl_xor(mx, i));
    float ex = expf(val - mx);
    float ssum = ex;
    #pragma unroll
    for (int i = 1; i < 16; i <<= 1) ssum += __shfl_xor(ssum, i);
    float r = val - mx - logf(ssum);
    if (n < N_NODES) out[(size_t)n * 16 + c] = r;
}

// ---------------------------------------------------------------------------
extern "C" void kernel_launch(void* const* d_in, const int* in_sizes, int n_in,
                              void* d_out, int out_size, void* d_ws, size_t ws_size,
                              hipStream_t stream) {
    const float* x     = (const float*)d_in[0];
    const int*   ei    = (const int*)d_in[1];
    const int*   src   = ei;
    const int*   dst   = ei + N_EDGES;
    const float* ew    = (const float*)d_in[2];
    const int*   et    = (const int*)d_in[3];
    const float* W1    = (const float*)d_in[4];
    const float* root1 = (const float*)d_in[5];
    const float* b1    = (const float*)d_in[6];
    const float* W2    = (const float*)d_in[7];
    const float* root2 = (const float*)d_in[8];
    const float* b2    = (const float*)d_in[9];
    float* out = (float*)d_out;

    // workspace layout
    char* ws = (char*)d_ws;
    int*    offs    = (int*)ws;                        //  2,000,004 B -> pad 2,000,896
    int*    ccur    = (int*)(ws + 2000896);            //      1,024 B
    int*    cstart  = (int*)(ws + 2001920);            //      2,176 B pad
    int2*   edges   = (int2*)(ws + 2004096);           // 12,800,000 B
    ushort* xh      = (ushort*)(ws + 14804096);        // 25,600,000 B
    ushort* h       = (ushort*)(ws + 40404096);        // 25,600,000 B
    ushort* Wt1     = (ushort*)(ws + 66004096);        //    196,608 B
    ushort* Wt2s    = (ushort*)(ws + 66200704);        //     24,576 B
    // union region @66,225,280: pe (25.7MB, build) -> A640 (128.1MB, L1) -> Yh (19.2MB, L2)
    int2*   pe      = (int2*)(ws + 66225280);
    ushort* Abuf    = (ushort*)(ws + 66225280);
    ushort* Yh      = (ushort*)(ws + 66225280);

    const int chunk = (ws_size >= 200000000ull) ? N_NODES : 25000;
    const int nch   = N_NODES / chunk;

    // --- precision conversions ---
    cvt_feat<<<((N_NODES * 128 / 4) + 255) / 256, 256, 0, stream>>>(x, xh);
    cvt_wstack<<<dim3(3, 128), 256, 0, stream>>>(W1, root1, Wt1);
    cvt_w2<<<(96 * 128 + 255) / 256, 256, 0, stream>>>(W2, root2, Wt2s);

    // --- build (dst,rel)-bucketed CSR: 3 passes ---
    hipMemsetAsync(ccur, 0, 1024, stream);
    partition_append<<<(N_EDGES + 4095) / 4096, 1024, 0, stream>>>(src, dst, ew, et, ccur, pe);
    cscan<<<1, 256, 0, stream>>>(ccur, cstart, offs);
    bucket_sort<<<NCOARSE, 1024, 0, stream>>>(ccur, cstart, pe, edges, offs);

    // --- layer 1: gather aggregates (640-wide) + GEMM with xh root segment ---
    for (int cc = 0; cc < nch; ++cc) {
        gather_all<<<chunk / 4, 256, 0, stream>>>(xh, edges, offs, Abuf, cc * chunk);
        gemmL1<<<(chunk + 127) / 128, 256, 0, stream>>>(
            xh, Abuf, Wt1, b1, h, cc * chunk, chunk);
    }

    // --- layer 2: transform-first (Yh = h @ Wt2s^T, bf16), 16-wide aggregate ---
    gemm96<<<(N_NODES + 127) / 128, 256, 0, stream>>>(h, Wt2s, Yh);
    agg2_softmax<<<(N_NODES + 15) / 16, 256, 0, stream>>>(Yh, edges, offs, b2, out);
}

// Round 10
// 224.638 us; speedup vs baseline: 2.5063x; 1.0451x over previous
//
#include <hip/hip_runtime.h>

// Problem constants (from reference)
#define N_NODES 100000
#define N_EDGES 1600000
#define N_REL   5
#define M_BUCKETS (N_NODES * N_REL)          // 500000 (dst,rel) buckets
#define NCOARSE  196                         // ceil(N_NODES / 512) coarse buckets
#define CAP      16384                       // pe capacity per coarse bucket (avg 8163)

using bf16x8 = __attribute__((ext_vector_type(8))) short;
using f32x4  = __attribute__((ext_vector_type(4))) float;
using f32x2  = __attribute__((ext_vector_type(2))) float;

__device__ __forceinline__ unsigned short f2bf(float f) {
    unsigned int u = __float_as_uint(f);
    u += 0x7fffu + ((u >> 16) & 1u);          // RNE
    return (unsigned short)(u >> 16);
}
__device__ __forceinline__ float bflo(unsigned int p) { return __uint_as_float(p << 16); }
__device__ __forceinline__ float bfhi(unsigned int p) { return __uint_as_float(p & 0xffff0000u); }
__device__ __forceinline__ float bfu(unsigned short u) { return __uint_as_float((unsigned int)u << 16); }

// ---------------------------------------------------------------------------
// Pass 1: append edges into coarse (dst>>9) regions of pe.
// Record = (src | rel<<17 | dlow9<<20, ew).
// ---------------------------------------------------------------------------
__global__ __launch_bounds__(1024) void partition_append(
    const int* __restrict__ src, const int* __restrict__ dstv,
    const float* __restrict__ ew, const int* __restrict__ et,
    int* __restrict__ ccur, int2* __restrict__ pe) {
    __shared__ int lh[256];
    __shared__ int lb[256];
    int tid = threadIdx.x;
    if (tid < 256) lh[tid] = 0;
    __syncthreads();
    int base = blockIdx.x * 4096;
    int key[4], rank[4], meta[4];
    float w[4];
    #pragma unroll
    for (int i = 0; i < 4; ++i) {
        int e = base + i * 1024 + tid;
        key[i] = -1;
        if (e < N_EDGES) {
            int d = dstv[e];
            key[i] = d >> 9;
            meta[i] = src[e] | (et[e] << 17) | ((d & 511) << 20);
            w[i] = ew[e];
            rank[i] = atomicAdd(&lh[key[i]], 1);
        }
    }
    __syncthreads();
    if (tid < 256) {
        int c = lh[tid];
        lb[tid] = c ? atomicAdd(&ccur[tid], c) : 0;
    }
    __syncthreads();
    #pragma unroll
    for (int i = 0; i < 4; ++i)
        if (key[i] >= 0) {
            int pos = lb[key[i]] + rank[i];
            if (pos < CAP)
                pe[((size_t)key[i] << 14) + pos] = make_int2(meta[i], __float_as_int(w[i]));
        }
}

// Pass 2 (tiny): exclusive scan of 256 coarse counts -> global bases; sentinel.
__global__ __launch_bounds__(256) void cscan(const int* __restrict__ ccur,
                                             int* __restrict__ cstart,
                                             int* __restrict__ offs) {
    __shared__ int lds[256];
    int tid = threadIdx.x;
    int v = ccur[tid];
    lds[tid] = v;
    __syncthreads();
    for (int d = 1; d < 256; d <<= 1) {
        int t = (tid >= d) ? lds[tid - d] : 0;
        __syncthreads();
        lds[tid] += t;
        __syncthreads();
    }
    cstart[tid] = lds[tid] - v;
    if (tid == 0) offs[M_BUCKETS] = N_EDGES;
}

// ---------------------------------------------------------------------------
// Pass 3: one block per coarse bucket: LDS fine-histogram + scan -> offs slice
// + scatter to final dense order. Folds 1/deg into w; keeps rel bits 17-19.
// Within a node, edges grouped by relation ascending.
// ---------------------------------------------------------------------------
__global__ __launch_bounds__(1024) void bucket_sort(
    const int* __restrict__ ccnt, const int* __restrict__ cstart,
    const int2* __restrict__ pe, int2* __restrict__ edges, int* __restrict__ offs) {
    int cb = blockIdx.x;
    int node0 = cb << 9;
    if (node0 >= N_NODES) return;
    int nNodes = N_NODES - node0; if (nNodes > 512) nNodes = 512;
    int nf = nNodes * N_REL;                 // fine buckets in this block (<=2560)
    __shared__ int hist[2560];
    __shared__ int cur[2560];
    __shared__ int sums[1024];
    int tid = threadIdx.x;
    int cnt = ccnt[cb]; if (cnt > CAP) cnt = CAP;
    int gbase = cstart[cb];
    const int2* my = pe + ((size_t)cb << 14);

    for (int i = tid; i < nf; i += 1024) hist[i] = 0;
    __syncthreads();
    for (int i = tid; i < cnt; i += 1024) {
        int m = my[i].x;
        int fb = ((m >> 20) & 511) * N_REL + ((m >> 17) & 7);
        atomicAdd(&hist[fb], 1);
    }
    __syncthreads();

    int t0 = tid * 3;
    int a0 = (t0 + 0 < nf) ? hist[t0 + 0] : 0;
    int a1 = (t0 + 1 < nf) ? hist[t0 + 1] : 0;
    int a2 = (t0 + 2 < nf) ? hist[t0 + 2] : 0;
    int s = a0 + a1 + a2;
    sums[tid] = s;
    __syncthreads();
    for (int d = 1; d < 1024; d <<= 1) {
        int t = (tid >= d) ? sums[tid - d] : 0;
        __syncthreads();
        sums[tid] += t;
        __syncthreads();
    }
    int excl = sums[tid] - s;
    int gb0 = node0 * N_REL;
    if (t0 + 0 < nf) { offs[gb0 + t0 + 0] = gbase + excl; cur[t0 + 0] = excl; }
    excl += a0;
    if (t0 + 1 < nf) { offs[gb0 + t0 + 1] = gbase + excl; cur[t0 + 1] = excl; }
    excl += a1;
    if (t0 + 2 < nf) { offs[gb0 + t0 + 2] = gbase + excl; cur[t0 + 2] = excl; }
    __syncthreads();

    for (int i = tid; i < cnt; i += 1024) {
        int2 r = my[i];
        int fb = ((r.x >> 20) & 511) * N_REL + ((r.x >> 17) & 7);
        int pos = gbase + atomicAdd(&cur[fb], 1);
        float wf = __int_as_float(r.y) / (float)hist[fb];   // fold 1/deg
        edges[pos] = make_int2(r.x & 0xFFFFF, __float_as_int(wf)); // src|rel<<17
    }
}

// ---------------------------------------------------------------------------
// Feature conversion: one read of x -> xh (bf16, for GEMM root segment)
//                                    + xq (fp8 e4m3, for the gather table)
// ---------------------------------------------------------------------------
__global__ void cvt_feat(const float* __restrict__ x, ushort* __restrict__ xh,
                         unsigned int* __restrict__ xq) {
    int i = blockIdx.x * blockDim.x + threadIdx.x;   // float4 index
    if (i >= (N_NODES * 128) / 4) return;
    float4 v = reinterpret_cast<const float4*>(x)[i];
    ushort4 o;
    o.x = f2bf(v.x); o.y = f2bf(v.y); o.z = f2bf(v.z); o.w = f2bf(v.w);
    reinterpret_cast<ushort4*>(xh)[i] = o;
    int p = __builtin_amdgcn_cvt_pk_fp8_f32(v.x, v.y, 0, false);
    p = __builtin_amdgcn_cvt_pk_fp8_f32(v.z, v.w, p, true);
    xq[i] = (unsigned int)p;
}

// Stack [root1; W1_0..W1_4] transposed: Wt[o][seg*128+k] (o: 128 outs).
__global__ void cvt_wstack(const float* __restrict__ W, const float* __restrict__ root,
                           ushort* __restrict__ Wt) {
    int t = blockIdx.x * blockDim.x + threadIdx.x;   // 0..767
    int o = blockIdx.y;
    int seg = t >> 7, k = t & 127;
    float v = (seg == 0) ? root[k * 128 + o] : W[(size_t)(seg - 1) * 128 * 128 + k * 128 + o];
    Wt[(size_t)o * 768 + t] = f2bf(v);
}

// Layer-2 stacked weights: Wt2s[o][k], o in 0..95: cols 0-15 root2, 16+r*16+c = W2_r col c.
__global__ void cvt_w2(const float* __restrict__ W2, const float* __restrict__ root2,
                       ushort* __restrict__ Wt2s) {
    int i = blockIdx.x * blockDim.x + threadIdx.x;
    if (i >= 96 * 128) return;
    int o = i >> 7, k = i & 127;
    float v = (o < 16) ? root2[k * 16 + o]
                       : W2[((size_t)((o >> 4) - 1) * 128 + k) * 16 + (o & 15)];
    Wt2s[i] = f2bf(v);
}

// ---------------------------------------------------------------------------
// Layer-1 gather: one wave per node; feature table is FP8 (2 B/lane/edge,
// 128 B/edge total — half the bytes, and v_cvt_pk_f32_fp8 unpacks 2 floats
// in 1 instr). Flat loop, 4-deep load clusters, scalar boundary flushes.
// ---------------------------------------------------------------------------
__global__ __launch_bounds__(256) void gather_all(
    const ushort* __restrict__ featq,  // fp8 [N][128] viewed as ushort[N][64]
    const int2* __restrict__ edges,    // (src|rel<<17, w/deg) relation-sorted
    const int* __restrict__ offs,      // exclusive starts, offs[M]=E
    ushort* __restrict__ A,            // [rows][640] bf16
    int node0) {
    int n = __builtin_amdgcn_readfirstlane(node0 + blockIdx.x * 4 + (threadIdx.x >> 6));
    int lane = threadIdx.x & 63;
    int b0 = n * N_REL;
    int o0 = __builtin_amdgcn_readfirstlane(offs[b0 + 0]);
    int o1 = __builtin_amdgcn_readfirstlane(offs[b0 + 1]);
    int o2 = __builtin_amdgcn_readfirstlane(offs[b0 + 2]);
    int o3 = __builtin_amdgcn_readfirstlane(offs[b0 + 3]);
    int o4 = __builtin_amdgcn_readfirstlane(offs[b0 + 4]);
    int o5 = __builtin_amdgcn_readfirstlane(offs[b0 + 5]);
    unsigned int* Ap = reinterpret_cast<unsigned int*>(A) + (size_t)(n - node0) * 320;

    int deg = o5 - o0;
    if (deg <= 64) {
        int2 er = (o0 + lane < o5) ? edges[o0 + lane] : make_int2(0, 0);
        unsigned long long bp =
              (unsigned long long)(unsigned)(o1 - o0)
            | ((unsigned long long)(unsigned)(o2 - o0) << 8)
            | ((unsigned long long)(unsigned)(o3 - o0) << 16)
            | ((unsigned long long)(unsigned)(o4 - o0) << 24)
            | ((unsigned long long)(unsigned)deg << 32);
        float ax = 0.f, ay = 0.f;
        int seg = 0;
        auto flushAt = [&](int jj) {
            while (seg < 5 && jj == (int)((bp >> (seg * 8)) & 0xFFull)) {
                Ap[64 * seg + lane] =
                    (unsigned int)f2bf(ax) | ((unsigned int)f2bf(ay) << 16);
                ax = 0.f; ay = 0.f; ++seg;
            }
        };
        int deg4 = (deg + 3) & ~3;
        for (int j = 0; j < deg4; j += 4) {
            // ---- load cluster: 4 independent fp8 gathers ----
            int m0 = __builtin_amdgcn_readlane(er.x, j + 0);
            int m1 = __builtin_amdgcn_readlane(er.x, j + 1);
            int m2 = __builtin_amdgcn_readlane(er.x, j + 2);
            int m3 = __builtin_amdgcn_readlane(er.x, j + 3);
            unsigned short q0 = featq[((size_t)(m0 & 0x1FFFF) << 6) + lane];
            unsigned short q1 = featq[((size_t)(m1 & 0x1FFFF) << 6) + lane];
            unsigned short q2 = featq[((size_t)(m2 & 0x1FFFF) << 6) + lane];
            unsigned short q3 = featq[((size_t)(m3 & 0x1FFFF) << 6) + lane];
            float w0 = __uint_as_float(__builtin_amdgcn_readlane(er.y, j + 0));
            float w1 = __uint_as_float(__builtin_amdgcn_readlane(er.y, j + 1));
            float w2 = __uint_as_float(__builtin_amdgcn_readlane(er.y, j + 2));
            float w3 = __uint_as_float(__builtin_amdgcn_readlane(er.y, j + 3));
            // ---- consume, flushing segment snapshots at boundaries ----
            f32x2 f;
            flushAt(j + 0);
            f = __builtin_amdgcn_cvt_pk_f32_fp8((int)q0, false);
            ax = fmaf(w0, f.x, ax); ay = fmaf(w0, f.y, ay);
            flushAt(j + 1);
            f = __builtin_amdgcn_cvt_pk_f32_fp8((int)q1, false);
            ax = fmaf(w1, f.x, ax); ay = fmaf(w1, f.y, ay);
            flushAt(j + 2);
            f = __builtin_amdgcn_cvt_pk_f32_fp8((int)q2, false);
            ax = fmaf(w2, f.x, ax); ay = fmaf(w2, f.y, ay);
            flushAt(j + 3);
            f = __builtin_amdgcn_cvt_pk_f32_fp8((int)q3, false);
            ax = fmaf(w3, f.x, ax); ay = fmaf(w3, f.y, ay);
        }
        while (seg < 5) {
            Ap[64 * seg + lane] =
                (unsigned int)f2bf(ax) | ((unsigned int)f2bf(ay) << 16);
            ax = 0.f; ay = 0.f; ++seg;
        }
    } else {
        int o[6] = {o0, o1, o2, o3, o4, o5};
        #pragma unroll
        for (int r = 0; r < 5; ++r) {
            int s0 = o[r], e1 = o[r + 1];
            float ax = 0.f, ay = 0.f;
            for (int base = s0; base < e1; base += 64) {
                int idx = base + lane;
                int2 er = (idx < e1) ? edges[idx] : make_int2(0, 0);
                int m = e1 - base; if (m > 64) m = 64;
                for (int j = 0; j < m; ++j) {
                    int mm = __builtin_amdgcn_readlane(er.x, j);
                    float w = __uint_as_float(__builtin_amdgcn_readlane(er.y, j));
                    unsigned short q = featq[((size_t)(mm & 0x1FFFF) << 6) + lane];
                    f32x2 f = __builtin_amdgcn_cvt_pk_f32_fp8((int)q, false);
                    ax = fmaf(w, f.x, ax);
                    ay = fmaf(w, f.y, ay);
                }
            }
            Ap[64 * r + lane] = (unsigned int)f2bf(ax) | ((unsigned int)f2bf(ay) << 16);
        }
    }
}

// ---------------------------------------------------------------------------
// Layer-1 GEMM: h[row][128] = relu([xh_row | A640_row] @ Wt1[128][768]^T + b1)
// ---------------------------------------------------------------------------
__global__ __launch_bounds__(256) void gemmL1(
    const ushort* __restrict__ xh,   // [N][128] bf16
    const ushort* __restrict__ A,    // chunk-local [rows][640] bf16
    const ushort* __restrict__ Wt,   // [128][768] bf16
    const float* __restrict__ bias,  // [128]
    ushort* __restrict__ h,          // [N][128] bf16
    int row0, int nrows) {
    __shared__ ushort As[128 * 64];          // 16 KB
    __shared__ ushort Bs[128 * 64];          // 16 KB
    const int tid = threadIdx.x, lane = tid & 63, wave = tid >> 6;
    const int m0 = blockIdx.x * 128;

    constexpr int MF = 4, NF = 4;
    const int wr0 = (wave >> 1) * 64;
    const int wc0 = (wave & 1) * 64;

    f32x4 acc[MF][NF] = {};

    for (int ks = 0; ks < 12; ++ks) {
        #pragma unroll
        for (int u = 0; u < 4; ++u) {
            int idx = tid + u * 256;
            int row = idx >> 3, slot = idx & 7;
            float4 v;
            if (ks < 2) {
                int gr = row0 + m0 + row; if (gr >= N_NODES) gr = N_NODES - 1;
                v = *reinterpret_cast<const float4*>(xh + (size_t)gr * 128 + ks * 64 + slot * 8);
            } else {
                v = *reinterpret_cast<const float4*>(
                    A + (size_t)(m0 + row) * 640 + (ks - 2) * 64 + slot * 8);
            }
            int byte = row * 128 + ((slot ^ (row & 7)) << 4);
            *reinterpret_cast<float4*>(reinterpret_cast<char*>(As) + byte) = v;
        }
        #pragma unroll
        for (int u = 0; u < 4; ++u) {
            int idx = tid + u * 256;
            int row = idx >> 3, slot = idx & 7;
            float4 v = *reinterpret_cast<const float4*>(
                Wt + (size_t)row * 768 + ks * 64 + slot * 8);
            int byte = row * 128 + ((slot ^ (row & 7)) << 4);
            *reinterpret_cast<float4*>(reinterpret_cast<char*>(Bs) + byte) = v;
        }
        __syncthreads();

        #pragma unroll
        for (int kh = 0; kh < 2; ++kh) {
            bf16x8 af[MF], bfr[NF];
            #pragma unroll
            for (int m = 0; m < MF; ++m) {
                int row = wr0 + m * 16 + (lane & 15);
                int slot = kh * 4 + (lane >> 4);
                int byte = row * 128 + ((slot ^ (row & 7)) << 4);
                af[m] = *reinterpret_cast<const bf16x8*>(
                    reinterpret_cast<const char*>(As) + byte);
            }
            #pragma unroll
            for (int nn = 0; nn < NF; ++nn) {
                int row = wc0 + nn * 16 + (lane & 15);
                int slot = kh * 4 + (lane >> 4);
                int byte = row * 128 + ((slot ^ (row & 7)) << 4);
                bfr[nn] = *reinterpret_cast<const bf16x8*>(
                    reinterpret_cast<const char*>(Bs) + byte);
            }
            #pragma unroll
            for (int m = 0; m < MF; ++m)
                #pragma unroll
                for (int nn = 0; nn < NF; ++nn)
                    acc[m][nn] = __builtin_amdgcn_mfma_f32_16x16x32_bf16(
                        af[m], bfr[nn], acc[m][nn], 0, 0, 0);
        }
        __syncthreads();
    }

    #pragma unroll
    for (int m = 0; m < MF; ++m) {
        int rloc = wr0 + m * 16 + (lane >> 4) * 4;
        #pragma unroll
        for (int nn = 0; nn < NF; ++nn) {
            int c = wc0 + nn * 16 + (lane & 15);
            float bv = bias[c];
            #pragma unroll
            for (int q = 0; q < 4; ++q) {
                int lrow = m0 + rloc + q;
                if (lrow < nrows) {
                    int grow = row0 + lrow;
                    float v = fmaxf(acc[m][nn][q] + bv, 0.f);
                    h[(size_t)grow * 128 + c] = f2bf(v);
                }
            }
        }
    }
}

// ---------------------------------------------------------------------------
// Layer-2 transform: Yh[n][96] = h[n][128] @ Wt2s[96][128]^T   (bf16 out)
// ---------------------------------------------------------------------------
__global__ __launch_bounds__(256) void gemm96(
    const ushort* __restrict__ h, const ushort* __restrict__ Wt,
    ushort* __restrict__ Yh) {
    __shared__ ushort As[128 * 128];   // 32 KB
    __shared__ ushort Bs[96 * 128];    // 24 KB
    const int tid = threadIdx.x, lane = tid & 63, wave = tid >> 6;
    const int m0 = blockIdx.x * 128;

    #pragma unroll
    for (int u = 0; u < 8; ++u) {
        int idx = tid + u * 256;
        int row = idx >> 4, slot = idx & 15;
        int gr = m0 + row; if (gr >= N_NODES) gr = N_NODES - 1;
        float4 v = *reinterpret_cast<const float4*>(h + (size_t)gr * 128 + slot * 8);
        int byte = row * 256 + ((slot ^ (row & 15)) << 4);
        *reinterpret_cast<float4*>(reinterpret_cast<char*>(As) + byte) = v;
    }
    #pragma unroll
    for (int u = 0; u < 6; ++u) {
        int idx = tid + u * 256;
        int row = idx >> 4, slot = idx & 15;
        float4 v = *reinterpret_cast<const float4*>(Wt + (size_t)row * 128 + slot * 8);
        int byte = row * 256 + ((slot ^ (row & 15)) << 4);
        *reinterpret_cast<float4*>(reinterpret_cast<char*>(Bs) + byte) = v;
    }
    __syncthreads();

    f32x4 acc[2][6] = {};
    #pragma unroll
    for (int ks = 0; ks < 4; ++ks) {
        bf16x8 af[2], bfr[6];
        #pragma unroll
        for (int m = 0; m < 2; ++m) {
            int row = wave * 32 + m * 16 + (lane & 15);
            int slot = ks * 4 + (lane >> 4);
            int byte = row * 256 + ((slot ^ (row & 15)) << 4);
            af[m] = *reinterpret_cast<const bf16x8*>(reinterpret_cast<const char*>(As) + byte);
        }
        #pragma unroll
        for (int nn = 0; nn < 6; ++nn) {
            int row = nn * 16 + (lane & 15);
            int slot = ks * 4 + (lane >> 4);
            int byte = row * 256 + ((slot ^ (row & 15)) << 4);
            bfr[nn] = *reinterpret_cast<const bf16x8*>(reinterpret_cast<const char*>(Bs) + byte);
        }
        #pragma unroll
        for (int m = 0; m < 2; ++m)
            #pragma unroll
            for (int nn = 0; nn < 6; ++nn)
                acc[m][nn] = __builtin_amdgcn_mfma_f32_16x16x32_bf16(
                    af[m], bfr[nn], acc[m][nn], 0, 0, 0);
    }

    #pragma unroll
    for (int m = 0; m < 2; ++m) {
        int rloc = m0 + wave * 32 + m * 16 + (lane >> 4) * 4;
        #pragma unroll
        for (int nn = 0; nn < 6; ++nn) {
            int c = nn * 16 + (lane & 15);
            #pragma unroll
            for (int q = 0; q < 4; ++q) {
                int row = rloc + q;
                if (row < N_NODES) Yh[(size_t)row * 96 + c] = f2bf(acc[m][nn][q]);
            }
        }
    }
}

// ---------------------------------------------------------------------------
// Layer-2 aggregate + bias + log_softmax, fused. 4 nodes/wave, 16 lanes/node.
// out[n][c] = logsoftmax( Yh[n][c] + b2[c] + sum_e w_e * Yh[src_e][16+rel*16+c] )
// ---------------------------------------------------------------------------
__global__ __launch_bounds__(256) void agg2_softmax(
    const ushort* __restrict__ Yh, const int2* __restrict__ edges,
    const int* __restrict__ offs, const float* __restrict__ b2,
    float* __restrict__ out) {
    int wave = threadIdx.x >> 6, lane = threadIdx.x & 63;
    int q = lane >> 4, c = lane & 15;
    int n = (blockIdx.x * 4 + wave) * 4 + q;
    int nn = (n < N_NODES) ? n : N_NODES - 1;
    int o0 = offs[nn * N_REL], o5 = offs[nn * N_REL + 5];
    int deg = o5 - o0;

    float val = bfu(Yh[(size_t)nn * 96 + c]) + b2[c];

    int md = deg;
    md = max(md, __shfl_xor(md, 16));
    md = max(md, __shfl_xor(md, 32));
    md = __builtin_amdgcn_readfirstlane(md);

    for (int b = 0; b < md; b += 16) {
        int idx = o0 + b + c;
        int2 er = (idx < o5) ? edges[idx] : make_int2(0, 0);   // (0,0) pads: w=0
        #pragma unroll
        for (int j = 0; j < 16; ++j) {
            int m = __shfl(er.x, q * 16 + j);
            float w = __uint_as_float(__shfl(er.y, q * 16 + j));
            int s = m & 0x1FFFF;
            int rel = (m >> 17) & 7;
            val = fmaf(w, bfu(Yh[(size_t)s * 96 + 16 + rel * 16 + c]), val);
        }
    }

    // log_softmax over the 16-lane group
    float mx = val;
    #pragma unroll
    for (int i = 1; i < 16; i <<= 1) mx = fmaxf(mx, __shfl_xor(mx, i));
    float ex = expf(val - mx);
    float ssum = ex;
    #pragma unroll
    for (int i = 1; i < 16; i <<= 1) ssum += __shfl_xor(ssum, i);
    float r = val - mx - logf(ssum);
    if (n < N_NODES) out[(size_t)n * 16 + c] = r;
}

// ---------------------------------------------------------------------------
extern "C" void kernel_launch(void* const* d_in, const int* in_sizes, int n_in,
                              void* d_out, int out_size, void* d_ws, size_t ws_size,
                              hipStream_t stream) {
    const float* x     = (const float*)d_in[0];
    const int*   ei    = (const int*)d_in[1];
    const int*   src   = ei;
    const int*   dst   = ei + N_EDGES;
    const float* ew    = (const float*)d_in[2];
    const int*   et    = (const int*)d_in[3];
    const float* W1    = (const float*)d_in[4];
    const float* root1 = (const float*)d_in[5];
    const float* b1    = (const float*)d_in[6];
    const float* W2    = (const float*)d_in[7];
    const float* root2 = (const float*)d_in[8];
    const float* b2    = (const float*)d_in[9];
    float* out = (float*)d_out;

    // workspace layout
    char* ws = (char*)d_ws;
    int*    offs    = (int*)ws;                        //  2,000,004 B -> pad 2,000,896
    int*    ccur    = (int*)(ws + 2000896);            //      1,024 B
    int*    cstart  = (int*)(ws + 2001920);            //      2,176 B pad
    int2*   edges   = (int2*)(ws + 2004096);           // 12,800,000 B
    ushort* xh      = (ushort*)(ws + 14804096);        // 25,600,000 B
    ushort* h       = (ushort*)(ws + 40404096);        // 25,600,000 B
    ushort* Wt1     = (ushort*)(ws + 66004096);        //    196,608 B
    ushort* Wt2s    = (ushort*)(ws + 66200704);        //     24,576 B
    unsigned int* xq = (unsigned int*)(ws + 66225280); // 12,800,000 B (fp8 table)
    // union region @79,026,000 (align 256): pe (25.7MB, build) -> A640 (128.1MB) -> Yh (19.2MB)
    int2*   pe      = (int2*)(ws + 79026176);
    ushort* Abuf    = (ushort*)(ws + 79026176);
    ushort* Yh      = (ushort*)(ws + 79026176);

    const int chunk = (ws_size >= 220000000ull) ? N_NODES : 25000;
    const int nch   = N_NODES / chunk;

    // --- precision conversions (x read once -> bf16 + fp8 tables) ---
    cvt_feat<<<((N_NODES * 128 / 4) + 255) / 256, 256, 0, stream>>>(x, xh, xq);
    cvt_wstack<<<dim3(3, 128), 256, 0, stream>>>(W1, root1, Wt1);
    cvt_w2<<<(96 * 128 + 255) / 256, 256, 0, stream>>>(W2, root2, Wt2s);

    // --- build (dst,rel)-bucketed CSR: 3 passes ---
    hipMemsetAsync(ccur, 0, 1024, stream);
    partition_append<<<(N_EDGES + 4095) / 4096, 1024, 0, stream>>>(src, dst, ew, et, ccur, pe);
    cscan<<<1, 256, 0, stream>>>(ccur, cstart, offs);
    bucket_sort<<<NCOARSE, 1024, 0, stream>>>(ccur, cstart, pe, edges, offs);

    // --- layer 1: fp8 gather aggregates (640-wide) + GEMM with xh root segment ---
    for (int cc = 0; cc < nch; ++cc) {
        gather_all<<<chunk / 4, 256, 0, stream>>>(
            (const ushort*)xq, edges, offs, Abuf, cc * chunk);
        gemmL1<<<(chunk + 127) / 128, 256, 0, stream>>>(
            xh, Abuf, Wt1, b1, h, cc * chunk, chunk);
    }

    // --- layer 2: transform-first (Yh = h @ Wt2s^T, bf16), 16-wide aggregate ---
    gemm96<<<(N_NODES + 127) / 128, 256, 0, stream>>>(h, Wt2s, Yh);
    agg2_softmax<<<(N_NODES + 15) / 16, 256, 0, stream>>>(Yh, edges, offs, b2, out);
}

// Round 11
// 217.077 us; speedup vs baseline: 2.5936x; 1.0348x over previous
//
#include <hip/hip_runtime.h>

// Problem constants (from reference)
#define N_NODES 100000
#define N_EDGES 1600000
#define N_REL   5
#define M_BUCKETS (N_NODES * N_REL)          // 500000 (dst,rel) buckets
#define NCOARSE  196                         // ceil(N_NODES / 512) coarse buckets
#define CAP      16384                       // pe capacity per coarse bucket (avg 8163)

using bf16x8 = __attribute__((ext_vector_type(8))) short;
using f32x4  = __attribute__((ext_vector_type(4))) float;
using f32x2  = __attribute__((ext_vector_type(2))) float;

__device__ __forceinline__ unsigned short f2bf(float f) {
    unsigned int u = __float_as_uint(f);
    u += 0x7fffu + ((u >> 16) & 1u);          // RNE
    return (unsigned short)(u >> 16);
}
__device__ __forceinline__ float bflo(unsigned int p) { return __uint_as_float(p << 16); }
__device__ __forceinline__ float bfhi(unsigned int p) { return __uint_as_float(p & 0xffff0000u); }
__device__ __forceinline__ float bfu(unsigned short u) { return __uint_as_float((unsigned int)u << 16); }

// ---------------------------------------------------------------------------
// Pass 1: append edges into coarse (dst>>9) regions of pe.
// Record = (src | rel<<17 | dlow9<<20, ew).
// ---------------------------------------------------------------------------
__global__ __launch_bounds__(1024) void partition_append(
    const int* __restrict__ src, const int* __restrict__ dstv,
    const float* __restrict__ ew, const int* __restrict__ et,
    int* __restrict__ ccur, int2* __restrict__ pe) {
    __shared__ int lh[256];
    __shared__ int lb[256];
    int tid = threadIdx.x;
    if (tid < 256) lh[tid] = 0;
    __syncthreads();
    int base = blockIdx.x * 4096;
    int key[4], rank[4], meta[4];
    float w[4];
    #pragma unroll
    for (int i = 0; i < 4; ++i) {
        int e = base + i * 1024 + tid;
        key[i] = -1;
        if (e < N_EDGES) {
            int d = dstv[e];
            key[i] = d >> 9;
            meta[i] = src[e] | (et[e] << 17) | ((d & 511) << 20);
            w[i] = ew[e];
            rank[i] = atomicAdd(&lh[key[i]], 1);
        }
    }
    __syncthreads();
    if (tid < 256) {
        int c = lh[tid];
        lb[tid] = c ? atomicAdd(&ccur[tid], c) : 0;
    }
    __syncthreads();
    #pragma unroll
    for (int i = 0; i < 4; ++i)
        if (key[i] >= 0) {
            int pos = lb[key[i]] + rank[i];
            if (pos < CAP)
                pe[((size_t)key[i] << 14) + pos] = make_int2(meta[i], __float_as_int(w[i]));
        }
}

// Pass 2 (tiny): exclusive scan of 256 coarse counts -> global bases; sentinel.
__global__ __launch_bounds__(256) void cscan(const int* __restrict__ ccur,
                                             int* __restrict__ cstart,
                                             int* __restrict__ offs) {
    __shared__ int lds[256];
    int tid = threadIdx.x;
    int v = ccur[tid];
    lds[tid] = v;
    __syncthreads();
    for (int d = 1; d < 256; d <<= 1) {
        int t = (tid >= d) ? lds[tid - d] : 0;
        __syncthreads();
        lds[tid] += t;
        __syncthreads();
    }
    cstart[tid] = lds[tid] - v;
    if (tid == 0) offs[M_BUCKETS] = N_EDGES;
}

// ---------------------------------------------------------------------------
// Pass 3: one block per coarse bucket: LDS fine-histogram + wave-shfl scan
// (2 barriers instead of 20) -> offs slice + scatter to final dense order.
// Folds 1/deg into w; keeps rel bits 17-19. Edges grouped by relation.
// ---------------------------------------------------------------------------
__global__ __launch_bounds__(1024) void bucket_sort(
    const int* __restrict__ ccnt, const int* __restrict__ cstart,
    const int2* __restrict__ pe, int2* __restrict__ edges, int* __restrict__ offs) {
    int cb = blockIdx.x;
    int node0 = cb << 9;
    if (node0 >= N_NODES) return;
    int nNodes = N_NODES - node0; if (nNodes > 512) nNodes = 512;
    int nf = nNodes * N_REL;                 // fine buckets in this block (<=2560)
    __shared__ int hist[2560];
    __shared__ int cur[2560];
    __shared__ int wtot[16];
    __shared__ int woff[16];
    int tid = threadIdx.x;
    int wid = tid >> 6, lane = tid & 63;
    int cnt = ccnt[cb]; if (cnt > CAP) cnt = CAP;
    int gbase = cstart[cb];
    const int2* my = pe + ((size_t)cb << 14);

    for (int i = tid; i < nf; i += 1024) hist[i] = 0;
    __syncthreads();
    for (int i = tid; i < cnt; i += 1024) {
        int m = my[i].x;
        int fb = ((m >> 20) & 511) * N_REL + ((m >> 17) & 7);
        atomicAdd(&hist[fb], 1);
    }
    __syncthreads();

    // exclusive scan over hist[0..nf): 3 elems/thread, wave shfl-scan + 16 partials
    int t0 = tid * 3;
    int a0 = (t0 + 0 < nf) ? hist[t0 + 0] : 0;
    int a1 = (t0 + 1 < nf) ? hist[t0 + 1] : 0;
    int a2 = (t0 + 2 < nf) ? hist[t0 + 2] : 0;
    int s = a0 + a1 + a2;
    int incl = s;
    #pragma unroll
    for (int d = 1; d < 64; d <<= 1) {
        int t = __shfl_up(incl, d);
        if (lane >= d) incl += t;
    }
    if (lane == 63) wtot[wid] = incl;
    __syncthreads();
    if (wid == 0 && lane < 16) {
        int v = wtot[lane];
        int inc2 = v;
        #pragma unroll
        for (int d = 1; d < 16; d <<= 1) {
            int t = __shfl_up(inc2, d);
            if (lane >= d) inc2 += t;
        }
        woff[lane] = inc2 - v;   // exclusive wave offset
    }
    __syncthreads();
    int excl = incl - s + woff[wid];

    int gb0 = node0 * N_REL;
    if (t0 + 0 < nf) { offs[gb0 + t0 + 0] = gbase + excl; cur[t0 + 0] = excl; }
    excl += a0;
    if (t0 + 1 < nf) { offs[gb0 + t0 + 1] = gbase + excl; cur[t0 + 1] = excl; }
    excl += a1;
    if (t0 + 2 < nf) { offs[gb0 + t0 + 2] = gbase + excl; cur[t0 + 2] = excl; }
    __syncthreads();

    for (int i = tid; i < cnt; i += 1024) {
        int2 r = my[i];
        int fb = ((r.x >> 20) & 511) * N_REL + ((r.x >> 17) & 7);
        int pos = gbase + atomicAdd(&cur[fb], 1);
        float wf = __int_as_float(r.y) / (float)hist[fb];   // fold 1/deg
        edges[pos] = make_int2(r.x & 0xFFFFF, __float_as_int(wf)); // src|rel<<17
    }
}

// ---------------------------------------------------------------------------
// Feature conversion: one read of x -> xh (bf16, for GEMM root segment)
//                                    + xq (fp8 e4m3, for the gather table)
// ---------------------------------------------------------------------------
__global__ void cvt_feat(const float* __restrict__ x, ushort* __restrict__ xh,
                         unsigned int* __restrict__ xq) {
    int i = blockIdx.x * blockDim.x + threadIdx.x;   // float4 index
    if (i >= (N_NODES * 128) / 4) return;
    float4 v = reinterpret_cast<const float4*>(x)[i];
    ushort4 o;
    o.x = f2bf(v.x); o.y = f2bf(v.y); o.z = f2bf(v.z); o.w = f2bf(v.w);
    reinterpret_cast<ushort4*>(xh)[i] = o;
    int p = __builtin_amdgcn_cvt_pk_fp8_f32(v.x, v.y, 0, false);
    p = __builtin_amdgcn_cvt_pk_fp8_f32(v.z, v.w, p, true);
    xq[i] = (unsigned int)p;
}

// Stack [root1; W1_0..W1_4] transposed: Wt[o][seg*128+k] (o: 128 outs).
__global__ void cvt_wstack(const float* __restrict__ W, const float* __restrict__ root,
                           ushort* __restrict__ Wt) {
    int t = blockIdx.x * blockDim.x + threadIdx.x;   // 0..767
    int o = blockIdx.y;
    int seg = t >> 7, k = t & 127;
    float v = (seg == 0) ? root[k * 128 + o] : W[(size_t)(seg - 1) * 128 * 128 + k * 128 + o];
    Wt[(size_t)o * 768 + t] = f2bf(v);
}

// Layer-2 stacked weights: Wt2s[o][k], o in 0..95: cols 0-15 root2, 16+r*16+c = W2_r col c.
__global__ void cvt_w2(const float* __restrict__ W2, const float* __restrict__ root2,
                       ushort* __restrict__ Wt2s) {
    int i = blockIdx.x * blockDim.x + threadIdx.x;
    if (i >= 96 * 128) return;
    int o = i >> 7, k = i & 127;
    float v = (o < 16) ? root2[k * 16 + o]
                       : W2[((size_t)((o >> 4) - 1) * 128 + k) * 16 + (o & 15)];
    Wt2s[i] = f2bf(v);
}

// ---------------------------------------------------------------------------
// Layer-1 gather: one wave per node; fp8 feature table (128 B/edge). Flat
// loop, 8-deep load clusters (2x the MLP of round 9's 4-deep), scalar
// boundary flushes. 1/deg pre-folded into w.
// ---------------------------------------------------------------------------
__global__ __launch_bounds__(256) void gather_all(
    const ushort* __restrict__ featq,  // fp8 [N][128] viewed as ushort[N][64]
    const int2* __restrict__ edges,    // (src|rel<<17, w/deg) relation-sorted
    const int* __restrict__ offs,      // exclusive starts, offs[M]=E
    ushort* __restrict__ A,            // [rows][640] bf16
    int node0) {
    int n = __builtin_amdgcn_readfirstlane(node0 + blockIdx.x * 4 + (threadIdx.x >> 6));
    int lane = threadIdx.x & 63;
    int b0 = n * N_REL;
    int o0 = __builtin_amdgcn_readfirstlane(offs[b0 + 0]);
    int o1 = __builtin_amdgcn_readfirstlane(offs[b0 + 1]);
    int o2 = __builtin_amdgcn_readfirstlane(offs[b0 + 2]);
    int o3 = __builtin_amdgcn_readfirstlane(offs[b0 + 3]);
    int o4 = __builtin_amdgcn_readfirstlane(offs[b0 + 4]);
    int o5 = __builtin_amdgcn_readfirstlane(offs[b0 + 5]);
    unsigned int* Ap = reinterpret_cast<unsigned int*>(A) + (size_t)(n - node0) * 320;

    int deg = o5 - o0;
    if (deg <= 64) {
        int2 er = (o0 + lane < o5) ? edges[o0 + lane] : make_int2(0, 0);
        unsigned long long bp =
              (unsigned long long)(unsigned)(o1 - o0)
            | ((unsigned long long)(unsigned)(o2 - o0) << 8)
            | ((unsigned long long)(unsigned)(o3 - o0) << 16)
            | ((unsigned long long)(unsigned)(o4 - o0) << 24)
            | ((unsigned long long)(unsigned)deg << 32);
        float ax = 0.f, ay = 0.f;
        int seg = 0;
        auto flushAt = [&](int jj) {
            while (seg < 5 && jj == (int)((bp >> (seg * 8)) & 0xFFull)) {
                Ap[64 * seg + lane] =
                    (unsigned int)f2bf(ax) | ((unsigned int)f2bf(ay) << 16);
                ax = 0.f; ay = 0.f; ++seg;
            }
        };
        int deg8 = (deg + 7) & ~7;
        for (int j = 0; j < deg8; j += 8) {
            // ---- load cluster: 8 independent fp8 gathers in flight ----
            unsigned short q[8];
            float w[8];
            #pragma unroll
            for (int u = 0; u < 8; ++u) {
                int m = __builtin_amdgcn_readlane(er.x, j + u);
                q[u] = featq[((size_t)(m & 0x1FFFF) << 6) + lane];
            }
            #pragma unroll
            for (int u = 0; u < 8; ++u)
                w[u] = __uint_as_float(__builtin_amdgcn_readlane(er.y, j + u));
            // ---- consume, flushing segment snapshots at boundaries ----
            #pragma unroll
            for (int u = 0; u < 8; ++u) {
                flushAt(j + u);
                f32x2 f = __builtin_amdgcn_cvt_pk_f32_fp8((int)q[u], false);
                ax = fmaf(w[u], f.x, ax); ay = fmaf(w[u], f.y, ay);
            }
        }
        while (seg < 5) {
            Ap[64 * seg + lane] =
                (unsigned int)f2bf(ax) | ((unsigned int)f2bf(ay) << 16);
            ax = 0.f; ay = 0.f; ++seg;
        }
    } else {
        int o[6] = {o0, o1, o2, o3, o4, o5};
        #pragma unroll
        for (int r = 0; r < 5; ++r) {
            int s0 = o[r], e1 = o[r + 1];
            float ax = 0.f, ay = 0.f;
            for (int base = s0; base < e1; base += 64) {
                int idx = base + lane;
                int2 er = (idx < e1) ? edges[idx] : make_int2(0, 0);
                int m = e1 - base; if (m > 64) m = 64;
                for (int j = 0; j < m; ++j) {
                    int mm = __builtin_amdgcn_readlane(er.x, j);
                    float w = __uint_as_float(__builtin_amdgcn_readlane(er.y, j));
                    unsigned short q = featq[((size_t)(mm & 0x1FFFF) << 6) + lane];
                    f32x2 f = __builtin_amdgcn_cvt_pk_f32_fp8((int)q, false);
                    ax = fmaf(w, f.x, ax);
                    ay = fmaf(w, f.y, ay);
                }
            }
            Ap[64 * r + lane] = (unsigned int)f2bf(ax) | ((unsigned int)f2bf(ay) << 16);
        }
    }
}

// ---------------------------------------------------------------------------
// Layer-1 GEMM: h[row][128] = relu([xh_row | A640_row] @ Wt1[128][768]^T + b1)
// ---------------------------------------------------------------------------
__global__ __launch_bounds__(256) void gemmL1(
    const ushort* __restrict__ xh,   // [N][128] bf16
    const ushort* __restrict__ A,    // chunk-local [rows][640] bf16
    const ushort* __restrict__ Wt,   // [128][768] bf16
    const float* __restrict__ bias,  // [128]
    ushort* __restrict__ h,          // [N][128] bf16
    int row0, int nrows) {
    __shared__ ushort As[128 * 64];          // 16 KB
    __shared__ ushort Bs[128 * 64];          // 16 KB
    const int tid = threadIdx.x, lane = tid & 63, wave = tid >> 6;
    const int m0 = blockIdx.x * 128;

    constexpr int MF = 4, NF = 4;
    const int wr0 = (wave >> 1) * 64;
    const int wc0 = (wave & 1) * 64;

    f32x4 acc[MF][NF] = {};

    for (int ks = 0; ks < 12; ++ks) {
        #pragma unroll
        for (int u = 0; u < 4; ++u) {
            int idx = tid + u * 256;
            int row = idx >> 3, slot = idx & 7;
            float4 v;
            if (ks < 2) {
                int gr = row0 + m0 + row; if (gr >= N_NODES) gr = N_NODES - 1;
                v = *reinterpret_cast<const float4*>(xh + (size_t)gr * 128 + ks * 64 + slot * 8);
            } else {
                v = *reinterpret_cast<const float4*>(
                    A + (size_t)(m0 + row) * 640 + (ks - 2) * 64 + slot * 8);
            }
            int byte = row * 128 + ((slot ^ (row & 7)) << 4);
            *reinterpret_cast<float4*>(reinterpret_cast<char*>(As) + byte) = v;
        }
        #pragma unroll
        for (int u = 0; u < 4; ++u) {
            int idx = tid + u * 256;
            int row = idx >> 3, slot = idx & 7;
            float4 v = *reinterpret_cast<const float4*>(
                Wt + (size_t)row * 768 + ks * 64 + slot * 8);
            int byte = row * 128 + ((slot ^ (row & 7)) << 4);
            *reinterpret_cast<float4*>(reinterpret_cast<char*>(Bs) + byte) = v;
        }
        __syncthreads();

        #pragma unroll
        for (int kh = 0; kh < 2; ++kh) {
            bf16x8 af[MF], bfr[NF];
            #pragma unroll
            for (int m = 0; m < MF; ++m) {
                int row = wr0 + m * 16 + (lane & 15);
                int slot = kh * 4 + (lane >> 4);
                int byte = row * 128 + ((slot ^ (row & 7)) << 4);
                af[m] = *reinterpret_cast<const bf16x8*>(
                    reinterpret_cast<const char*>(As) + byte);
            }
            #pragma unroll
            for (int nn = 0; nn < NF; ++nn) {
                int row = wc0 + nn * 16 + (lane & 15);
                int slot = kh * 4 + (lane >> 4);
                int byte = row * 128 + ((slot ^ (row & 7)) << 4);
                bfr[nn] = *reinterpret_cast<const bf16x8*>(
                    reinterpret_cast<const char*>(Bs) + byte);
            }
            #pragma unroll
            for (int m = 0; m < MF; ++m)
                #pragma unroll
                for (int nn = 0; nn < NF; ++nn)
                    acc[m][nn] = __builtin_amdgcn_mfma_f32_16x16x32_bf16(
                        af[m], bfr[nn], acc[m][nn], 0, 0, 0);
        }
        __syncthreads();
    }

    #pragma unroll
    for (int m = 0; m < MF; ++m) {
        int rloc = wr0 + m * 16 + (lane >> 4) * 4;
        #pragma unroll
        for (int nn = 0; nn < NF; ++nn) {
            int c = wc0 + nn * 16 + (lane & 15);
            float bv = bias[c];
            #pragma unroll
            for (int q = 0; q < 4; ++q) {
                int lrow = m0 + rloc + q;
                if (lrow < nrows) {
                    int grow = row0 + lrow;
                    float v = fmaxf(acc[m][nn][q] + bv, 0.f);
                    h[(size_t)grow * 128 + c] = f2bf(v);
                }
            }
        }
    }
}

// ---------------------------------------------------------------------------
// Layer-2 transform: Yh[n][96] = h[n][128] @ Wt2s[96][128]^T   (bf16 out)
// ---------------------------------------------------------------------------
__global__ __launch_bounds__(256) void gemm96(
    const ushort* __restrict__ h, const ushort* __restrict__ Wt,
    ushort* __restrict__ Yh) {
    __shared__ ushort As[128 * 128];   // 32 KB
    __shared__ ushort Bs[96 * 128];    // 24 KB
    const int tid = threadIdx.x, lane = tid & 63, wave = tid >> 6;
    const int m0 = blockIdx.x * 128;

    #pragma unroll
    for (int u = 0; u < 8; ++u) {
        int idx = tid + u * 256;
        int row = idx >> 4, slot = idx & 15;
        int gr = m0 + row; if (gr >= N_NODES) gr = N_NODES - 1;
        float4 v = *reinterpret_cast<const float4*>(h + (size_t)gr * 128 + slot * 8);
        int byte = row * 256 + ((slot ^ (row & 15)) << 4);
        *reinterpret_cast<float4*>(reinterpret_cast<char*>(As) + byte) = v;
    }
    #pragma unroll
    for (int u = 0; u < 6; ++u) {
        int idx = tid + u * 256;
        int row = idx >> 4, slot = idx & 15;
        float4 v = *reinterpret_cast<const float4*>(Wt + (size_t)row * 128 + slot * 8);
        int byte = row * 256 + ((slot ^ (row & 15)) << 4);
        *reinterpret_cast<float4*>(reinterpret_cast<char*>(Bs) + byte) = v;
    }
    __syncthreads();

    f32x4 acc[2][6] = {};
    #pragma unroll
    for (int ks = 0; ks < 4; ++ks) {
        bf16x8 af[2], bfr[6];
        #pragma unroll
        for (int m = 0; m < 2; ++m) {
            int row = wave * 32 + m * 16 + (lane & 15);
            int slot = ks * 4 + (lane >> 4);
            int byte = row * 256 + ((slot ^ (row & 15)) << 4);
            af[m] = *reinterpret_cast<const bf16x8*>(reinterpret_cast<const char*>(As) + byte);
        }
        #pragma unroll
        for (int nn = 0; nn < 6; ++nn) {
            int row = nn * 16 + (lane & 15);
            int slot = ks * 4 + (lane >> 4);
            int byte = row * 256 + ((slot ^ (row & 15)) << 4);
            bfr[nn] = *reinterpret_cast<const bf16x8*>(reinterpret_cast<const char*>(Bs) + byte);
        }
        #pragma unroll
        for (int m = 0; m < 2; ++m)
            #pragma unroll
            for (int nn = 0; nn < 6; ++nn)
                acc[m][nn] = __builtin_amdgcn_mfma_f32_16x16x32_bf16(
                    af[m], bfr[nn], acc[m][nn], 0, 0, 0);
    }

    #pragma unroll
    for (int m = 0; m < 2; ++m) {
        int rloc = m0 + wave * 32 + m * 16 + (lane >> 4) * 4;
        #pragma unroll
        for (int nn = 0; nn < 6; ++nn) {
            int c = nn * 16 + (lane & 15);
            #pragma unroll
            for (int q = 0; q < 4; ++q) {
                int row = rloc + q;
                if (row < N_NODES) Yh[(size_t)row * 96 + c] = f2bf(acc[m][nn][q]);
            }
        }
    }
}

// ---------------------------------------------------------------------------
// Layer-2 aggregate + bias + log_softmax, fused. 4 nodes/wave, 16 lanes/node.
// Per-group degree loop (no wave-max waste); shfl sources stay in-group.
// ---------------------------------------------------------------------------
__global__ __launch_bounds__(256) void agg2_softmax(
    const ushort* __restrict__ Yh, const int2* __restrict__ edges,
    const int* __restrict__ offs, const float* __restrict__ b2,
    float* __restrict__ out) {
    int wave = threadIdx.x >> 6, lane = threadIdx.x & 63;
    int q = lane >> 4, c = lane & 15;
    int n = (blockIdx.x * 4 + wave) * 4 + q;
    int nn = (n < N_NODES) ? n : N_NODES - 1;
    int o0 = offs[nn * N_REL], o5 = offs[nn * N_REL + 5];
    int deg = o5 - o0;

    float val = bfu(Yh[(size_t)nn * 96 + c]) + b2[c];

    for (int b = 0; b < deg; b += 16) {      // per-group bound: divergence is exec-masked
        int idx = o0 + b + c;
        int2 er = (idx < o5) ? edges[idx] : make_int2(0, 0);   // (0,0) pads: w=0
        #pragma unroll
        for (int j = 0; j < 16; ++j) {
            int m = __shfl(er.x, q * 16 + j);
            float w = __uint_as_float(__shfl(er.y, q * 16 + j));
            int s = m & 0x1FFFF;
            int rel = (m >> 17) & 7;
            val = fmaf(w, bfu(Yh[(size_t)s * 96 + 16 + rel * 16 + c]), val);
        }
    }

    // log_softmax over the 16-lane group
    float mx = val;
    #pragma unroll
    for (int i = 1; i < 16; i <<= 1) mx = fmaxf(mx, __shfl_xor(mx, i));
    float ex = expf(val - mx);
    float ssum = ex;
    #pragma unroll
    for (int i = 1; i < 16; i <<= 1) ssum += __shfl_xor(ssum, i);
    float r = val - mx - logf(ssum);
    if (n < N_NODES) out[(size_t)n * 16 + c] = r;
}

// ---------------------------------------------------------------------------
extern "C" void kernel_launch(void* const* d_in, const int* in_sizes, int n_in,
                              void* d_out, int out_size, void* d_ws, size_t ws_size,
                              hipStream_t stream) {
    const float* x     = (const float*)d_in[0];
    const int*   ei    = (const int*)d_in[1];
    const int*   src   = ei;
    const int*   dst   = ei + N_EDGES;
    const float* ew    = (const float*)d_in[2];
    const int*   et    = (const int*)d_in[3];
    const float* W1    = (const float*)d_in[4];
    const float* root1 = (const float*)d_in[5];
    const float* b1    = (const float*)d_in[6];
    const float* W2    = (const float*)d_in[7];
    const float* root2 = (const float*)d_in[8];
    const float* b2    = (const float*)d_in[9];
    float* out = (float*)d_out;

    // workspace layout
    char* ws = (char*)d_ws;
    int*    offs    = (int*)ws;                        //  2,000,004 B -> pad 2,000,896
    int*    ccur    = (int*)(ws + 2000896);            //      1,024 B
    int*    cstart  = (int*)(ws + 2001920);            //      2,176 B pad
    int2*   edges   = (int2*)(ws + 2004096);           // 12,800,000 B
    ushort* xh      = (ushort*)(ws + 14804096);        // 25,600,000 B
    ushort* h       = (ushort*)(ws + 40404096);        // 25,600,000 B
    ushort* Wt1     = (ushort*)(ws + 66004096);        //    196,608 B
    ushort* Wt2s    = (ushort*)(ws + 66200704);        //     24,576 B
    unsigned int* xq = (unsigned int*)(ws + 66225280); // 12,800,000 B (fp8 table)
    // union region: pe (25.7MB, build) -> A640 (128.1MB) -> Yh (19.2MB)
    int2*   pe      = (int2*)(ws + 79026176);
    ushort* Abuf    = (ushort*)(ws + 79026176);
    ushort* Yh      = (ushort*)(ws + 79026176);

    const int chunk = (ws_size >= 220000000ull) ? N_NODES : 25000;
    const int nch   = N_NODES / chunk;

    // --- precision conversions (x read once -> bf16 + fp8 tables) ---
    cvt_feat<<<((N_NODES * 128 / 4) + 255) / 256, 256, 0, stream>>>(x, xh, xq);
    cvt_wstack<<<dim3(3, 128), 256, 0, stream>>>(W1, root1, Wt1);
    cvt_w2<<<(96 * 128 + 255) / 256, 256, 0, stream>>>(W2, root2, Wt2s);

    // --- build (dst,rel)-bucketed CSR: 3 passes ---
    hipMemsetAsync(ccur, 0, 1024, stream);
    partition_append<<<(N_EDGES + 4095) / 4096, 1024, 0, stream>>>(src, dst, ew, et, ccur, pe);
    cscan<<<1, 256, 0, stream>>>(ccur, cstart, offs);
    bucket_sort<<<NCOARSE, 1024, 0, stream>>>(ccur, cstart, pe, edges, offs);

    // --- layer 1: fp8 gather aggregates (640-wide) + GEMM with xh root segment ---
    for (int cc = 0; cc < nch; ++cc) {
        gather_all<<<chunk / 4, 256, 0, stream>>>(
            (const ushort*)xq, edges, offs, Abuf, cc * chunk);
        gemmL1<<<(chunk + 127) / 128, 256, 0, stream>>>(
            xh, Abuf, Wt1, b1, h, cc * chunk, chunk);
    }

    // --- layer 2: transform-first (Yh = h @ Wt2s^T, bf16), 16-wide aggregate ---
    gemm96<<<(N_NODES + 127) / 128, 256, 0, stream>>>(h, Wt2s, Yh);
    agg2_softmax<<<(N_NODES + 15) / 16, 256, 0, stream>>>(Yh, edges, offs, b2, out);
}

// Round 12
// 215.522 us; speedup vs baseline: 2.6123x; 1.0072x over previous
//
#include <hip/hip_runtime.h>

// Problem constants (from reference)
#define N_NODES 100000
#define N_EDGES 1600000
#define N_REL   5
#define NCOARSE  196                         // ceil(N_NODES / 512) coarse buckets
#define CAP      16384                       // pe capacity per coarse bucket (avg 8163)
#define SLACK    2560                        // max pad records per coarse bucket

using bf16x8 = __attribute__((ext_vector_type(8))) short;
using f32x4  = __attribute__((ext_vector_type(4))) float;
using f32x2  = __attribute__((ext_vector_type(2))) float;

__device__ __forceinline__ unsigned short f2bf(float f) {
    unsigned int u = __float_as_uint(f);
    u += 0x7fffu + ((u >> 16) & 1u);          // RNE
    return (unsigned short)(u >> 16);
}
__device__ __forceinline__ float bfu(unsigned short u) { return __uint_as_float((unsigned int)u << 16); }

// ---------------------------------------------------------------------------
// Pass 1: append edges into coarse (dst>>9) regions of pe.
// Record = (src | rel<<17 | dlow9<<20, ew).
// ---------------------------------------------------------------------------
__global__ __launch_bounds__(1024) void partition_append(
    const int* __restrict__ src, const int* __restrict__ dstv,
    const float* __restrict__ ew, const int* __restrict__ et,
    int* __restrict__ ccur, int2* __restrict__ pe) {
    __shared__ int lh[256];
    __shared__ int lb[256];
    int tid = threadIdx.x;
    if (tid < 256) lh[tid] = 0;
    __syncthreads();
    int base = blockIdx.x * 4096;
    int key[4], rank[4], meta[4];
    float w[4];
    #pragma unroll
    for (int i = 0; i < 4; ++i) {
        int e = base + i * 1024 + tid;
        key[i] = -1;
        if (e < N_EDGES) {
            int d = dstv[e];
            key[i] = d >> 9;
            meta[i] = src[e] | (et[e] << 17) | ((d & 511) << 20);
            w[i] = ew[e];
            rank[i] = atomicAdd(&lh[key[i]], 1);
        }
    }
    __syncthreads();
    if (tid < 256) {
        int c = lh[tid];
        lb[tid] = c ? atomicAdd(&ccur[tid], c) : 0;
    }
    __syncthreads();
    #pragma unroll
    for (int i = 0; i < 4; ++i)
        if (key[i] >= 0) {
            int pos = lb[key[i]] + rank[i];
            if (pos < CAP)
                pe[((size_t)key[i] << 14) + pos] = make_int2(meta[i], __float_as_int(w[i]));
        }
}

// Pass 2 (tiny): exclusive scan of 256 coarse counts (+SLACK pad headroom).
__global__ __launch_bounds__(256) void cscan(const int* __restrict__ ccur,
                                             int* __restrict__ cstart) {
    __shared__ int lds[256];
    int tid = threadIdx.x;
    int v = ccur[tid] + SLACK;
    lds[tid] = v;
    __syncthreads();
    for (int d = 1; d < 256; d <<= 1) {
        int t = (tid >= d) ? lds[tid - d] : 0;
        __syncthreads();
        lds[tid] += t;
        __syncthreads();
    }
    cstart[tid] = lds[tid] - v;
}

// ---------------------------------------------------------------------------
// Pass 3: one block per coarse bucket. Fine histogram, PADDED (even) scan,
// sentinel fill, per-node descriptors (nbase + packed boundaries), scatter.
// Each (node,rel) range is padded to even length with (0,0) records so the
// gather's 2-edge half-wave steps never straddle a segment boundary.
// ---------------------------------------------------------------------------
__global__ __launch_bounds__(1024) void bucket_sort(
    const int* __restrict__ ccnt, const int* __restrict__ cstart,
    const int2* __restrict__ pe, int2* __restrict__ edges,
    int* __restrict__ nbase, int2* __restrict__ nbp) {
    int cb = blockIdx.x;
    int node0 = cb << 9;
    if (node0 >= N_NODES) return;
    int nNodes = N_NODES - node0; if (nNodes > 512) nNodes = 512;
    int nf = nNodes * N_REL;
    __shared__ int hist[2560];
    __shared__ int cur[2560];
    __shared__ int wtot[16];
    __shared__ int woff[16];
    int tid = threadIdx.x;
    int wid = tid >> 6, lane = tid & 63;
    int cnt = ccnt[cb]; if (cnt > CAP) cnt = CAP;
    int gbase = cstart[cb];
    const int2* my = pe + ((size_t)cb << 14);

    for (int i = tid; i < nf; i += 1024) hist[i] = 0;
    __syncthreads();
    for (int i = tid; i < cnt; i += 1024) {
        int m = my[i].x;
        atomicAdd(&hist[((m >> 20) & 511) * N_REL + ((m >> 17) & 7)], 1);
    }
    __syncthreads();

    // exclusive scan over PADDED counts: 3 elems/thread, wave shfl + 16 partials
    int t0 = tid * 3;
    int a0 = (t0 + 0 < nf) ? ((hist[t0 + 0] + 1) & ~1) : 0;
    int a1 = (t0 + 1 < nf) ? ((hist[t0 + 1] + 1) & ~1) : 0;
    int a2 = (t0 + 2 < nf) ? ((hist[t0 + 2] + 1) & ~1) : 0;
    int s = a0 + a1 + a2;
    int incl = s;
    #pragma unroll
    for (int d = 1; d < 64; d <<= 1) {
        int t = __shfl_up(incl, d);
        if (lane >= d) incl += t;
    }
    if (lane == 63) wtot[wid] = incl;
    __syncthreads();
    if (wid == 0 && lane < 16) {
        int v = wtot[lane];
        int inc2 = v;
        #pragma unroll
        for (int d = 1; d < 16; d <<= 1) {
            int t = __shfl_up(inc2, d);
            if (lane >= d) inc2 += t;
        }
        woff[lane] = inc2 - v;
    }
    __syncthreads();
    int excl = incl - s + woff[wid];
    if (t0 + 0 < nf) cur[t0 + 0] = excl;
    excl += a0;
    if (t0 + 1 < nf) cur[t0 + 1] = excl;
    excl += a1;
    if (t0 + 2 < nf) cur[t0 + 2] = excl;
    __syncthreads();

    // sentinel records for odd-count buckets (position never hit by scatter)
    for (int i = tid; i < nf; i += 1024)
        if (hist[i] & 1)
            edges[(size_t)gbase + cur[i] + hist[i]] = make_int2(0, 0);
    // per-node descriptors: base + packed (padded, even) boundaries
    for (int i = tid; i < nNodes; i += 1024) {
        int b = i * N_REL;
        int c0 = cur[b];
        int B1 = cur[b + 1] - c0, B2 = cur[b + 2] - c0;
        int B3 = cur[b + 3] - c0, B4 = cur[b + 4] - c0;
        int degp = cur[b + 4] + ((hist[b + 4] + 1) & ~1) - c0;
        nbase[node0 + i] = gbase + c0;
        nbp[node0 + i] = make_int2(B1 | (B2 << 8) | (B3 << 16) | (B4 << 24), degp);
    }
    __syncthreads();

    for (int i = tid; i < cnt; i += 1024) {
        int2 r = my[i];
        int fb = ((r.x >> 20) & 511) * N_REL + ((r.x >> 17) & 7);
        int pos = gbase + atomicAdd(&cur[fb], 1);
        float wf = __int_as_float(r.y) / (float)hist[fb];   // fold 1/deg
        edges[pos] = make_int2(r.x & 0xFFFFF, __float_as_int(wf)); // src|rel<<17
    }
}

// ---------------------------------------------------------------------------
// Feature conversion: one read of x -> xh (bf16) + xq (fp8 e4m3)
// ---------------------------------------------------------------------------
__global__ void cvt_feat(const float* __restrict__ x, ushort* __restrict__ xh,
                         unsigned int* __restrict__ xq) {
    int i = blockIdx.x * blockDim.x + threadIdx.x;   // float4 index
    if (i >= (N_NODES * 128) / 4) return;
    float4 v = reinterpret_cast<const float4*>(x)[i];
    ushort4 o;
    o.x = f2bf(v.x); o.y = f2bf(v.y); o.z = f2bf(v.z); o.w = f2bf(v.w);
    reinterpret_cast<ushort4*>(xh)[i] = o;
    int p = __builtin_amdgcn_cvt_pk_fp8_f32(v.x, v.y, 0, false);
    p = __builtin_amdgcn_cvt_pk_fp8_f32(v.z, v.w, p, true);
    xq[i] = (unsigned int)p;
}

// Stack [root1; W1_0..W1_4] transposed: Wt[o][seg*128+k] (o: 128 outs).
__global__ void cvt_wstack(const float* __restrict__ W, const float* __restrict__ root,
                           ushort* __restrict__ Wt) {
    int t = blockIdx.x * blockDim.x + threadIdx.x;   // 0..767
    int o = blockIdx.y;
    int seg = t >> 7, k = t & 127;
    float v = (seg == 0) ? root[k * 128 + o] : W[(size_t)(seg - 1) * 128 * 128 + k * 128 + o];
    Wt[(size_t)o * 768 + t] = f2bf(v);
}

// Layer-2 stacked weights: Wt2s[o][k], o 0..95: 0-15 root2, 16+r*16+c = W2_r col c.
__global__ void cvt_w2(const float* __restrict__ W2, const float* __restrict__ root2,
                       ushort* __restrict__ Wt2s) {
    int i = blockIdx.x * blockDim.x + threadIdx.x;
    if (i >= 96 * 128) return;
    int o = i >> 7, k = i & 127;
    float v = (o < 16) ? root2[k * 16 + o]
                       : W2[((size_t)((o >> 4) - 1) * 128 + k) * 16 + (o & 15)];
    Wt2s[i] = f2bf(v);
}

// ---------------------------------------------------------------------------
// Layer-1 gather, half-wave 2-edge scheme: lanes 0-31 process even edges,
// lanes 32-63 odd edges; each lane loads a dword (4 fp8 features). One shfl
// serves both halves. Segment boundaries are even (padded), so flushes stay
// scalar; halves merge via shfl_xor(32) at each flush. ~5.5 VALU/edge.
// ---------------------------------------------------------------------------
__global__ __launch_bounds__(256) void gather_all(
    const unsigned int* __restrict__ xq,   // fp8 [N][32] dwords
    const int2* __restrict__ edges,        // padded, (src|rel<<17, w/deg)
    const int* __restrict__ nbase,
    const int2* __restrict__ nbp,
    ushort* __restrict__ A,                // [rows][640] bf16
    int node0) {
    int n = __builtin_amdgcn_readfirstlane(node0 + blockIdx.x * 4 + (threadIdx.x >> 6));
    int lane = threadIdx.x & 63;
    int half = lane >> 5, lane31 = lane & 31;
    int o0   = __builtin_amdgcn_readfirstlane(nbase[n]);
    int bx   = __builtin_amdgcn_readfirstlane(nbp[n].x);
    int degp = __builtin_amdgcn_readfirstlane(nbp[n].y);
    uint2* Ap2 = reinterpret_cast<uint2*>(A + (size_t)(n - node0) * 640);

    if (degp <= 64) {
        int2 er = (lane < degp) ? edges[o0 + lane] : make_int2(0, 0);
        unsigned long long bp = (unsigned long long)(unsigned)bx
                              | ((unsigned long long)(unsigned)degp << 32);
        float a0 = 0.f, a1 = 0.f, a2 = 0.f, a3 = 0.f;
        int seg = 0;
        auto flushAt = [&](int jj) {
            while (seg < 5 && jj == (int)((bp >> (seg * 8)) & 0xFFull)) {
                float t0 = a0 + __shfl_xor(a0, 32);
                float t1 = a1 + __shfl_xor(a1, 32);
                float t2 = a2 + __shfl_xor(a2, 32);
                float t3 = a3 + __shfl_xor(a3, 32);
                if (lane < 32) {
                    uint2 v;
                    v.x = (unsigned int)f2bf(t0) | ((unsigned int)f2bf(t1) << 16);
                    v.y = (unsigned int)f2bf(t2) | ((unsigned int)f2bf(t3) << 16);
                    Ap2[seg * 32 + lane31] = v;
                }
                a0 = a1 = a2 = a3 = 0.f; ++seg;
            }
        };
        int deg8 = (degp + 7) & ~7;
        for (int j = 0; j < deg8; j += 8) {
            unsigned int q[4]; float wv[4];
            #pragma unroll
            for (int s2 = 0; s2 < 4; ++s2) {       // 4 loads in flight (8 edges)
                int jv = j + 2 * s2 + half;
                int m = __shfl(er.x, jv);
                wv[s2] = __uint_as_float(__shfl(er.y, jv));
                q[s2] = xq[((size_t)(m & 0x1FFFF) << 5) + lane31];
            }
            #pragma unroll
            for (int s2 = 0; s2 < 4; ++s2) {
                flushAt(j + 2 * s2);
                f32x2 flo = __builtin_amdgcn_cvt_pk_f32_fp8((int)q[s2], false);
                f32x2 fhi = __builtin_amdgcn_cvt_pk_f32_fp8((int)q[s2], true);
                a0 = fmaf(wv[s2], flo.x, a0); a1 = fmaf(wv[s2], flo.y, a1);
                a2 = fmaf(wv[s2], fhi.x, a2); a3 = fmaf(wv[s2], fhi.y, a3);
            }
        }
        while (seg < 5) {
            float t0 = a0 + __shfl_xor(a0, 32);
            float t1 = a1 + __shfl_xor(a1, 32);
            float t2 = a2 + __shfl_xor(a2, 32);
            float t3 = a3 + __shfl_xor(a3, 32);
            if (lane < 32) {
                uint2 v;
                v.x = (unsigned int)f2bf(t0) | ((unsigned int)f2bf(t1) << 16);
                v.y = (unsigned int)f2bf(t2) | ((unsigned int)f2bf(t3) << 16);
                Ap2[seg * 32 + lane31] = v;
            }
            a0 = a1 = a2 = a3 = 0.f; ++seg;
        }
    } else {
        // rare slow path: full-wave, 2 feats/lane, per-relation sub-ranges
        const ushort* fq = reinterpret_cast<const ushort*>(xq);
        int B[6];
        B[0] = 0; B[1] = bx & 0xFF; B[2] = (bx >> 8) & 0xFF;
        B[3] = (bx >> 16) & 0xFF; B[4] = (unsigned)bx >> 24; B[5] = degp;
        unsigned int* Ap = reinterpret_cast<unsigned int*>(Ap2);
        #pragma unroll
        for (int r = 0; r < 5; ++r) {
            int s0 = o0 + B[r], e1 = o0 + B[r + 1];
            float ax = 0.f, ay = 0.f;
            for (int base = s0; base < e1; base += 64) {
                int2 er = (base + lane < e1) ? edges[base + lane] : make_int2(0, 0);
                int m = e1 - base; if (m > 64) m = 64;
                for (int j = 0; j < m; ++j) {
                    int mm = __builtin_amdgcn_readlane(er.x, j);
                    float w = __uint_as_float(__builtin_amdgcn_readlane(er.y, j));
                    ushort qv = fq[((size_t)(mm & 0x1FFFF) << 6) + lane];
                    f32x2 f = __builtin_amdgcn_cvt_pk_f32_fp8((int)qv, false);
                    ax = fmaf(w, f.x, ax);
                    ay = fmaf(w, f.y, ay);
                }
            }
            Ap[r * 64 + lane] = (unsigned int)f2bf(ax) | ((unsigned int)f2bf(ay) << 16);
        }
    }
}

// ---------------------------------------------------------------------------
// Layer-1 GEMM: h[row][128] = relu([xh_row | A640_row] @ Wt1[128][768]^T + b1)
// ---------------------------------------------------------------------------
__global__ __launch_bounds__(256) void gemmL1(
    const ushort* __restrict__ xh,   // [N][128] bf16
    const ushort* __restrict__ A,    // chunk-local [rows][640] bf16
    const ushort* __restrict__ Wt,   // [128][768] bf16
    const float* __restrict__ bias,  // [128]
    ushort* __restrict__ h,          // [N][128] bf16
    int row0, int nrows) {
    __shared__ ushort As[128 * 64];          // 16 KB
    __shared__ ushort Bs[128 * 64];          // 16 KB
    const int tid = threadIdx.x, lane = tid & 63, wave = tid >> 6;
    const int m0 = blockIdx.x * 128;

    constexpr int MF = 4, NF = 4;
    const int wr0 = (wave >> 1) * 64;
    const int wc0 = (wave & 1) * 64;

    f32x4 acc[MF][NF] = {};

    for (int ks = 0; ks < 12; ++ks) {
        #pragma unroll
        for (int u = 0; u < 4; ++u) {
            int idx = tid + u * 256;
            int row = idx >> 3, slot = idx & 7;
            float4 v;
            if (ks < 2) {
                int gr = row0 + m0 + row; if (gr >= N_NODES) gr = N_NODES - 1;
                v = *reinterpret_cast<const float4*>(xh + (size_t)gr * 128 + ks * 64 + slot * 8);
            } else {
                v = *reinterpret_cast<const float4*>(
                    A + (size_t)(m0 + row) * 640 + (ks - 2) * 64 + slot * 8);
            }
            int byte = row * 128 + ((slot ^ (row & 7)) << 4);
            *reinterpret_cast<float4*>(reinterpret_cast<char*>(As) + byte) = v;
        }
        #pragma unroll
        for (int u = 0; u < 4; ++u) {
            int idx = tid + u * 256;
            int row = idx >> 3, slot = idx & 7;
            float4 v = *reinterpret_cast<const float4*>(
                Wt + (size_t)row * 768 + ks * 64 + slot * 8);
            int byte = row * 128 + ((slot ^ (row & 7)) << 4);
            *reinterpret_cast<float4*>(reinterpret_cast<char*>(Bs) + byte) = v;
        }
        __syncthreads();

        #pragma unroll
        for (int kh = 0; kh < 2; ++kh) {
            bf16x8 af[MF], bfr[NF];
            #pragma unroll
            for (int m = 0; m < MF; ++m) {
                int row = wr0 + m * 16 + (lane & 15);
                int slot = kh * 4 + (lane >> 4);
                int byte = row * 128 + ((slot ^ (row & 7)) << 4);
                af[m] = *reinterpret_cast<const bf16x8*>(
                    reinterpret_cast<const char*>(As) + byte);
            }
            #pragma unroll
            for (int nn = 0; nn < NF; ++nn) {
                int row = wc0 + nn * 16 + (lane & 15);
                int slot = kh * 4 + (lane >> 4);
                int byte = row * 128 + ((slot ^ (row & 7)) << 4);
                bfr[nn] = *reinterpret_cast<const bf16x8*>(
                    reinterpret_cast<const char*>(Bs) + byte);
            }
            #pragma unroll
            for (int m = 0; m < MF; ++m)
                #pragma unroll
                for (int nn = 0; nn < NF; ++nn)
                    acc[m][nn] = __builtin_amdgcn_mfma_f32_16x16x32_bf16(
                        af[m], bfr[nn], acc[m][nn], 0, 0, 0);
        }
        __syncthreads();
    }

    #pragma unroll
    for (int m = 0; m < MF; ++m) {
        int rloc = wr0 + m * 16 + (lane >> 4) * 4;
        #pragma unroll
        for (int nn = 0; nn < NF; ++nn) {
            int c = wc0 + nn * 16 + (lane & 15);
            float bv = bias[c];
            #pragma unroll
            for (int q = 0; q < 4; ++q) {
                int lrow = m0 + rloc + q;
                if (lrow < nrows) {
                    int grow = row0 + lrow;
                    float v = fmaxf(acc[m][nn][q] + bv, 0.f);
                    h[(size_t)grow * 128 + c] = f2bf(v);
                }
            }
        }
    }
}

// ---------------------------------------------------------------------------
// Layer-2 transform: Yh[n][96] = h[n][128] @ Wt2s[96][128]^T   (bf16 out)
// ---------------------------------------------------------------------------
__global__ __launch_bounds__(256) void gemm96(
    const ushort* __restrict__ h, const ushort* __restrict__ Wt,
    ushort* __restrict__ Yh) {
    __shared__ ushort As[128 * 128];   // 32 KB
    __shared__ ushort Bs[96 * 128];    // 24 KB
    const int tid = threadIdx.x, lane = tid & 63, wave = tid >> 6;
    const int m0 = blockIdx.x * 128;

    #pragma unroll
    for (int u = 0; u < 8; ++u) {
        int idx = tid + u * 256;
        int row = idx >> 4, slot = idx & 15;
        int gr = m0 + row; if (gr >= N_NODES) gr = N_NODES - 1;
        float4 v = *reinterpret_cast<const float4*>(h + (size_t)gr * 128 + slot * 8);
        int byte = row * 256 + ((slot ^ (row & 15)) << 4);
        *reinterpret_cast<float4*>(reinterpret_cast<char*>(As) + byte) = v;
    }
    #pragma unroll
    for (int u = 0; u < 6; ++u) {
        int idx = tid + u * 256;
        int row = idx >> 4, slot = idx & 15;
        float4 v = *reinterpret_cast<const float4*>(Wt + (size_t)row * 128 + slot * 8);
        int byte = row * 256 + ((slot ^ (row & 15)) << 4);
        *reinterpret_cast<float4*>(reinterpret_cast<char*>(Bs) + byte) = v;
    }
    __syncthreads();

    f32x4 acc[2][6] = {};
    #pragma unroll
    for (int ks = 0; ks < 4; ++ks) {
        bf16x8 af[2], bfr[6];
        #pragma unroll
        for (int m = 0; m < 2; ++m) {
            int row = wave * 32 + m * 16 + (lane & 15);
            int slot = ks * 4 + (lane >> 4);
            int byte = row * 256 + ((slot ^ (row & 15)) << 4);
            af[m] = *reinterpret_cast<const bf16x8*>(reinterpret_cast<const char*>(As) + byte);
        }
        #pragma unroll
        for (int nn = 0; nn < 6; ++nn) {
            int row = nn * 16 + (lane & 15);
            int slot = ks * 4 + (lane >> 4);
            int byte = row * 256 + ((slot ^ (row & 15)) << 4);
            bfr[nn] = *reinterpret_cast<const bf16x8*>(reinterpret_cast<const char*>(Bs) + byte);
        }
        #pragma unroll
        for (int m = 0; m < 2; ++m)
            #pragma unroll
            for (int nn = 0; nn < 6; ++nn)
                acc[m][nn] = __builtin_amdgcn_mfma_f32_16x16x32_bf16(
                    af[m], bfr[nn], acc[m][nn], 0, 0, 0);
    }

    #pragma unroll
    for (int m = 0; m < 2; ++m) {
        int rloc = m0 + wave * 32 + m * 16 + (lane >> 4) * 4;
        #pragma unroll
        for (int nn = 0; nn < 6; ++nn) {
            int c = nn * 16 + (lane & 15);
            #pragma unroll
            for (int q = 0; q < 4; ++q) {
                int row = rloc + q;
                if (row < N_NODES) Yh[(size_t)row * 96 + c] = f2bf(acc[m][nn][q]);
            }
        }
    }
}

// ---------------------------------------------------------------------------
// Layer-2 aggregate + bias + log_softmax, fused. 4 nodes/wave, 16 lanes/node.
// Walks the padded edge list via nbase/nbp (pads have w=0).
// ---------------------------------------------------------------------------
__global__ __launch_bounds__(256) void agg2_softmax(
    const ushort* __restrict__ Yh, const int2* __restrict__ edges,
    const int* __restrict__ nbase, const int2* __restrict__ nbp,
    const float* __restrict__ b2, float* __restrict__ out) {
    int wave = threadIdx.x >> 6, lane = threadIdx.x & 63;
    int q = lane >> 4, c = lane & 15;
    int n = (blockIdx.x * 4 + wave) * 4 + q;
    int nn = (n < N_NODES) ? n : N_NODES - 1;
    int o0 = nbase[nn];
    int degp = nbp[nn].y;

    float val = bfu(Yh[(size_t)nn * 96 + c]) + b2[c];

    for (int b = 0; b < degp; b += 16) {
        int2 er = (b + c < degp) ? edges[o0 + b + c] : make_int2(0, 0);
        #pragma unroll
        for (int j = 0; j < 16; ++j) {
            int m = __shfl(er.x, q * 16 + j);
            float w = __uint_as_float(__shfl(er.y, q * 16 + j));
            int s = m & 0x1FFFF;
            int rel = (m >> 17) & 7;
            val = fmaf(w, bfu(Yh[(size_t)s * 96 + 16 + rel * 16 + c]), val);
        }
    }

    // log_softmax over the 16-lane group
    float mx = val;
    #pragma unroll
    for (int i = 1; i < 16; i <<= 1) mx = fmaxf(mx, __shfl_xor(mx, i));
    float ex = expf(val - mx);
    float ssum = ex;
    #pragma unroll
    for (int i = 1; i < 16; i <<= 1) ssum += __shfl_xor(ssum, i);
    float r = val - mx - logf(ssum);
    if (n < N_NODES) out[(size_t)n * 16 + c] = r;
}

// ---------------------------------------------------------------------------
extern "C" void kernel_launch(void* const* d_in, const int* in_sizes, int n_in,
                              void* d_out, int out_size, void* d_ws, size_t ws_size,
                              hipStream_t stream) {
    const float* x     = (const float*)d_in[0];
    const int*   ei    = (const int*)d_in[1];
    const int*   src   = ei;
    const int*   dst   = ei + N_EDGES;
    const float* ew    = (const float*)d_in[2];
    const int*   et    = (const int*)d_in[3];
    const float* W1    = (const float*)d_in[4];
    const float* root1 = (const float*)d_in[5];
    const float* b1    = (const float*)d_in[6];
    const float* W2    = (const float*)d_in[7];
    const float* root2 = (const float*)d_in[8];
    const float* b2    = (const float*)d_in[9];
    float* out = (float*)d_out;

    // workspace layout
    char* ws = (char*)d_ws;
    int*    ccur    = (int*)ws;                        //      1,024 B
    int*    cstart  = (int*)(ws + 1024);               //      1,024 B
    int*    nbase   = (int*)(ws + 4096);               //    400,000 B
    int2*   nbp     = (int2*)(ws + 404096);            //    800,000 B
    int2*   edges   = (int2*)(ws + 1204096);           // 16,814,080 B (padded)
    ushort* xh      = (ushort*)(ws + 18018304);        // 25,600,000 B
    ushort* h       = (ushort*)(ws + 43618304);        // 25,600,000 B
    ushort* Wt1     = (ushort*)(ws + 69218304);        //    196,608 B
    ushort* Wt2s    = (ushort*)(ws + 69414912);        //     24,576 B
    unsigned int* xq = (unsigned int*)(ws + 69439488); // 12,800,000 B (fp8 table)
    // union region @82,239,488: pe (25.7MB, build) -> Abuf (128.1MB) -> Yh (19.2MB)
    int2*   pe      = (int2*)(ws + 82239488);
    ushort* Abuf    = (ushort*)(ws + 82239488);
    ushort* Yh      = (ushort*)(ws + 82239488);

    const int chunk = (ws_size >= 220000000ull) ? N_NODES : 25000;
    const int nch   = N_NODES / chunk;

    // --- precision conversions (x read once -> bf16 + fp8 tables) ---
    cvt_feat<<<((N_NODES * 128 / 4) + 255) / 256, 256, 0, stream>>>(x, xh, xq);
    cvt_wstack<<<dim3(3, 128), 256, 0, stream>>>(W1, root1, Wt1);
    cvt_w2<<<(96 * 128 + 255) / 256, 256, 0, stream>>>(W2, root2, Wt2s);

    // --- build padded (dst,rel)-bucketed CSR: 3 passes ---
    hipMemsetAsync(ccur, 0, 1024, stream);
    partition_append<<<(N_EDGES + 4095) / 4096, 1024, 0, stream>>>(src, dst, ew, et, ccur, pe);
    cscan<<<1, 256, 0, stream>>>(ccur, cstart);
    bucket_sort<<<NCOARSE, 1024, 0, stream>>>(ccur, cstart, pe, edges, nbase, nbp);

    // --- layer 1: fp8 half-wave gather (640-wide) + GEMM with xh root segment ---
    for (int cc = 0; cc < nch; ++cc) {
        gather_all<<<chunk / 4, 256, 0, stream>>>(
            xq, edges, nbase, nbp, Abuf, cc * chunk);
        gemmL1<<<(chunk + 127) / 128, 256, 0, stream>>>(
            xh, Abuf, Wt1, b1, h, cc * chunk, chunk);
    }

    // --- layer 2: transform-first (Yh = h @ Wt2s^T, bf16), 16-wide aggregate ---
    gemm96<<<(N_NODES + 127) / 128, 256, 0, stream>>>(h, Wt2s, Yh);
    agg2_softmax<<<(N_NODES + 15) / 16, 256, 0, stream>>>(Yh, edges, nbase, nbp, b2, out);
}

// Round 13
// 210.114 us; speedup vs baseline: 2.6795x; 1.0257x over previous
//
#include <hip/hip_runtime.h>

// Problem constants (from reference)
#define N_NODES 100000
#define N_EDGES 1600000
#define N_REL   5
#define NCOARSE  196                         // ceil(N_NODES / 512) coarse buckets
#define CAP      16384                       // pe capacity per coarse bucket (avg 8163)

using bf16x8 = __attribute__((ext_vector_type(8))) short;
using f32x4  = __attribute__((ext_vector_type(4))) float;
using f32x2  = __attribute__((ext_vector_type(2))) float;

__device__ __forceinline__ unsigned short f2bf(float f) {
    unsigned int u = __float_as_uint(f);
    u += 0x7fffu + ((u >> 16) & 1u);          // RNE
    return (unsigned short)(u >> 16);
}
__device__ __forceinline__ float bfu(unsigned short u) { return __uint_as_float((unsigned int)u << 16); }

// ---------------------------------------------------------------------------
// Pass 1: append edges into coarse (dst>>9) regions of pe.
// Record = (src | rel<<17 | dlow9<<20, ew).
// ---------------------------------------------------------------------------
__global__ __launch_bounds__(1024) void partition_append(
    const int* __restrict__ src, const int* __restrict__ dstv,
    const float* __restrict__ ew, const int* __restrict__ et,
    int* __restrict__ ccur, int2* __restrict__ pe) {
    __shared__ int lh[256];
    __shared__ int lb[256];
    int tid = threadIdx.x;
    if (tid < 256) lh[tid] = 0;
    __syncthreads();
    int base = blockIdx.x * 4096;
    int key[4], rank[4], meta[4];
    float w[4];
    #pragma unroll
    for (int i = 0; i < 4; ++i) {
        int e = base + i * 1024 + tid;
        key[i] = -1;
        if (e < N_EDGES) {
            int d = dstv[e];
            key[i] = d >> 9;
            meta[i] = src[e] | (et[e] << 17) | ((d & 511) << 20);
            w[i] = ew[e];
            rank[i] = atomicAdd(&lh[key[i]], 1);
        }
    }
    __syncthreads();
    if (tid < 256) {
        int c = lh[tid];
        lb[tid] = c ? atomicAdd(&ccur[tid], c) : 0;
    }
    __syncthreads();
    #pragma unroll
    for (int i = 0; i < 4; ++i)
        if (key[i] >= 0) {
            int pos = lb[key[i]] + rank[i];
            if (pos < CAP)
                pe[((size_t)key[i] << 14) + pos] = make_int2(meta[i], __float_as_int(w[i]));
        }
}

// Pass 2 (tiny): exclusive scan of 256 coarse counts -> global bases.
__global__ __launch_bounds__(256) void cscan(const int* __restrict__ ccur,
                                             int* __restrict__ cstart) {
    __shared__ int lds[256];
    int tid = threadIdx.x;
    int v = ccur[tid];
    lds[tid] = v;
    __syncthreads();
    for (int d = 1; d < 256; d <<= 1) {
        int t = (tid >= d) ? lds[tid - d] : 0;
        __syncthreads();
        lds[tid] += t;
        __syncthreads();
    }
    cstart[tid] = lds[tid] - v;
}

// ---------------------------------------------------------------------------
// Pass 3: one block per coarse bucket. Fine histogram, wave-shfl scan,
// per-node descriptors (nbase + packed relation boundaries), dense scatter.
// Unpadded. 1/deg folded into w; rel kept in bits 17-19 for agg2.
// ---------------------------------------------------------------------------
__global__ __launch_bounds__(1024) void bucket_sort(
    const int* __restrict__ ccnt, const int* __restrict__ cstart,
    const int2* __restrict__ pe, int2* __restrict__ edges,
    int* __restrict__ nbase, int2* __restrict__ nbp) {
    int cb = blockIdx.x;
    int node0 = cb << 9;
    if (node0 >= N_NODES) return;
    int nNodes = N_NODES - node0; if (nNodes > 512) nNodes = 512;
    int nf = nNodes * N_REL;
    __shared__ int hist[2560];
    __shared__ int cur[2560];
    __shared__ int wtot[16];
    __shared__ int woff[16];
    int tid = threadIdx.x;
    int wid = tid >> 6, lane = tid & 63;
    int cnt = ccnt[cb]; if (cnt > CAP) cnt = CAP;
    int gbase = cstart[cb];
    const int2* my = pe + ((size_t)cb << 14);

    for (int i = tid; i < nf; i += 1024) hist[i] = 0;
    __syncthreads();
    for (int i = tid; i < cnt; i += 1024) {
        int m = my[i].x;
        atomicAdd(&hist[((m >> 20) & 511) * N_REL + ((m >> 17) & 7)], 1);
    }
    __syncthreads();

    // exclusive scan over hist: 3 elems/thread, wave shfl-scan + 16 partials
    int t0 = tid * 3;
    int a0 = (t0 + 0 < nf) ? hist[t0 + 0] : 0;
    int a1 = (t0 + 1 < nf) ? hist[t0 + 1] : 0;
    int a2 = (t0 + 2 < nf) ? hist[t0 + 2] : 0;
    int s = a0 + a1 + a2;
    int incl = s;
    #pragma unroll
    for (int d = 1; d < 64; d <<= 1) {
        int t = __shfl_up(incl, d);
        if (lane >= d) incl += t;
    }
    if (lane == 63) wtot[wid] = incl;
    __syncthreads();
    if (wid == 0 && lane < 16) {
        int v = wtot[lane];
        int inc2 = v;
        #pragma unroll
        for (int d = 1; d < 16; d <<= 1) {
            int t = __shfl_up(inc2, d);
            if (lane >= d) inc2 += t;
        }
        woff[lane] = inc2 - v;
    }
    __syncthreads();
    int excl = incl - s + woff[wid];
    if (t0 + 0 < nf) cur[t0 + 0] = excl;
    excl += a0;
    if (t0 + 1 < nf) cur[t0 + 1] = excl;
    excl += a1;
    if (t0 + 2 < nf) cur[t0 + 2] = excl;
    __syncthreads();

    // per-node descriptors: base + packed boundaries (B1..B4) + true degree
    for (int i = tid; i < nNodes; i += 1024) {
        int b = i * N_REL;
        int c0 = cur[b];
        int B1 = cur[b + 1] - c0, B2 = cur[b + 2] - c0;
        int B3 = cur[b + 3] - c0, B4 = cur[b + 4] - c0;
        int deg = cur[b + 4] + hist[b + 4] - c0;
        nbase[node0 + i] = gbase + c0;
        nbp[node0 + i] = make_int2(B1 | (B2 << 8) | (B3 << 16) | (B4 << 24), deg);
    }
    __syncthreads();

    for (int i = tid; i < cnt; i += 1024) {
        int2 r = my[i];
        int fb = ((r.x >> 20) & 511) * N_REL + ((r.x >> 17) & 7);
        int pos = gbase + atomicAdd(&cur[fb], 1);
        float wf = __int_as_float(r.y) / (float)hist[fb];   // fold 1/deg
        edges[pos] = make_int2(r.x & 0xFFFFF, __float_as_int(wf)); // src|rel<<17
    }
}

// ---------------------------------------------------------------------------
// Feature conversion: one read of x -> xh (bf16) + xq (fp8 e4m3)
// ---------------------------------------------------------------------------
__global__ void cvt_feat(const float* __restrict__ x, ushort* __restrict__ xh,
                         unsigned int* __restrict__ xq) {
    int i = blockIdx.x * blockDim.x + threadIdx.x;   // float4 index
    if (i >= (N_NODES * 128) / 4) return;
    float4 v = reinterpret_cast<const float4*>(x)[i];
    ushort4 o;
    o.x = f2bf(v.x); o.y = f2bf(v.y); o.z = f2bf(v.z); o.w = f2bf(v.w);
    reinterpret_cast<ushort4*>(xh)[i] = o;
    int p = __builtin_amdgcn_cvt_pk_fp8_f32(v.x, v.y, 0, false);
    p = __builtin_amdgcn_cvt_pk_fp8_f32(v.z, v.w, p, true);
    xq[i] = (unsigned int)p;
}

// Stack [root1; W1_0..W1_4] transposed: Wt[o][seg*128+k] (o: 128 outs).
__global__ void cvt_wstack(const float* __restrict__ W, const float* __restrict__ root,
                           ushort* __restrict__ Wt) {
    int t = blockIdx.x * blockDim.x + threadIdx.x;   // 0..767
    int o = blockIdx.y;
    int seg = t >> 7, k = t & 127;
    float v = (seg == 0) ? root[k * 128 + o] : W[(size_t)(seg - 1) * 128 * 128 + k * 128 + o];
    Wt[(size_t)o * 768 + t] = f2bf(v);
}

// Layer-2 stacked weights: Wt2s[o][k], o 0..95: 0-15 root2, 16+r*16+c = W2_r col c.
__global__ void cvt_w2(const float* __restrict__ W2, const float* __restrict__ root2,
                       ushort* __restrict__ Wt2s) {
    int i = blockIdx.x * blockDim.x + threadIdx.x;
    if (i >= 96 * 128) return;
    int o = i >> 7, k = i & 127;
    float v = (o < 16) ? root2[k * 16 + o]
                       : W2[((size_t)((o >> 4) - 1) * 128 + k) * 16 + (o & 15)];
    Wt2s[i] = f2bf(v);
}

// ---------------------------------------------------------------------------
// Layer-1 gather: one wave per node; fp8 feature table (128 B/edge). Flat
// loop, 8-deep readlane load clusters, scalar boundary flushes. Descriptors
// give base + packed relation boundaries + true degree. 1/deg pre-folded.
// ---------------------------------------------------------------------------
__global__ __launch_bounds__(256) void gather_all(
    const ushort* __restrict__ featq,  // fp8 [N][128] viewed as ushort[N][64]
    const int2* __restrict__ edges,    // (src|rel<<17, w/deg) relation-sorted
    const int* __restrict__ nbase,
    const int2* __restrict__ nbp,
    ushort* __restrict__ A,            // [rows][640] bf16
    int node0) {
    int n = __builtin_amdgcn_readfirstlane(node0 + blockIdx.x * 4 + (threadIdx.x >> 6));
    int lane = threadIdx.x & 63;
    int o0  = __builtin_amdgcn_readfirstlane(nbase[n]);
    int bx  = __builtin_amdgcn_readfirstlane(nbp[n].x);
    int deg = __builtin_amdgcn_readfirstlane(nbp[n].y);
    unsigned int* Ap = reinterpret_cast<unsigned int*>(A) + (size_t)(n - node0) * 320;

    if (deg <= 64) {
        int2 er = (lane < deg) ? edges[o0 + lane] : make_int2(0, 0);
        unsigned long long bp = (unsigned long long)(unsigned)bx
                              | ((unsigned long long)(unsigned)deg << 32);
        float ax = 0.f, ay = 0.f;
        int seg = 0;
        auto flushAt = [&](int jj) {
            while (seg < 5 && jj == (int)((bp >> (seg * 8)) & 0xFFull)) {
                Ap[64 * seg + lane] =
                    (unsigned int)f2bf(ax) | ((unsigned int)f2bf(ay) << 16);
                ax = 0.f; ay = 0.f; ++seg;
            }
        };
        int deg8 = (deg + 7) & ~7;
        for (int j = 0; j < deg8; j += 8) {
            // ---- load cluster: 8 independent fp8 gathers in flight ----
            unsigned short q[8];
            float w[8];
            #pragma unroll
            for (int u = 0; u < 8; ++u) {
                int m = __builtin_amdgcn_readlane(er.x, j + u);
                q[u] = featq[((size_t)(m & 0x1FFFF) << 6) + lane];
            }
            #pragma unroll
            for (int u = 0; u < 8; ++u)
                w[u] = __uint_as_float(__builtin_amdgcn_readlane(er.y, j + u));
            // ---- consume, flushing segment snapshots at boundaries ----
            #pragma unroll
            for (int u = 0; u < 8; ++u) {
                flushAt(j + u);
                f32x2 f = __builtin_amdgcn_cvt_pk_f32_fp8((int)q[u], false);
                ax = fmaf(w[u], f.x, ax); ay = fmaf(w[u], f.y, ay);
            }
        }
        while (seg < 5) {
            Ap[64 * seg + lane] =
                (unsigned int)f2bf(ax) | ((unsigned int)f2bf(ay) << 16);
            ax = 0.f; ay = 0.f; ++seg;
        }
    } else {
        // rare slow path: per-relation sub-ranges
        int B[6];
        B[0] = 0; B[1] = bx & 0xFF; B[2] = (bx >> 8) & 0xFF;
        B[3] = (bx >> 16) & 0xFF; B[4] = (unsigned)bx >> 24; B[5] = deg;
        #pragma unroll
        for (int r = 0; r < 5; ++r) {
            int s0 = o0 + B[r], e1 = o0 + B[r + 1];
            float ax = 0.f, ay = 0.f;
            for (int base = s0; base < e1; base += 64) {
                int2 er = (base + lane < e1) ? edges[base + lane] : make_int2(0, 0);
                int m = e1 - base; if (m > 64) m = 64;
                for (int j = 0; j < m; ++j) {
                    int mm = __builtin_amdgcn_readlane(er.x, j);
                    float w = __uint_as_float(__builtin_amdgcn_readlane(er.y, j));
                    unsigned short qv = featq[((size_t)(mm & 0x1FFFF) << 6) + lane];
                    f32x2 f = __builtin_amdgcn_cvt_pk_f32_fp8((int)qv, false);
                    ax = fmaf(w, f.x, ax);
                    ay = fmaf(w, f.y, ay);
                }
            }
            Ap[r * 64 + lane] = (unsigned int)f2bf(ax) | ((unsigned int)f2bf(ay) << 16);
        }
    }
}

// ---------------------------------------------------------------------------
// FUSED layer-1 GEMM + layer-2 transform:
//   h_blk = relu([xh | A640] @ Wt1^T + b1)   (LDS only — never hits HBM)
//   Yh_blk = h_blk @ Wt2s^T                  (bf16 out)
// Phase 1: 12 K-steps, 16+16 KB LDS double-use; epilogue stores h into the
// SAME 32 KB LDS (swizzled). Phase 2: gemm96 core, B-frags straight from the
// L2-resident 24 KB Wt2s (no LDS staging).
// ---------------------------------------------------------------------------
__global__ __launch_bounds__(256) void gemmL1f(
    const ushort* __restrict__ xh,   // [N][128] bf16
    const ushort* __restrict__ A,    // chunk-local [rows][640] bf16
    const ushort* __restrict__ Wt,   // [128][768] bf16
    const float* __restrict__ bias,  // [128]
    const ushort* __restrict__ Wt2,  // [96][128] bf16 (L2-resident)
    ushort* __restrict__ Yh,         // [N][96] bf16
    int row0, int nrows) {
    __shared__ ushort lds[128 * 128];        // 32 KB: phase1 As|Bs, then h
    ushort* As = lds;
    ushort* Bs = lds + 128 * 64;
    const int tid = threadIdx.x, lane = tid & 63, wave = tid >> 6;
    const int m0 = blockIdx.x * 128;

    constexpr int MF = 4, NF = 4;
    const int wr0 = (wave >> 1) * 64;
    const int wc0 = (wave & 1) * 64;

    f32x4 acc[MF][NF] = {};

    for (int ks = 0; ks < 12; ++ks) {
        #pragma unroll
        for (int u = 0; u < 4; ++u) {
            int idx = tid + u * 256;
            int row = idx >> 3, slot = idx & 7;
            float4 v;
            if (ks < 2) {
                int gr = row0 + m0 + row; if (gr >= N_NODES) gr = N_NODES - 1;
                v = *reinterpret_cast<const float4*>(xh + (size_t)gr * 128 + ks * 64 + slot * 8);
            } else {
                v = *reinterpret_cast<const float4*>(
                    A + (size_t)(m0 + row) * 640 + (ks - 2) * 64 + slot * 8);
            }
            int byte = row * 128 + ((slot ^ (row & 7)) << 4);
            *reinterpret_cast<float4*>(reinterpret_cast<char*>(As) + byte) = v;
        }
        #pragma unroll
        for (int u = 0; u < 4; ++u) {
            int idx = tid + u * 256;
            int row = idx >> 3, slot = idx & 7;
            float4 v = *reinterpret_cast<const float4*>(
                Wt + (size_t)row * 768 + ks * 64 + slot * 8);
            int byte = row * 128 + ((slot ^ (row & 7)) << 4);
            *reinterpret_cast<float4*>(reinterpret_cast<char*>(Bs) + byte) = v;
        }
        __syncthreads();

        #pragma unroll
        for (int kh = 0; kh < 2; ++kh) {
            bf16x8 af[MF], bfr[NF];
            #pragma unroll
            for (int m = 0; m < MF; ++m) {
                int row = wr0 + m * 16 + (lane & 15);
                int slot = kh * 4 + (lane >> 4);
                int byte = row * 128 + ((slot ^ (row & 7)) << 4);
                af[m] = *reinterpret_cast<const bf16x8*>(
                    reinterpret_cast<const char*>(As) + byte);
            }
            #pragma unroll
            for (int nn = 0; nn < NF; ++nn) {
                int row = wc0 + nn * 16 + (lane & 15);
                int slot = kh * 4 + (lane >> 4);
                int byte = row * 128 + ((slot ^ (row & 7)) << 4);
                bfr[nn] = *reinterpret_cast<const bf16x8*>(
                    reinterpret_cast<const char*>(Bs) + byte);
            }
            #pragma unroll
            for (int m = 0; m < MF; ++m)
                #pragma unroll
                for (int nn = 0; nn < NF; ++nn)
                    acc[m][nn] = __builtin_amdgcn_mfma_f32_16x16x32_bf16(
                        af[m], bfr[nn], acc[m][nn], 0, 0, 0);
        }
        __syncthreads();
    }

    // ---- phase-1 epilogue: bias + relu -> h (bf16) into LDS, swizzled ----
    #pragma unroll
    for (int m = 0; m < MF; ++m) {
        int rloc = wr0 + m * 16 + (lane >> 4) * 4;
        #pragma unroll
        for (int nn = 0; nn < NF; ++nn) {
            int c = wc0 + nn * 16 + (lane & 15);
            float bv = bias[c];
            #pragma unroll
            for (int q = 0; q < 4; ++q) {
                int row = rloc + q;
                float v = fmaxf(acc[m][nn][q] + bv, 0.f);
                int byte = row * 256 + ((((c >> 3) ^ (row & 15)) << 4)) + (c & 7) * 2;
                *reinterpret_cast<ushort*>(reinterpret_cast<char*>(lds) + byte) = f2bf(v);
            }
        }
    }
    __syncthreads();

    // ---- phase 2: Yh = h @ Wt2^T (B-frags direct from global L2) ----
    f32x4 acc2[2][6] = {};
    #pragma unroll
    for (int ks = 0; ks < 4; ++ks) {
        bf16x8 af[2], bfr[6];
        #pragma unroll
        for (int m = 0; m < 2; ++m) {
            int row = wave * 32 + m * 16 + (lane & 15);
            int slot = ks * 4 + (lane >> 4);
            int byte = row * 256 + ((slot ^ (row & 15)) << 4);
            af[m] = *reinterpret_cast<const bf16x8*>(
                reinterpret_cast<const char*>(lds) + byte);
        }
        #pragma unroll
        for (int nn = 0; nn < 6; ++nn) {
            int row = nn * 16 + (lane & 15);
            int slot = ks * 4 + (lane >> 4);
            bfr[nn] = *reinterpret_cast<const bf16x8*>(
                Wt2 + (size_t)row * 128 + slot * 8);
        }
        #pragma unroll
        for (int m = 0; m < 2; ++m)
            #pragma unroll
            for (int nn = 0; nn < 6; ++nn)
                acc2[m][nn] = __builtin_amdgcn_mfma_f32_16x16x32_bf16(
                    af[m], bfr[nn], acc2[m][nn], 0, 0, 0);
    }

    #pragma unroll
    for (int m = 0; m < 2; ++m) {
        int rloc = wave * 32 + m * 16 + (lane >> 4) * 4;
        #pragma unroll
        for (int nn = 0; nn < 6; ++nn) {
            int c = nn * 16 + (lane & 15);
            #pragma unroll
            for (int q = 0; q < 4; ++q) {
                int lrow = m0 + rloc + q;
                int grow = row0 + lrow;
                if (lrow < nrows && grow < N_NODES)
                    Yh[(size_t)grow * 96 + c] = f2bf(acc2[m][nn][q]);
            }
        }
    }
}

// ---------------------------------------------------------------------------
// Layer-2 aggregate + bias + log_softmax, fused. 4 nodes/wave, 16 lanes/node.
// ---------------------------------------------------------------------------
__global__ __launch_bounds__(256) void agg2_softmax(
    const ushort* __restrict__ Yh, const int2* __restrict__ edges,
    const int* __restrict__ nbase, const int2* __restrict__ nbp,
    const float* __restrict__ b2, float* __restrict__ out) {
    int wave = threadIdx.x >> 6, lane = threadIdx.x & 63;
    int q = lane >> 4, c = lane & 15;
    int n = (blockIdx.x * 4 + wave) * 4 + q;
    int nn = (n < N_NODES) ? n : N_NODES - 1;
    int o0 = nbase[nn];
    int deg = nbp[nn].y;

    float val = bfu(Yh[(size_t)nn * 96 + c]) + b2[c];

    for (int b = 0; b < deg; b += 16) {
        int2 er = (b + c < deg) ? edges[o0 + b + c] : make_int2(0, 0);
        #pragma unroll
        for (int j = 0; j < 16; ++j) {
            int m = __shfl(er.x, q * 16 + j);
            float w = __uint_as_float(__shfl(er.y, q * 16 + j));
            int s = m & 0x1FFFF;
            int rel = (m >> 17) & 7;
            val = fmaf(w, bfu(Yh[(size_t)s * 96 + 16 + rel * 16 + c]), val);
        }
    }

    // log_softmax over the 16-lane group
    float mx = val;
    #pragma unroll
    for (int i = 1; i < 16; i <<= 1) mx = fmaxf(mx, __shfl_xor(mx, i));
    float ex = expf(val - mx);
    float ssum = ex;
    #pragma unroll
    for (int i = 1; i < 16; i <<= 1) ssum += __shfl_xor(ssum, i);
    float r = val - mx - logf(ssum);
    if (n < N_NODES) out[(size_t)n * 16 + c] = r;
}

// ---------------------------------------------------------------------------
extern "C" void kernel_launch(void* const* d_in, const int* in_sizes, int n_in,
                              void* d_out, int out_size, void* d_ws, size_t ws_size,
                              hipStream_t stream) {
    const float* x     = (const float*)d_in[0];
    const int*   ei    = (const int*)d_in[1];
    const int*   src   = ei;
    const int*   dst   = ei + N_EDGES;
    const float* ew    = (const float*)d_in[2];
    const int*   et    = (const int*)d_in[3];
    const float* W1    = (const float*)d_in[4];
    const float* root1 = (const float*)d_in[5];
    const float* b1    = (const float*)d_in[6];
    const float* W2    = (const float*)d_in[7];
    const float* root2 = (const float*)d_in[8];
    const float* b2    = (const float*)d_in[9];
    float* out = (float*)d_out;

    // workspace layout
    char* ws = (char*)d_ws;
    int*    ccur    = (int*)ws;                        //      1,024 B
    int*    cstart  = (int*)(ws + 1024);               //      1,024 B
    int*    nbase   = (int*)(ws + 4096);               //    400,000 B
    int2*   nbp     = (int2*)(ws + 404096);            //    800,000 B
    int2*   edges   = (int2*)(ws + 1204096);           // 12,800,000 B
    ushort* xh      = (ushort*)(ws + 18018304);        // 25,600,000 B
    ushort* Wt1     = (ushort*)(ws + 43618304);        //    196,608 B
    ushort* Wt2s    = (ushort*)(ws + 43814912);        //     24,576 B
    unsigned int* xq = (unsigned int*)(ws + 43839488); // 12,800,000 B (fp8 table)
    // union region @56,639,488: pe (25.7MB, build only) -> Abuf
    int2*   pe      = (int2*)(ws + 56639488);
    ushort* Abuf    = (ushort*)(ws + 56639488);

    // chunking: full-size A = 100096*1280 B = 128.1 MB
    const int chunk = (ws_size >= 225000000ull) ? N_NODES : 25000;
    const int nch   = N_NODES / chunk;
    // Yh after the A region (full) or after the 32MB chunk A (chunked)
    ushort* Yh = (ushort*)(ws + 56639488 +
        (chunk == N_NODES ? 128122880ull : 32112640ull));

    // --- precision conversions (x read once -> bf16 + fp8 tables) ---
    cvt_feat<<<((N_NODES * 128 / 4) + 255) / 256, 256, 0, stream>>>(x, xh, xq);
    cvt_wstack<<<dim3(3, 128), 256, 0, stream>>>(W1, root1, Wt1);
    cvt_w2<<<(96 * 128 + 255) / 256, 256, 0, stream>>>(W2, root2, Wt2s);

    // --- build (dst,rel)-bucketed CSR: 3 passes ---
    hipMemsetAsync(ccur, 0, 1024, stream);
    partition_append<<<(N_EDGES + 4095) / 4096, 1024, 0, stream>>>(src, dst, ew, et, ccur, pe);
    cscan<<<1, 256, 0, stream>>>(ccur, cstart);
    bucket_sort<<<NCOARSE, 1024, 0, stream>>>(ccur, cstart, pe, edges, nbase, nbp);

    // --- layer 1 + layer-2 transform, fused (h never hits HBM) ---
    for (int cc = 0; cc < nch; ++cc) {
        gather_all<<<chunk / 4, 256, 0, stream>>>(
            (const ushort*)xq, edges, nbase, nbp, Abuf, cc * chunk);
        gemmL1f<<<(chunk + 127) / 128, 256, 0, stream>>>(
            xh, Abuf, Wt1, b1, Wt2s, Yh, cc * chunk, chunk);
    }

    // --- layer-2 aggregate + bias + log_softmax ---
    agg2_softmax<<<(N_NODES + 15) / 16, 256, 0, stream>>>(
        Yh, edges, nbase, nbp, b2, out);
}